// Round 1
// baseline (6084.846 us; speedup 1.0000x reference)
//
#include <hip/hip_runtime.h>
#include <hip/hip_bf16.h>
#include <math.h>

typedef unsigned long long ull;
typedef unsigned int uint;

// ---------------------------------------------------------------------------
// Weight transpose: w (O, C, 2) -> wT[(c*2+t)*O + o]
// ---------------------------------------------------------------------------
__global__ void transpose_w_kernel(const float* __restrict__ w, float* __restrict__ wT,
                                   int O, int C) {
    int total = O * C * 2;
    for (int i = blockIdx.x * blockDim.x + threadIdx.x; i < total;
         i += gridDim.x * blockDim.x) {
        int o = i / (C * 2);
        int rem = i - o * C * 2;        // c*2 + t
        wT[(size_t)rem * O + o] = w[i];
    }
}

// ---------------------------------------------------------------------------
// Generic bitonic sort (ascending) in LDS
// ---------------------------------------------------------------------------
template <typename T>
__device__ inline void bitonic_sort(T* keys, int P, int tid, int nthreads) {
    for (int size = 2; size <= P; size <<= 1) {
        for (int stride = size >> 1; stride > 0; stride >>= 1) {
            __syncthreads();
            for (int i = tid; i < (P >> 1); i += nthreads) {
                int lo = i & (stride - 1);
                int a = ((i - lo) << 1) | lo;
                int b = a | stride;
                T x = keys[a], y = keys[b];
                bool asc = ((a & size) == 0);
                if ((x > y) == asc) { keys[a] = y; keys[b] = x; }
            }
        }
    }
    __syncthreads();
}

// ---------------------------------------------------------------------------
// Top-k along a (possibly strided) row, output in ORIGINAL index order
// (matches jax.lax.top_k + sort-indices + gather, incl. tie semantics).
// row -> n = row / CC, c = row % CC.
// src addr(e) = base(n) + c*src_c_stride + e*src_e_stride
// dst addr(i) = dst + dst_off + n*dst_n_stride + c*dst_c_stride + i*dst_e_stride
// ---------------------------------------------------------------------------
__global__ __launch_bounds__(256) void topk_kernel(
    const float* __restrict__ src, const float* __restrict__ src2, int split_n,
    int CC, long long src_n_stride, long long src_c_stride, long long src_e_stride,
    int L, int P, int k, int P2,
    float* __restrict__ dst, long long dst_off, long long dst_n_stride,
    long long dst_c_stride, long long dst_e_stride)
{
    extern __shared__ char smem[];
    ull* keys = (ull*)smem;
    float* vals = (float*)(keys + P);
    uint* idxs = (uint*)(vals + P);

    int row = blockIdx.x;
    int n = row / CC, c = row - n * CC;
    const float* sp = (split_n > 0 && n >= split_n)
                          ? src2 + (size_t)(n - split_n) * src_n_stride
                          : src + (size_t)n * src_n_stride;
    sp += (size_t)c * src_c_stride;

    int tid = threadIdx.x;
    for (int i = tid; i < P; i += blockDim.x) {
        float v = (i < L) ? sp[(size_t)i * src_e_stride] : -INFINITY;
        vals[i] = v;
        uint u = __float_as_uint(v);
        u = (u & 0x80000000u) ? ~u : (u | 0x80000000u);   // order-preserving map
        keys[i] = ((ull)(~u) << 32) | (uint)i;            // desc value, asc index
    }
    bitonic_sort<ull>(keys, P, tid, blockDim.x);

    for (int i = tid; i < P2; i += blockDim.x)
        idxs[i] = (i < k) ? (uint)(keys[i] & 0xffffffffull) : 0xffffffffu;
    bitonic_sort<uint>(idxs, P2, tid, blockDim.x);

    float* dp = dst + (size_t)dst_off + (size_t)n * dst_n_stride + (size_t)c * dst_c_stride;
    for (int i = tid; i < k; i += blockDim.x)
        dp[(size_t)i * dst_e_stride] = vals[idxs[i]];
}

// ---------------------------------------------------------------------------
// conv1d kernel-2 with PAD=4 zero padding + tanh.
// src rows contiguous: src[n*n_stride + l*C + c]. dst (N, Lout=Lin+7, 300).
// wT layout [(c*2+t)*300 + o]. Block: 320 threads (o = tid), LT positions.
// ---------------------------------------------------------------------------
template <int LT>
__global__ __launch_bounds__(320) void conv1d_tanh_kernel(
    const float* __restrict__ src, const float* __restrict__ src2, int split_n,
    long long n_stride, int Lin, int C,
    const float* __restrict__ wT, const float* __restrict__ bias,
    float* __restrict__ dst, int Lout)
{
    extern __shared__ float zs[];   // (LT+1) * C
    int n = blockIdx.y;
    int l0 = blockIdx.x * LT;
    const float* sp = (split_n > 0 && n >= split_n)
                          ? src2 + (size_t)(n - split_n) * n_stride
                          : src + (size_t)n * n_stride;
    int tid = threadIdx.x;
    int tot = (LT + 1) * C;
    for (int i = tid; i < tot; i += blockDim.x) {
        int r = i / C, c = i - r * C;
        int g = l0 + r - 4;   // PAD
        zs[i] = (g >= 0 && g < Lin) ? sp[(size_t)g * C + c] : 0.0f;
    }
    __syncthreads();

    int o = tid;
    if (o < 300) {
        float acc[LT];
        float bo = bias[o];
#pragma unroll
        for (int p = 0; p < LT; p++) acc[p] = bo;

        for (int c = 0; c < C; c += 2) {
            float w00 = wT[(size_t)(2 * c) * 300 + o];
            float w01 = wT[(size_t)(2 * c + 1) * 300 + o];
            float w10 = wT[(size_t)(2 * c + 2) * 300 + o];
            float w11 = wT[(size_t)(2 * c + 3) * 300 + o];
            float2 z2[LT + 1];
#pragma unroll
            for (int p = 0; p <= LT; p++)
                z2[p] = *(const float2*)&zs[p * C + c];
#pragma unroll
            for (int p = 0; p < LT; p++)
                acc[p] += z2[p].x * w00 + z2[p + 1].x * w01
                        + z2[p].y * w10 + z2[p + 1].y * w11;
        }
#pragma unroll
        for (int p = 0; p < LT; p++) {
            int l = l0 + p;
            if (l < Lout)
                dst[((size_t)n * Lout + l) * 300 + o] = tanhf(acc[p]);
        }
    }
}

// ---------------------------------------------------------------------------
// qt[b,q,e] = sum_d qg[b,q,d] * bw[d,e].  One block per (b,q) row.
// ---------------------------------------------------------------------------
__global__ __launch_bounds__(320) void qt_kernel(
    const float* __restrict__ qg, const float* __restrict__ bw,
    float* __restrict__ qt)
{
    __shared__ float rowS[300];
    int r = blockIdx.x;
    const float* gp = qg + (size_t)r * 300;
    int tid = threadIdx.x;
    for (int i = tid; i < 300; i += blockDim.x) rowS[i] = gp[i];
    __syncthreads();
    if (tid < 300) {
        float acc = 0.f;
        for (int d = 0; d < 300; d++) acc += rowS[d] * bw[d * 300 + tid];
        qt[(size_t)r * 300 + tid] = acc;
    }
}

// ---------------------------------------------------------------------------
// M = sigmoid(qt . dg^T + bb), fused with adaptive max pool 480->40 (win 12)
// and 960->40 (win 24). Block: region 48q x 96j (4x4 pooled outputs),
// 320 threads, active 288, thread tile 4x4, e-chunked LDS.
// ---------------------------------------------------------------------------
#define MP_EC 60
#define MP_SR 61
__global__ __launch_bounds__(320) void mpool_kernel(
    const float* __restrict__ qt, const float* __restrict__ dg,
    const float* __restrict__ bb, float* __restrict__ mp)
{
    __shared__ float qtS[48 * MP_SR];
    __shared__ float dgS[96 * MP_SR];
    __shared__ float red[16 * 18];

    int jb = blockIdx.x, qb = blockIdx.y, n = blockIdx.z;
    int b = n & 15;
    const float* qp = qt + (size_t)b * 480 * 300 + (size_t)(qb * 48) * 300;
    const float* dp = dg + (size_t)n * 960 * 300 + (size_t)(jb * 96) * 300;
    int t = threadIdx.x;
    int tq = t / 24, tj = t - tq * 24;   // valid when t < 288

    float acc[16];
#pragma unroll
    for (int i = 0; i < 16; i++) acc[i] = 0.f;

    for (int e0 = 0; e0 < 300; e0 += MP_EC) {
        __syncthreads();
        for (int i = t; i < 48 * MP_EC; i += 320) {
            int q = i / MP_EC, e = i - q * MP_EC;
            qtS[q * MP_SR + e] = qp[(size_t)q * 300 + e0 + e];
        }
        for (int i = t; i < 96 * MP_EC; i += 320) {
            int j = i / MP_EC, e = i - j * MP_EC;
            dgS[j * MP_SR + e] = dp[(size_t)j * 300 + e0 + e];
        }
        __syncthreads();
        if (t < 288) {
            const float* qrow = &qtS[(tq * 4) * MP_SR];
            const float* drow = &dgS[(tj * 4) * MP_SR];
            for (int e = 0; e < MP_EC; e++) {
                float a0 = qrow[e], a1 = qrow[MP_SR + e];
                float a2 = qrow[2 * MP_SR + e], a3 = qrow[3 * MP_SR + e];
                float b0 = drow[e], b1 = drow[MP_SR + e];
                float b2 = drow[2 * MP_SR + e], b3 = drow[3 * MP_SR + e];
                acc[0] += a0 * b0;  acc[1] += a0 * b1;  acc[2] += a0 * b2;  acc[3] += a0 * b3;
                acc[4] += a1 * b0;  acc[5] += a1 * b1;  acc[6] += a1 * b2;  acc[7] += a1 * b3;
                acc[8] += a2 * b0;  acc[9] += a2 * b1;  acc[10] += a2 * b2; acc[11] += a2 * b3;
                acc[12] += a3 * b0; acc[13] += a3 * b1; acc[14] += a3 * b2; acc[15] += a3 * b3;
            }
        }
    }
    if (t < 288) {
        float m = acc[0];
#pragma unroll
        for (int i = 1; i < 16; i++) m = fmaxf(m, acc[i]);
        int qi = tq / 3, ji = tj / 6;
        int sub = (tq % 3) * 6 + (tj % 6);
        red[(qi * 4 + ji) * 18 + sub] = m;
    }
    __syncthreads();
    if (t < 16) {
        float m = red[t * 18];
        for (int s = 1; s < 18; s++) m = fmaxf(m, red[t * 18 + s]);
        float z = m + bb[0];
        float sig = 1.f / (1.f + expf(-z));
        int qi = t / 4, ji = t - qi * 4;
        mp[(size_t)n * 1600 + (size_t)(qb * 4 + qi) * 40 + (jb * 4 + ji)] = sig;
    }
}

// ---------------------------------------------------------------------------
// One conv block: X (80,40,40) -> pad4 -> conv2x2 (50 ch) -> sigmoid ->
// adaptive pool 47->40 (H) then 47->40 (W) -> max over 50 channels -> Y.
// One block per n.
// ---------------------------------------------------------------------------
__global__ __launch_bounds__(256) void convblock_kernel(
    const float* __restrict__ X, const float* __restrict__ w,
    const float* __restrict__ bias, float* __restrict__ Y)
{
    __shared__ float xp[48 * 48];
    __shared__ float ys[47 * 47];
    __shared__ float t1[40 * 47];
    __shared__ float outacc[1600];

    int n = blockIdx.x, t = threadIdx.x;
    const float* xn = X + (size_t)n * 1600;
    for (int i = t; i < 48 * 48; i += 256) {
        int r = i / 48, c = i - r * 48;
        int rr = r - 4, cc = c - 4;
        xp[i] = (rr >= 0 && rr < 40 && cc >= 0 && cc < 40) ? xn[rr * 40 + cc] : 0.f;
    }
    for (int i = t; i < 1600; i += 256) outacc[i] = -INFINITY;
    __syncthreads();

    for (int oc = 0; oc < 50; oc++) {
        float w00 = w[oc * 4 + 0], w01 = w[oc * 4 + 1];
        float w10 = w[oc * 4 + 2], w11 = w[oc * 4 + 3];
        float bo = bias[oc];
        for (int i = t; i < 47 * 47; i += 256) {
            int r = i / 47, c = i - r * 47;
            float v = xp[r * 48 + c] * w00 + xp[r * 48 + c + 1] * w01
                    + xp[(r + 1) * 48 + c] * w10 + xp[(r + 1) * 48 + c + 1] * w11 + bo;
            ys[i] = 1.f / (1.f + expf(-v));
        }
        __syncthreads();
        for (int i = t; i < 40 * 47; i += 256) {
            int r = i / 47, c = i - r * 47;
            int s = (47 * r) / 40, e = (47 * (r + 1) + 39) / 40;
            float m = ys[s * 47 + c];
            for (int x = s + 1; x < e; x++) m = fmaxf(m, ys[x * 47 + c]);
            t1[i] = m;
        }
        __syncthreads();
        for (int i = t; i < 1600; i += 256) {
            int r = i / 40, c = i - r * 40;
            int s = (47 * c) / 40, e = (47 * (c + 1) + 39) / 40;
            float m = t1[r * 47 + s];
            for (int x = s + 1; x < e; x++) m = fmaxf(m, t1[r * 47 + x]);
            outacc[i] = fmaxf(outacc[i], m);
        }
        __syncthreads();
    }
    for (int i = t; i < 1600; i += 256) Y[(size_t)n * 1600 + i] = outacc[i];
}

// ---------------------------------------------------------------------------
// Head: h[i] = sig(feat[n,i,:].lw + lb); out[n] = sig(h.lw + lb)
// ---------------------------------------------------------------------------
__global__ __launch_bounds__(64) void head_kernel(
    const float* __restrict__ feat, const float* __restrict__ lw,
    const float* __restrict__ lb, float* __restrict__ out)
{
    __shared__ float hs[40];
    int n = blockIdx.x, t = threadIdx.x;
    const float* f = feat + (size_t)n * 1600;
    if (t < 40) {
        float a = 0.f;
        for (int j = 0; j < 40; j++) a += f[t * 40 + j] * lw[j];
        hs[t] = 1.f / (1.f + expf(-(a + lb[0])));
    }
    __syncthreads();
    if (t == 0) {
        float a = 0.f;
        for (int i = 0; i < 40; i++) a += hs[i] * lw[i];
        out[n] = 1.f / (1.f + expf(-(a + lb[0])));
    }
}

// ---------------------------------------------------------------------------
extern "C" void kernel_launch(void* const* d_in, const int* in_sizes, int n_in,
                              void* d_out, int out_size, void* d_ws, size_t ws_size,
                              hipStream_t stream) {
    const float* query    = (const float*)d_in[0];
    const float* pos_doc  = (const float*)d_in[1];
    const float* neg_docs = (const float*)d_in[2];
    const float* qw1 = (const float*)d_in[3];  const float* qb1 = (const float*)d_in[4];
    const float* qw2 = (const float*)d_in[5];  const float* qb2 = (const float*)d_in[6];
    const float* qw3 = (const float*)d_in[7];  const float* qb3 = (const float*)d_in[8];
    const float* dw1 = (const float*)d_in[9];  const float* db1 = (const float*)d_in[10];
    const float* dw2 = (const float*)d_in[11]; const float* db2 = (const float*)d_in[12];
    const float* dw3 = (const float*)d_in[13]; const float* db3 = (const float*)d_in[14];
    const float* bw  = (const float*)d_in[15]; const float* bb  = (const float*)d_in[16];
    const float* mw1 = (const float*)d_in[17]; const float* mb1 = (const float*)d_in[18];
    const float* mw2 = (const float*)d_in[19]; const float* mb2 = (const float*)d_in[20];
    const float* mw3 = (const float*)d_in[21]; const float* mb3 = (const float*)d_in[22];
    const float* lw  = (const float*)d_in[23]; const float* lb  = (const float*)d_in[24];

    float* ws = (float*)d_ws;
    float* qw1T = ws + 0;
    float* qw2T = ws + 614400;
    float* qw3T = ws + 794400;
    float* dw1T = ws + 974400;
    float* dw2T = ws + 1588800;
    float* dw3T = ws + 1768800;
    float* qg   = ws + 1948800;    // (16, 480, 300)
    float* dg   = ws + 4252800;    // (80, 960, 300)
    float* yt   = ws + 27292800;   // conv temp, max (80, 486, 300)
    float* qtb  = ws + 38956800;   // (16, 480, 300)
    float* mp   = ws + 41260800;   // (80, 40, 40)
    float* xb2  = ws + 41388800;   // (80, 40, 40)

    // --- weight transposes ---
    transpose_w_kernel<<<2400, 256, 0, stream>>>(qw1, qw1T, 300, 1024);
    transpose_w_kernel<<<704, 256, 0, stream>>>(qw2, qw2T, 300, 300);
    transpose_w_kernel<<<704, 256, 0, stream>>>(qw3, qw3T, 300, 300);
    transpose_w_kernel<<<2400, 256, 0, stream>>>(dw1, dw1T, 300, 1024);
    transpose_w_kernel<<<704, 256, 0, stream>>>(dw2, dw2T, 300, 300);
    transpose_w_kernel<<<704, 256, 0, stream>>>(dw3, dw3T, 300, 300);

    // ====================== query tower (qg: 239+160+80+1 = 480) ============
    // g0: top-300 of 1024 channels per (b,l)
    topk_kernel<<<16 * 239, 256, 1024 * 8 + 1024 * 4 + 512 * 4, stream>>>(
        query, nullptr, 0,
        239, 239LL * 1024, 1024, 1,
        1024, 1024, 300, 512,
        qg, 0, 480LL * 300, 300, 1);
    // conv1: (16,239,1024) -> yt (16,246,300)
    {
        dim3 g((246 + 11) / 12, 16);
        conv1d_tanh_kernel<12><<<g, 320, 13 * 1024 * 4, stream>>>(
            query, nullptr, 0, 239LL * 1024, 239, 1024, qw1T, qb1, yt, 246);
    }
    // p1: top-160 along length per (b,channel)
    topk_kernel<<<16 * 300, 256, 256 * 8 + 256 * 4 + 256 * 4, stream>>>(
        yt, nullptr, 0,
        300, 246LL * 300, 1, 300,
        246, 256, 160, 256,
        qg, 239LL * 300, 480LL * 300, 1, 300);
    // conv2: p1 (16,160,300) -> yt (16,167,300)
    {
        dim3 g((167 + 15) / 16, 16);
        conv1d_tanh_kernel<16><<<g, 320, 17 * 300 * 4, stream>>>(
            qg + 239 * 300, nullptr, 0, 480LL * 300, 160, 300, qw2T, qb2, yt, 167);
    }
    // p2: top-80
    topk_kernel<<<16 * 300, 256, 256 * 8 + 256 * 4 + 128 * 4, stream>>>(
        yt, nullptr, 0,
        300, 167LL * 300, 1, 300,
        167, 256, 80, 128,
        qg, 399LL * 300, 480LL * 300, 1, 300);
    // conv3: p2 (16,80,300) -> yt (16,87,300)
    {
        dim3 g((87 + 15) / 16, 16);
        conv1d_tanh_kernel<16><<<g, 320, 17 * 300 * 4, stream>>>(
            qg + 399 * 300, nullptr, 0, 480LL * 300, 80, 300, qw3T, qb3, yt, 87);
    }
    // p3: top-1
    topk_kernel<<<16 * 300, 256, 128 * 8 + 128 * 4 + 2 * 4, stream>>>(
        yt, nullptr, 0,
        300, 87LL * 300, 1, 300,
        87, 128, 1, 2,
        qg, 479LL * 300, 480LL * 300, 1, 300);

    // ====================== doc tower (dg: 479+320+160+1 = 960) =============
    // g0
    topk_kernel<<<80 * 479, 256, 1024 * 8 + 1024 * 4 + 512 * 4, stream>>>(
        pos_doc, neg_docs, 16,
        479, 479LL * 1024, 1024, 1,
        1024, 1024, 300, 512,
        dg, 0, 960LL * 300, 300, 1);
    // conv1: (80,479,1024) -> yt (80,486,300)
    {
        dim3 g((486 + 11) / 12, 80);
        conv1d_tanh_kernel<12><<<g, 320, 13 * 1024 * 4, stream>>>(
            pos_doc, neg_docs, 16, 479LL * 1024, 479, 1024, dw1T, db1, yt, 486);
    }
    // p1: top-320 of 486
    topk_kernel<<<80 * 300, 256, 512 * 8 + 512 * 4 + 512 * 4, stream>>>(
        yt, nullptr, 0,
        300, 486LL * 300, 1, 300,
        486, 512, 320, 512,
        dg, 479LL * 300, 960LL * 300, 1, 300);
    // conv2: p1 (80,320,300) -> yt (80,327,300)
    {
        dim3 g((327 + 15) / 16, 80);
        conv1d_tanh_kernel<16><<<g, 320, 17 * 300 * 4, stream>>>(
            dg + 479 * 300, nullptr, 0, 960LL * 300, 320, 300, dw2T, db2, yt, 327);
    }
    // p2: top-160 of 327
    topk_kernel<<<80 * 300, 256, 512 * 8 + 512 * 4 + 256 * 4, stream>>>(
        yt, nullptr, 0,
        300, 327LL * 300, 1, 300,
        327, 512, 160, 256,
        dg, 799LL * 300, 960LL * 300, 1, 300);
    // conv3: p2 (80,160,300) -> yt (80,167,300)
    {
        dim3 g((167 + 15) / 16, 80);
        conv1d_tanh_kernel<16><<<g, 320, 17 * 300 * 4, stream>>>(
            dg + 799 * 300, nullptr, 0, 960LL * 300, 160, 300, dw3T, db3, yt, 167);
    }
    // p3: top-1
    topk_kernel<<<80 * 300, 256, 256 * 8 + 256 * 4 + 2 * 4, stream>>>(
        yt, nullptr, 0,
        300, 167LL * 300, 1, 300,
        167, 256, 1, 2,
        dg, 959LL * 300, 960LL * 300, 1, 300);

    // ====================== similarity + pooling ============================
    qt_kernel<<<16 * 480, 320, 0, stream>>>(qg, bw, qtb);
    {
        dim3 g(10, 10, 80);
        mpool_kernel<<<g, 320, 0, stream>>>(qtb, dg, bb, mp);
    }

    // ====================== conv blocks + head ==============================
    convblock_kernel<<<80, 256, 0, stream>>>(mp, mw1, mb1, xb2);
    convblock_kernel<<<80, 256, 0, stream>>>(xb2, mw2, mb2, mp);
    convblock_kernel<<<80, 256, 0, stream>>>(mp, mw3, mb3, xb2);
    head_kernel<<<80, 64, 0, stream>>>(xb2, lw, lb, (float*)d_out);
}

// Round 2
// 4396.353 us; speedup vs baseline: 1.3841x; 1.3841x over previous
//
#include <hip/hip_runtime.h>
#include <hip/hip_bf16.h>
#include <math.h>

typedef unsigned long long ull;
typedef unsigned int uint;
typedef unsigned short ushort_t;

typedef short bf16x8 __attribute__((ext_vector_type(8)));
typedef float floatx4 __attribute__((ext_vector_type(4)));

// ---------------------------------------------------------------------------
// fp32 -> bf16 (round-to-nearest-even-ish)
// ---------------------------------------------------------------------------
__device__ inline ushort_t f2b(float f) {
    uint u = __float_as_uint(f);
    u = u + 0x7fffu + ((u >> 16) & 1u);
    return (ushort_t)(u >> 16);
}

// ---------------------------------------------------------------------------
// Prep: w (300, C, 2) fp32 -> Wb[t][n][c] bf16, n in [0,320), c in [0,Cp),
// zero-filled outside n<300, c<C.
// ---------------------------------------------------------------------------
__global__ void prep_w_kernel(const float* __restrict__ w, ushort_t* __restrict__ Wb,
                              int C, int Cp) {
    int total = 2 * 320 * Cp;
    for (int i = blockIdx.x * blockDim.x + threadIdx.x; i < total;
         i += gridDim.x * blockDim.x) {
        int t = i / (320 * Cp);
        int rem = i - t * 320 * Cp;
        int n = rem / Cp, c = rem - n * Cp;
        float v = (n < 300 && c < C) ? w[((size_t)n * C + c) * 2 + t] : 0.f;
        Wb[i] = f2b(v);
    }
}

// ---------------------------------------------------------------------------
// MFMA conv1d k=2, PAD=4, + tanh.  out[n,l,o] = tanh(b[o] + sum_c
//   xpad[l,c]*W0[c,o] + xpad[l+1,c]*W1[c,o]),  xpad = zero-pad-4 of src rows.
// Block: 256 thr, tile M=128 x N=160 (grid.x=2 covers N=320 padded).
// Wave tile 64x80 = 4x5 of 16x16x32 bf16 MFMA. K-chunks of 32 channels.
// X staged in LDS bf16 (row stride 40 -> aligned b128, conflict-free);
// W read as B-frags from pre-converted bf16 global (L2-resident).
// ---------------------------------------------------------------------------
__global__ __launch_bounds__(256) void conv1d_mfma_kernel(
    const float* __restrict__ src, const float* __restrict__ src2, int split_n,
    long long n_stride, int Lin, int C, int Cp, int Lout,
    const ushort_t* __restrict__ Wb, const float* __restrict__ bias,
    float* __restrict__ dst)
{
    __shared__ ushort_t Xs[129 * 40];

    int nb = blockIdx.x;          // N half (0/1)
    int mt = blockIdx.y;          // M tile
    int n  = blockIdx.z;          // sample
    int l0 = mt * 128;
    const float* sp = (split_n > 0 && n >= split_n)
                          ? src2 + (size_t)(n - split_n) * n_stride
                          : src + (size_t)n * n_stride;

    int tid = threadIdx.x;
    int wid = tid >> 6, lane = tid & 63;
    int wm = (wid >> 1) * 64;     // wave M offset in block
    int wn = (wid & 1) * 80;      // wave N offset in block
    int lrow = lane & 15, quad = lane >> 4;

    floatx4 acc[4][5];
#pragma unroll
    for (int i = 0; i < 4; i++)
#pragma unroll
        for (int j = 0; j < 5; j++) acc[i][j] = (floatx4){0.f, 0.f, 0.f, 0.f};

    for (int c0 = 0; c0 < Cp; c0 += 32) {
        __syncthreads();
        // stage xpad rows l0..l0+128, channels c0..c0+31 as bf16
        for (int idx = tid * 4; idx < 129 * 32; idx += 1024) {
            int r = idx >> 5, col = idx & 31;
            int g = l0 + r - 4;            // xpad row -> src row
            int c = c0 + col;
            ushort4 out4 = {0, 0, 0, 0};
            if (g >= 0 && g < Lin && c < C) {
                float4 v = *(const float4*)&sp[(size_t)g * C + c];
                out4.x = f2b(v.x); out4.y = f2b(v.y);
                out4.z = f2b(v.z); out4.w = f2b(v.w);
            }
            *(ushort4*)&Xs[r * 40 + col] = out4;
        }
        __syncthreads();

        // B-frags (W) from global: lane -> n=lrow, k=quad*8..+8
        bf16x8 wf[2][5];
#pragma unroll
        for (int t = 0; t < 2; t++)
#pragma unroll
            for (int ns = 0; ns < 5; ns++) {
                int ncol = nb * 160 + wn + ns * 16 + lrow;
                wf[t][ns] = *(const bf16x8*)&Wb[((size_t)(t * 320 + ncol)) * Cp + c0 + quad * 8];
            }
        // A-frags from LDS: lane -> m=lrow, k=quad*8..+8 (tap shifts row by 1)
        bf16x8 af[2][4];
#pragma unroll
        for (int t = 0; t < 2; t++)
#pragma unroll
            for (int ms = 0; ms < 4; ms++) {
                int row = wm + ms * 16 + lrow + t;
                af[t][ms] = *(const bf16x8*)&Xs[row * 40 + quad * 8];
            }
#pragma unroll
        for (int t = 0; t < 2; t++)
#pragma unroll
            for (int ms = 0; ms < 4; ms++)
#pragma unroll
                for (int ns = 0; ns < 5; ns++)
                    acc[ms][ns] = __builtin_amdgcn_mfma_f32_16x16x32_bf16(
                        af[t][ms], wf[t][ns], acc[ms][ns], 0, 0, 0);
    }

    // epilogue: C/D layout col=lane&15, row=quad*4+reg
#pragma unroll
    for (int ns = 0; ns < 5; ns++) {
        int o = nb * 160 + wn + ns * 16 + lrow;
        if (o >= 300) continue;
        float bo = bias[o];
#pragma unroll
        for (int ms = 0; ms < 4; ms++) {
#pragma unroll
            for (int r = 0; r < 4; r++) {
                int m = l0 + wm + ms * 16 + quad * 4 + r;
                if (m < Lout)
                    dst[((size_t)n * Lout + m) * 300 + o] = tanhf(acc[ms][ns][r] + bo);
            }
        }
    }
}

// ---------------------------------------------------------------------------
// Generic bitonic sort (ascending) in LDS
// ---------------------------------------------------------------------------
template <typename T>
__device__ inline void bitonic_sort(T* keys, int P, int tid, int nthreads) {
    for (int size = 2; size <= P; size <<= 1) {
        for (int stride = size >> 1; stride > 0; stride >>= 1) {
            __syncthreads();
            for (int i = tid; i < (P >> 1); i += nthreads) {
                int lo = i & (stride - 1);
                int a = ((i - lo) << 1) | lo;
                int b = a | stride;
                T x = keys[a], y = keys[b];
                bool asc = ((a & size) == 0);
                if ((x > y) == asc) { keys[a] = y; keys[b] = x; }
            }
        }
    }
    __syncthreads();
}

// ---------------------------------------------------------------------------
// Top-k along a (possibly strided) row, output in ORIGINAL index order.
// ---------------------------------------------------------------------------
__global__ __launch_bounds__(256) void topk_kernel(
    const float* __restrict__ src, const float* __restrict__ src2, int split_n,
    int CC, long long src_n_stride, long long src_c_stride, long long src_e_stride,
    int L, int P, int k, int P2,
    float* __restrict__ dst, long long dst_off, long long dst_n_stride,
    long long dst_c_stride, long long dst_e_stride)
{
    extern __shared__ char smem[];
    ull* keys = (ull*)smem;
    float* vals = (float*)(keys + P);
    uint* idxs = (uint*)(vals + P);

    int row = blockIdx.x;
    int n = row / CC, c = row - n * CC;
    const float* sp = (split_n > 0 && n >= split_n)
                          ? src2 + (size_t)(n - split_n) * src_n_stride
                          : src + (size_t)n * src_n_stride;
    sp += (size_t)c * src_c_stride;

    int tid = threadIdx.x;
    for (int i = tid; i < P; i += blockDim.x) {
        float v = (i < L) ? sp[(size_t)i * src_e_stride] : -INFINITY;
        vals[i] = v;
        uint u = __float_as_uint(v);
        u = (u & 0x80000000u) ? ~u : (u | 0x80000000u);
        keys[i] = ((ull)(~u) << 32) | (uint)i;
    }
    bitonic_sort<ull>(keys, P, tid, blockDim.x);

    for (int i = tid; i < P2; i += blockDim.x)
        idxs[i] = (i < k) ? (uint)(keys[i] & 0xffffffffull) : 0xffffffffu;
    bitonic_sort<uint>(idxs, P2, tid, blockDim.x);

    float* dp = dst + (size_t)dst_off + (size_t)n * dst_n_stride + (size_t)c * dst_c_stride;
    for (int i = tid; i < k; i += blockDim.x)
        dp[(size_t)i * dst_e_stride] = vals[idxs[i]];
}

// ---------------------------------------------------------------------------
// qt[b,q,e] = sum_d qg[b,q,d] * bw[d,e].  One block per (b,q) row.
// ---------------------------------------------------------------------------
__global__ __launch_bounds__(320) void qt_kernel(
    const float* __restrict__ qg, const float* __restrict__ bw,
    float* __restrict__ qt)
{
    __shared__ float rowS[300];
    int r = blockIdx.x;
    const float* gp = qg + (size_t)r * 300;
    int tid = threadIdx.x;
    for (int i = tid; i < 300; i += blockDim.x) rowS[i] = gp[i];
    __syncthreads();
    if (tid < 300) {
        float acc = 0.f;
        for (int d = 0; d < 300; d++) acc += rowS[d] * bw[d * 300 + tid];
        qt[(size_t)r * 300 + tid] = acc;
    }
}

// ---------------------------------------------------------------------------
// M = sigmoid(qt . dg^T + bb) fused with adaptive max pools 480->40, 960->40.
// ---------------------------------------------------------------------------
#define MP_EC 60
#define MP_SR 61
__global__ __launch_bounds__(320) void mpool_kernel(
    const float* __restrict__ qt, const float* __restrict__ dg,
    const float* __restrict__ bb, float* __restrict__ mp)
{
    __shared__ float qtS[48 * MP_SR];
    __shared__ float dgS[96 * MP_SR];
    __shared__ float red[16 * 18];

    int jb = blockIdx.x, qb = blockIdx.y, n = blockIdx.z;
    int b = n & 15;
    const float* qp = qt + (size_t)b * 480 * 300 + (size_t)(qb * 48) * 300;
    const float* dp = dg + (size_t)n * 960 * 300 + (size_t)(jb * 96) * 300;
    int t = threadIdx.x;
    int tq = t / 24, tj = t - tq * 24;

    float acc[16];
#pragma unroll
    for (int i = 0; i < 16; i++) acc[i] = 0.f;

    for (int e0 = 0; e0 < 300; e0 += MP_EC) {
        __syncthreads();
        for (int i = t; i < 48 * MP_EC; i += 320) {
            int q = i / MP_EC, e = i - q * MP_EC;
            qtS[q * MP_SR + e] = qp[(size_t)q * 300 + e0 + e];
        }
        for (int i = t; i < 96 * MP_EC; i += 320) {
            int j = i / MP_EC, e = i - j * MP_EC;
            dgS[j * MP_SR + e] = dp[(size_t)j * 300 + e0 + e];
        }
        __syncthreads();
        if (t < 288) {
            const float* qrow = &qtS[(tq * 4) * MP_SR];
            const float* drow = &dgS[(tj * 4) * MP_SR];
            for (int e = 0; e < MP_EC; e++) {
                float a0 = qrow[e], a1 = qrow[MP_SR + e];
                float a2 = qrow[2 * MP_SR + e], a3 = qrow[3 * MP_SR + e];
                float b0 = drow[e], b1 = drow[MP_SR + e];
                float b2 = drow[2 * MP_SR + e], b3 = drow[3 * MP_SR + e];
                acc[0] += a0 * b0;  acc[1] += a0 * b1;  acc[2] += a0 * b2;  acc[3] += a0 * b3;
                acc[4] += a1 * b0;  acc[5] += a1 * b1;  acc[6] += a1 * b2;  acc[7] += a1 * b3;
                acc[8] += a2 * b0;  acc[9] += a2 * b1;  acc[10] += a2 * b2; acc[11] += a2 * b3;
                acc[12] += a3 * b0; acc[13] += a3 * b1; acc[14] += a3 * b2; acc[15] += a3 * b3;
            }
        }
    }
    if (t < 288) {
        float m = acc[0];
#pragma unroll
        for (int i = 1; i < 16; i++) m = fmaxf(m, acc[i]);
        int qi = tq / 3, ji = tj / 6;
        int sub = (tq % 3) * 6 + (tj % 6);
        red[(qi * 4 + ji) * 18 + sub] = m;
    }
    __syncthreads();
    if (t < 16) {
        float m = red[t * 18];
        for (int s = 1; s < 18; s++) m = fmaxf(m, red[t * 18 + s]);
        float z = m + bb[0];
        float sig = 1.f / (1.f + expf(-z));
        int qi = t / 4, ji = t - qi * 4;
        mp[(size_t)n * 1600 + (size_t)(qb * 4 + qi) * 40 + (jb * 4 + ji)] = sig;
    }
}

// ---------------------------------------------------------------------------
// Conv block: pad4 -> conv2x2(50) -> sigmoid -> pool 47->40 (H,W) -> ch-max.
// ---------------------------------------------------------------------------
__global__ __launch_bounds__(256) void convblock_kernel(
    const float* __restrict__ X, const float* __restrict__ w,
    const float* __restrict__ bias, float* __restrict__ Y)
{
    __shared__ float xp[48 * 48];
    __shared__ float ys[47 * 47];
    __shared__ float t1[40 * 47];
    __shared__ float outacc[1600];

    int n = blockIdx.x, t = threadIdx.x;
    const float* xn = X + (size_t)n * 1600;
    for (int i = t; i < 48 * 48; i += 256) {
        int r = i / 48, c = i - r * 48;
        int rr = r - 4, cc = c - 4;
        xp[i] = (rr >= 0 && rr < 40 && cc >= 0 && cc < 40) ? xn[rr * 40 + cc] : 0.f;
    }
    for (int i = t; i < 1600; i += 256) outacc[i] = -INFINITY;
    __syncthreads();

    for (int oc = 0; oc < 50; oc++) {
        float w00 = w[oc * 4 + 0], w01 = w[oc * 4 + 1];
        float w10 = w[oc * 4 + 2], w11 = w[oc * 4 + 3];
        float bo = bias[oc];
        for (int i = t; i < 47 * 47; i += 256) {
            int r = i / 47, c = i - r * 47;
            float v = xp[r * 48 + c] * w00 + xp[r * 48 + c + 1] * w01
                    + xp[(r + 1) * 48 + c] * w10 + xp[(r + 1) * 48 + c + 1] * w11 + bo;
            ys[i] = 1.f / (1.f + expf(-v));
        }
        __syncthreads();
        for (int i = t; i < 40 * 47; i += 256) {
            int r = i / 47, c = i - r * 47;
            int s = (47 * r) / 40, e = (47 * (r + 1) + 39) / 40;
            float m = ys[s * 47 + c];
            for (int x = s + 1; x < e; x++) m = fmaxf(m, ys[x * 47 + c]);
            t1[i] = m;
        }
        __syncthreads();
        for (int i = t; i < 1600; i += 256) {
            int r = i / 40, c = i - r * 40;
            int s = (47 * c) / 40, e = (47 * (c + 1) + 39) / 40;
            float m = t1[r * 47 + s];
            for (int x = s + 1; x < e; x++) m = fmaxf(m, t1[r * 47 + x]);
            outacc[i] = fmaxf(outacc[i], m);
        }
        __syncthreads();
    }
    for (int i = t; i < 1600; i += 256) Y[(size_t)n * 1600 + i] = outacc[i];
}

// ---------------------------------------------------------------------------
// Head
// ---------------------------------------------------------------------------
__global__ __launch_bounds__(64) void head_kernel(
    const float* __restrict__ feat, const float* __restrict__ lw,
    const float* __restrict__ lb, float* __restrict__ out)
{
    __shared__ float hs[40];
    int n = blockIdx.x, t = threadIdx.x;
    const float* f = feat + (size_t)n * 1600;
    if (t < 40) {
        float a = 0.f;
        for (int j = 0; j < 40; j++) a += f[t * 40 + j] * lw[j];
        hs[t] = 1.f / (1.f + expf(-(a + lb[0])));
    }
    __syncthreads();
    if (t == 0) {
        float a = 0.f;
        for (int i = 0; i < 40; i++) a += hs[i] * lw[i];
        out[n] = 1.f / (1.f + expf(-(a + lb[0])));
    }
}

// ---------------------------------------------------------------------------
extern "C" void kernel_launch(void* const* d_in, const int* in_sizes, int n_in,
                              void* d_out, int out_size, void* d_ws, size_t ws_size,
                              hipStream_t stream) {
    const float* query    = (const float*)d_in[0];
    const float* pos_doc  = (const float*)d_in[1];
    const float* neg_docs = (const float*)d_in[2];
    const float* qw1 = (const float*)d_in[3];  const float* qb1 = (const float*)d_in[4];
    const float* qw2 = (const float*)d_in[5];  const float* qb2 = (const float*)d_in[6];
    const float* qw3 = (const float*)d_in[7];  const float* qb3 = (const float*)d_in[8];
    const float* dw1 = (const float*)d_in[9];  const float* db1 = (const float*)d_in[10];
    const float* dw2 = (const float*)d_in[11]; const float* db2 = (const float*)d_in[12];
    const float* dw3 = (const float*)d_in[13]; const float* db3 = (const float*)d_in[14];
    const float* bw  = (const float*)d_in[15]; const float* bb  = (const float*)d_in[16];
    const float* mw1 = (const float*)d_in[17]; const float* mb1 = (const float*)d_in[18];
    const float* mw2 = (const float*)d_in[19]; const float* mb2 = (const float*)d_in[20];
    const float* mw3 = (const float*)d_in[21]; const float* mb3 = (const float*)d_in[22];
    const float* lw  = (const float*)d_in[23]; const float* lb  = (const float*)d_in[24];

    float* ws = (float*)d_ws;
    ushort_t* qw1b = (ushort_t*)(ws + 0);        // 2*320*1024 bf16
    ushort_t* qw2b = (ushort_t*)(ws + 327680);   // 2*320*320
    ushort_t* qw3b = (ushort_t*)(ws + 430080);
    ushort_t* dw1b = (ushort_t*)(ws + 532480);
    ushort_t* dw2b = (ushort_t*)(ws + 860160);
    ushort_t* dw3b = (ushort_t*)(ws + 962560);
    float* qg   = ws + 1064960;    // (16, 480, 300)
    float* dg   = ws + 3368960;    // (80, 960, 300)
    float* yt   = ws + 26408960;   // conv temp, max (80, 486, 300)
    float* qtb  = ws + 38072960;   // (16, 480, 300)
    float* mp   = ws + 40376960;   // (80, 40, 40)
    float* xb2  = ws + 40504960;   // (80, 40, 40)

    // --- weight prep (fp32 -> padded bf16 [t][320][Cp]) ---
    prep_w_kernel<<<512, 256, 0, stream>>>(qw1, qw1b, 1024, 1024);
    prep_w_kernel<<<256, 256, 0, stream>>>(qw2, qw2b, 300, 320);
    prep_w_kernel<<<256, 256, 0, stream>>>(qw3, qw3b, 300, 320);
    prep_w_kernel<<<512, 256, 0, stream>>>(dw1, dw1b, 1024, 1024);
    prep_w_kernel<<<256, 256, 0, stream>>>(dw2, dw2b, 300, 320);
    prep_w_kernel<<<256, 256, 0, stream>>>(dw3, dw3b, 300, 320);

    // ====================== query tower (qg: 239+160+80+1 = 480) ============
    topk_kernel<<<16 * 239, 256, 1024 * 8 + 1024 * 4 + 512 * 4, stream>>>(
        query, nullptr, 0,
        239, 239LL * 1024, 1024, 1,
        1024, 1024, 300, 512,
        qg, 0, 480LL * 300, 300, 1);
    {   // conv1: (16,239,1024) -> yt (16,246,300)
        dim3 g(2, 2, 16);
        conv1d_mfma_kernel<<<g, 256, 0, stream>>>(
            query, nullptr, 0, 239LL * 1024, 239, 1024, 1024, 246, qw1b, qb1, yt);
    }
    topk_kernel<<<16 * 300, 256, 256 * 8 + 256 * 4 + 256 * 4, stream>>>(
        yt, nullptr, 0,
        300, 246LL * 300, 1, 300,
        246, 256, 160, 256,
        qg, 239LL * 300, 480LL * 300, 1, 300);
    {   // conv2: p1 (16,160,300) -> yt (16,167,300)
        dim3 g(2, 2, 16);
        conv1d_mfma_kernel<<<g, 256, 0, stream>>>(
            qg + 239 * 300, nullptr, 0, 480LL * 300, 160, 300, 320, 167, qw2b, qb2, yt);
    }
    topk_kernel<<<16 * 300, 256, 256 * 8 + 256 * 4 + 128 * 4, stream>>>(
        yt, nullptr, 0,
        300, 167LL * 300, 1, 300,
        167, 256, 80, 128,
        qg, 399LL * 300, 480LL * 300, 1, 300);
    {   // conv3: p2 (16,80,300) -> yt (16,87,300)
        dim3 g(2, 1, 16);
        conv1d_mfma_kernel<<<g, 256, 0, stream>>>(
            qg + 399 * 300, nullptr, 0, 480LL * 300, 80, 300, 320, 87, qw3b, qb3, yt);
    }
    topk_kernel<<<16 * 300, 256, 128 * 8 + 128 * 4 + 2 * 4, stream>>>(
        yt, nullptr, 0,
        300, 87LL * 300, 1, 300,
        87, 128, 1, 2,
        qg, 479LL * 300, 480LL * 300, 1, 300);

    // ====================== doc tower (dg: 479+320+160+1 = 960) =============
    topk_kernel<<<80 * 479, 256, 1024 * 8 + 1024 * 4 + 512 * 4, stream>>>(
        pos_doc, neg_docs, 16,
        479, 479LL * 1024, 1024, 1,
        1024, 1024, 300, 512,
        dg, 0, 960LL * 300, 300, 1);
    {   // conv1: (80,479,1024) -> yt (80,486,300)
        dim3 g(2, 4, 80);
        conv1d_mfma_kernel<<<g, 256, 0, stream>>>(
            pos_doc, neg_docs, 16, 479LL * 1024, 479, 1024, 1024, 486, dw1b, db1, yt);
    }
    topk_kernel<<<80 * 300, 256, 512 * 8 + 512 * 4 + 512 * 4, stream>>>(
        yt, nullptr, 0,
        300, 486LL * 300, 1, 300,
        486, 512, 320, 512,
        dg, 479LL * 300, 960LL * 300, 1, 300);
    {   // conv2: p1 (80,320,300) -> yt (80,327,300)
        dim3 g(2, 3, 80);
        conv1d_mfma_kernel<<<g, 256, 0, stream>>>(
            dg + 479 * 300, nullptr, 0, 960LL * 300, 320, 300, 320, 327, dw2b, db2, yt);
    }
    topk_kernel<<<80 * 300, 256, 512 * 8 + 512 * 4 + 256 * 4, stream>>>(
        yt, nullptr, 0,
        300, 327LL * 300, 1, 300,
        327, 512, 160, 256,
        dg, 799LL * 300, 960LL * 300, 1, 300);
    {   // conv3: p2 (80,160,300) -> yt (80,167,300)
        dim3 g(2, 2, 80);
        conv1d_mfma_kernel<<<g, 256, 0, stream>>>(
            dg + 799 * 300, nullptr, 0, 960LL * 300, 160, 300, 320, 167, dw3b, db3, yt);
    }
    topk_kernel<<<80 * 300, 256, 256 * 8 + 256 * 4 + 2 * 4, stream>>>(
        yt, nullptr, 0,
        300, 167LL * 300, 1, 300,
        167, 256, 1, 2,
        dg, 959LL * 300, 960LL * 300, 1, 300);

    // ====================== similarity + pooling ============================
    qt_kernel<<<16 * 480, 320, 0, stream>>>(qg, bw, qtb);
    {
        dim3 g(10, 10, 80);
        mpool_kernel<<<g, 320, 0, stream>>>(qtb, dg, bb, mp);
    }

    // ====================== conv blocks + head ==============================
    convblock_kernel<<<80, 256, 0, stream>>>(mp, mw1, mb1, xb2);
    convblock_kernel<<<80, 256, 0, stream>>>(xb2, mw2, mb2, mp);
    convblock_kernel<<<80, 256, 0, stream>>>(mp, mw3, mb3, xb2);
    head_kernel<<<80, 64, 0, stream>>>(xb2, lw, lb, (float*)d_out);
}

// Round 3
// 3659.725 us; speedup vs baseline: 1.6627x; 1.2013x over previous
//
#include <hip/hip_runtime.h>
#include <hip/hip_bf16.h>
#include <math.h>

typedef unsigned long long ull;
typedef unsigned int uint;
typedef unsigned short ushort_t;

typedef short bf16x8 __attribute__((ext_vector_type(8)));
typedef float floatx4 __attribute__((ext_vector_type(4)));

// ---------------------------------------------------------------------------
// fp32 -> bf16 (round-to-nearest-even-ish)
// ---------------------------------------------------------------------------
__device__ inline ushort_t f2b(float f) {
    uint u = __float_as_uint(f);
    u = u + 0x7fffu + ((u >> 16) & 1u);
    return (ushort_t)(u >> 16);
}

// ---------------------------------------------------------------------------
// Prep: w (300, C, 2) fp32 -> Wb[t][n][c] bf16, n in [0,320), c in [0,Cp).
// ---------------------------------------------------------------------------
__global__ void prep_w_kernel(const float* __restrict__ w, ushort_t* __restrict__ Wb,
                              int C, int Cp) {
    int total = 2 * 320 * Cp;
    for (int i = blockIdx.x * blockDim.x + threadIdx.x; i < total;
         i += gridDim.x * blockDim.x) {
        int t = i / (320 * Cp);
        int rem = i - t * 320 * Cp;
        int n = rem / Cp, c = rem - n * Cp;
        float v = (n < 300 && c < C) ? w[((size_t)n * C + c) * 2 + t] : 0.f;
        Wb[i] = f2b(v);
    }
}

// ---------------------------------------------------------------------------
// dg (80,960,300) fp32 -> dgb16 (80,960,320) bf16 (zero-padded cols 300..319)
// Block: 256 thr = 4 rows x 64 lanes.
// ---------------------------------------------------------------------------
__global__ __launch_bounds__(256) void dg_to_bf16_kernel(
    const float* __restrict__ dg, ushort_t* __restrict__ dgb16)
{
    int row = blockIdx.x * 4 + (threadIdx.x >> 6);
    int lane = threadIdx.x & 63;
    const float* sp = dg + (size_t)row * 300;
    ushort_t* dp = dgb16 + (size_t)row * 320;
#pragma unroll
    for (int i = 0; i < 5; i++) {
        int c = lane + i * 64;
        float v = (c < 300) ? sp[c] : 0.f;
        dp[c] = f2b(v);
    }
}

// ---------------------------------------------------------------------------
// MFMA conv1d k=2, PAD=4, + tanh (as R1).
// ---------------------------------------------------------------------------
__global__ __launch_bounds__(256) void conv1d_mfma_kernel(
    const float* __restrict__ src, const float* __restrict__ src2, int split_n,
    long long n_stride, int Lin, int C, int Cp, int Lout,
    const ushort_t* __restrict__ Wb, const float* __restrict__ bias,
    float* __restrict__ dst)
{
    __shared__ ushort_t Xs[129 * 40];

    int nb = blockIdx.x;
    int mt = blockIdx.y;
    int n  = blockIdx.z;
    int l0 = mt * 128;
    const float* sp = (split_n > 0 && n >= split_n)
                          ? src2 + (size_t)(n - split_n) * n_stride
                          : src + (size_t)n * n_stride;

    int tid = threadIdx.x;
    int wid = tid >> 6, lane = tid & 63;
    int wm = (wid >> 1) * 64;
    int wn = (wid & 1) * 80;
    int lrow = lane & 15, quad = lane >> 4;

    floatx4 acc[4][5];
#pragma unroll
    for (int i = 0; i < 4; i++)
#pragma unroll
        for (int j = 0; j < 5; j++) acc[i][j] = (floatx4){0.f, 0.f, 0.f, 0.f};

    for (int c0 = 0; c0 < Cp; c0 += 32) {
        __syncthreads();
        for (int idx = tid * 4; idx < 129 * 32; idx += 1024) {
            int r = idx >> 5, col = idx & 31;
            int g = l0 + r - 4;
            int c = c0 + col;
            ushort4 out4 = {0, 0, 0, 0};
            if (g >= 0 && g < Lin && c < C) {
                float4 v = *(const float4*)&sp[(size_t)g * C + c];
                out4.x = f2b(v.x); out4.y = f2b(v.y);
                out4.z = f2b(v.z); out4.w = f2b(v.w);
            }
            *(ushort4*)&Xs[r * 40 + col] = out4;
        }
        __syncthreads();

        bf16x8 wf[2][5];
#pragma unroll
        for (int t = 0; t < 2; t++)
#pragma unroll
            for (int ns = 0; ns < 5; ns++) {
                int ncol = nb * 160 + wn + ns * 16 + lrow;
                wf[t][ns] = *(const bf16x8*)&Wb[((size_t)(t * 320 + ncol)) * Cp + c0 + quad * 8];
            }
        bf16x8 af[2][4];
#pragma unroll
        for (int t = 0; t < 2; t++)
#pragma unroll
            for (int ms = 0; ms < 4; ms++) {
                int row = wm + ms * 16 + lrow + t;
                af[t][ms] = *(const bf16x8*)&Xs[row * 40 + quad * 8];
            }
#pragma unroll
        for (int t = 0; t < 2; t++)
#pragma unroll
            for (int ms = 0; ms < 4; ms++)
#pragma unroll
                for (int ns = 0; ns < 5; ns++)
                    acc[ms][ns] = __builtin_amdgcn_mfma_f32_16x16x32_bf16(
                        af[t][ms], wf[t][ns], acc[ms][ns], 0, 0, 0);
    }

#pragma unroll
    for (int ns = 0; ns < 5; ns++) {
        int o = nb * 160 + wn + ns * 16 + lrow;
        if (o >= 300) continue;
        float bo = bias[o];
#pragma unroll
        for (int ms = 0; ms < 4; ms++) {
#pragma unroll
            for (int r = 0; r < 4; r++) {
                int m = l0 + wm + ms * 16 + quad * 4 + r;
                if (m < Lout)
                    dst[((size_t)n * Lout + m) * 300 + o] = tanhf(acc[ms][ns][r] + bo);
            }
        }
    }
}

// ---------------------------------------------------------------------------
// Generic bitonic sort (ascending) in LDS
// ---------------------------------------------------------------------------
template <typename T>
__device__ inline void bitonic_sort(T* keys, int P, int tid, int nthreads) {
    for (int size = 2; size <= P; size <<= 1) {
        for (int stride = size >> 1; stride > 0; stride >>= 1) {
            __syncthreads();
            for (int i = tid; i < (P >> 1); i += nthreads) {
                int lo = i & (stride - 1);
                int a = ((i - lo) << 1) | lo;
                int b = a | stride;
                T x = keys[a], y = keys[b];
                bool asc = ((a & size) == 0);
                if ((x > y) == asc) { keys[a] = y; keys[b] = x; }
            }
        }
    }
    __syncthreads();
}

// ---------------------------------------------------------------------------
// Top-k along a (possibly strided) row, output in ORIGINAL index order.
// ---------------------------------------------------------------------------
__global__ __launch_bounds__(256) void topk_kernel(
    const float* __restrict__ src, const float* __restrict__ src2, int split_n,
    int CC, long long src_n_stride, long long src_c_stride, long long src_e_stride,
    int L, int P, int k, int P2,
    float* __restrict__ dst, long long dst_off, long long dst_n_stride,
    long long dst_c_stride, long long dst_e_stride)
{
    extern __shared__ char smem[];
    ull* keys = (ull*)smem;
    float* vals = (float*)(keys + P);
    uint* idxs = (uint*)(vals + P);

    int row = blockIdx.x;
    int n = row / CC, c = row - n * CC;
    const float* sp = (split_n > 0 && n >= split_n)
                          ? src2 + (size_t)(n - split_n) * src_n_stride
                          : src + (size_t)n * src_n_stride;
    sp += (size_t)c * src_c_stride;

    int tid = threadIdx.x;
    for (int i = tid; i < P; i += blockDim.x) {
        float v = (i < L) ? sp[(size_t)i * src_e_stride] : -INFINITY;
        vals[i] = v;
        uint u = __float_as_uint(v);
        u = (u & 0x80000000u) ? ~u : (u | 0x80000000u);
        keys[i] = ((ull)(~u) << 32) | (uint)i;
    }
    bitonic_sort<ull>(keys, P, tid, blockDim.x);

    for (int i = tid; i < P2; i += blockDim.x)
        idxs[i] = (i < k) ? (uint)(keys[i] & 0xffffffffull) : 0xffffffffu;
    bitonic_sort<uint>(idxs, P2, tid, blockDim.x);

    float* dp = dst + (size_t)dst_off + (size_t)n * dst_n_stride + (size_t)c * dst_c_stride;
    for (int i = tid; i < k; i += blockDim.x)
        dp[(size_t)i * dst_e_stride] = vals[idxs[i]];
}

// ---------------------------------------------------------------------------
// qt row GEMV: qtb16[r,e] = bf16( sum_d qg[r,d] * bw[d,e] ), e padded to 320.
// ---------------------------------------------------------------------------
__global__ __launch_bounds__(320) void qt_kernel(
    const float* __restrict__ qg, const float* __restrict__ bw,
    ushort_t* __restrict__ qtb16)
{
    __shared__ float rowS[300];
    int r = blockIdx.x;
    const float* gp = qg + (size_t)r * 300;
    int tid = threadIdx.x;
    for (int i = tid; i < 300; i += blockDim.x) rowS[i] = gp[i];
    __syncthreads();
    float acc = 0.f;
    if (tid < 300) {
        for (int d = 0; d < 300; d++) acc += rowS[d] * bw[d * 300 + tid];
    }
    qtb16[(size_t)r * 320 + tid] = (tid < 300) ? f2b(acc) : (ushort_t)0;
}

// ---------------------------------------------------------------------------
// MFMA M-GEMM fused with pooling:
// pooled[n, qw, jw] = sigmoid(bb + max over 12x24 window of qt[b].dg[n]^T).
// Block tile 96(M) x 192(N), 4 waves of 48x96 (3x6 16x16x32 MFMAs), K=320.
// Fragments straight from global (L2-resident); pool via per-lane row-max ->
// LDS [2][12][192] -> 64-thread rectangle reduce.
// ---------------------------------------------------------------------------
__global__ __launch_bounds__(256) void mpool_mfma_kernel(
    const ushort_t* __restrict__ qtb16, const ushort_t* __restrict__ dgb16,
    const float* __restrict__ bb, float* __restrict__ mp)
{
    __shared__ float pool[2 * 12 * 192];

    int jb = blockIdx.x;          // 0..4 (192-col tile)
    int qb = blockIdx.y;          // 0..4 (96-row tile)
    int n  = blockIdx.z;          // 0..79
    int b  = n & 15;

    int tid = threadIdx.x;
    int wid = tid >> 6, lane = tid & 63;
    int wm2 = wid >> 1;
    int wm = wm2 * 48, wn = (wid & 1) * 96;
    int lrow = lane & 15, quad = lane >> 4;

    const ushort_t* Abase = qtb16 + ((size_t)b * 480 + qb * 96 + wm) * 320 + quad * 8;
    const ushort_t* Bbase = dgb16 + ((size_t)n * 960 + jb * 192 + wn) * 320 + quad * 8;

    floatx4 acc[3][6];
#pragma unroll
    for (int i = 0; i < 3; i++)
#pragma unroll
        for (int j = 0; j < 6; j++) acc[i][j] = (floatx4){0.f, 0.f, 0.f, 0.f};

#pragma unroll 2
    for (int c0 = 0; c0 < 320; c0 += 32) {
        bf16x8 af[3], bf[6];
#pragma unroll
        for (int mt = 0; mt < 3; mt++)
            af[mt] = *(const bf16x8*)&Abase[(size_t)(mt * 16 + lrow) * 320 + c0];
#pragma unroll
        for (int nt = 0; nt < 6; nt++)
            bf[nt] = *(const bf16x8*)&Bbase[(size_t)(nt * 16 + lrow) * 320 + c0];
#pragma unroll
        for (int mt = 0; mt < 3; mt++)
#pragma unroll
            for (int nt = 0; nt < 6; nt++)
                acc[mt][nt] = __builtin_amdgcn_mfma_f32_16x16x32_bf16(
                    af[mt], bf[nt], acc[mt][nt], 0, 0, 0);
    }

    // per-lane row-max of each 4-row group (groups never straddle 12-windows)
#pragma unroll
    for (int mt = 0; mt < 3; mt++) {
        int g = mt * 4 + quad;
#pragma unroll
        for (int nt = 0; nt < 6; nt++) {
            floatx4 a = acc[mt][nt];
            float rm = fmaxf(fmaxf(a[0], a[1]), fmaxf(a[2], a[3]));
            pool[(wm2 * 12 + g) * 192 + wn + nt * 16 + lrow] = rm;
        }
    }
    __syncthreads();

    if (tid < 64) {
        int qw = tid >> 3, jw = tid & 7;
        int slab = qw >> 2, w = qw & 3;
        float m = -INFINITY;
        const float* pp = &pool[(slab * 12 + w * 3) * 192 + jw * 24];
        for (int g = 0; g < 3; g++)
            for (int c = 0; c < 24; c++)
                m = fmaxf(m, pp[g * 192 + c]);
        float sig = 1.f / (1.f + expf(-(m + bb[0])));
        mp[(size_t)n * 1600 + (size_t)(qb * 8 + qw) * 40 + (jb * 8 + jw)] = sig;
    }
}

// ---------------------------------------------------------------------------
// Conv block: pad4 -> conv2x2(50) -> sigmoid -> pool 47->40 (H,W) -> ch-max.
// ---------------------------------------------------------------------------
__global__ __launch_bounds__(256) void convblock_kernel(
    const float* __restrict__ X, const float* __restrict__ w,
    const float* __restrict__ bias, float* __restrict__ Y)
{
    __shared__ float xp[48 * 48];
    __shared__ float ys[47 * 47];
    __shared__ float t1[40 * 47];
    __shared__ float outacc[1600];

    int n = blockIdx.x, t = threadIdx.x;
    const float* xn = X + (size_t)n * 1600;
    for (int i = t; i < 48 * 48; i += 256) {
        int r = i / 48, c = i - r * 48;
        int rr = r - 4, cc = c - 4;
        xp[i] = (rr >= 0 && rr < 40 && cc >= 0 && cc < 40) ? xn[rr * 40 + cc] : 0.f;
    }
    for (int i = t; i < 1600; i += 256) outacc[i] = -INFINITY;
    __syncthreads();

    for (int oc = 0; oc < 50; oc++) {
        float w00 = w[oc * 4 + 0], w01 = w[oc * 4 + 1];
        float w10 = w[oc * 4 + 2], w11 = w[oc * 4 + 3];
        float bo = bias[oc];
        for (int i = t; i < 47 * 47; i += 256) {
            int r = i / 47, c = i - r * 47;
            float v = xp[r * 48 + c] * w00 + xp[r * 48 + c + 1] * w01
                    + xp[(r + 1) * 48 + c] * w10 + xp[(r + 1) * 48 + c + 1] * w11 + bo;
            ys[i] = 1.f / (1.f + expf(-v));
        }
        __syncthreads();
        for (int i = t; i < 40 * 47; i += 256) {
            int r = i / 47, c = i - r * 47;
            int s = (47 * r) / 40, e = (47 * (r + 1) + 39) / 40;
            float m = ys[s * 47 + c];
            for (int x = s + 1; x < e; x++) m = fmaxf(m, ys[x * 47 + c]);
            t1[i] = m;
        }
        __syncthreads();
        for (int i = t; i < 1600; i += 256) {
            int r = i / 40, c = i - r * 40;
            int s = (47 * c) / 40, e = (47 * (c + 1) + 39) / 40;
            float m = t1[r * 47 + s];
            for (int x = s + 1; x < e; x++) m = fmaxf(m, t1[r * 47 + x]);
            outacc[i] = fmaxf(outacc[i], m);
        }
        __syncthreads();
    }
    for (int i = t; i < 1600; i += 256) Y[(size_t)n * 1600 + i] = outacc[i];
}

// ---------------------------------------------------------------------------
// Head
// ---------------------------------------------------------------------------
__global__ __launch_bounds__(64) void head_kernel(
    const float* __restrict__ feat, const float* __restrict__ lw,
    const float* __restrict__ lb, float* __restrict__ out)
{
    __shared__ float hs[40];
    int n = blockIdx.x, t = threadIdx.x;
    const float* f = feat + (size_t)n * 1600;
    if (t < 40) {
        float a = 0.f;
        for (int j = 0; j < 40; j++) a += f[t * 40 + j] * lw[j];
        hs[t] = 1.f / (1.f + expf(-(a + lb[0])));
    }
    __syncthreads();
    if (t == 0) {
        float a = 0.f;
        for (int i = 0; i < 40; i++) a += hs[i] * lw[i];
        out[n] = 1.f / (1.f + expf(-(a + lb[0])));
    }
}

// ---------------------------------------------------------------------------
extern "C" void kernel_launch(void* const* d_in, const int* in_sizes, int n_in,
                              void* d_out, int out_size, void* d_ws, size_t ws_size,
                              hipStream_t stream) {
    const float* query    = (const float*)d_in[0];
    const float* pos_doc  = (const float*)d_in[1];
    const float* neg_docs = (const float*)d_in[2];
    const float* qw1 = (const float*)d_in[3];  const float* qb1 = (const float*)d_in[4];
    const float* qw2 = (const float*)d_in[5];  const float* qb2 = (const float*)d_in[6];
    const float* qw3 = (const float*)d_in[7];  const float* qb3 = (const float*)d_in[8];
    const float* dw1 = (const float*)d_in[9];  const float* db1 = (const float*)d_in[10];
    const float* dw2 = (const float*)d_in[11]; const float* db2 = (const float*)d_in[12];
    const float* dw3 = (const float*)d_in[13]; const float* db3 = (const float*)d_in[14];
    const float* bw  = (const float*)d_in[15]; const float* bb  = (const float*)d_in[16];
    const float* mw1 = (const float*)d_in[17]; const float* mb1 = (const float*)d_in[18];
    const float* mw2 = (const float*)d_in[19]; const float* mb2 = (const float*)d_in[20];
    const float* mw3 = (const float*)d_in[21]; const float* mb3 = (const float*)d_in[22];
    const float* lw  = (const float*)d_in[23]; const float* lb  = (const float*)d_in[24];

    float* ws = (float*)d_ws;
    ushort_t* qw1b = (ushort_t*)(ws + 0);        // 2*320*1024 bf16
    ushort_t* qw2b = (ushort_t*)(ws + 327680);   // 2*320*320
    ushort_t* qw3b = (ushort_t*)(ws + 430080);
    ushort_t* dw1b = (ushort_t*)(ws + 532480);
    ushort_t* dw2b = (ushort_t*)(ws + 860160);
    ushort_t* dw3b = (ushort_t*)(ws + 962560);
    float* qg   = ws + 1064960;    // (16, 480, 300)
    float* dg   = ws + 3368960;    // (80, 960, 300)
    float* yt   = ws + 26408960;   // conv temp, max (80, 486, 300)
    // dgb16 overlaps yt (yt dead after last doc top-k)
    ushort_t* dgb16 = (ushort_t*)(ws + 26408960);   // (80,960,320) bf16
    ushort_t* qtb16 = (ushort_t*)(ws + 38696960);   // (16,480,320) bf16
    float* mp   = ws + 39925760;   // (80, 40, 40)
    float* xb2  = ws + 40053760;   // (80, 40, 40)

    // --- weight prep ---
    prep_w_kernel<<<512, 256, 0, stream>>>(qw1, qw1b, 1024, 1024);
    prep_w_kernel<<<256, 256, 0, stream>>>(qw2, qw2b, 300, 320);
    prep_w_kernel<<<256, 256, 0, stream>>>(qw3, qw3b, 300, 320);
    prep_w_kernel<<<512, 256, 0, stream>>>(dw1, dw1b, 1024, 1024);
    prep_w_kernel<<<256, 256, 0, stream>>>(dw2, dw2b, 300, 320);
    prep_w_kernel<<<256, 256, 0, stream>>>(dw3, dw3b, 300, 320);

    // ====================== query tower (qg: 239+160+80+1 = 480) ============
    topk_kernel<<<16 * 239, 256, 1024 * 8 + 1024 * 4 + 512 * 4, stream>>>(
        query, nullptr, 0,
        239, 239LL * 1024, 1024, 1,
        1024, 1024, 300, 512,
        qg, 0, 480LL * 300, 300, 1);
    {
        dim3 g(2, 2, 16);
        conv1d_mfma_kernel<<<g, 256, 0, stream>>>(
            query, nullptr, 0, 239LL * 1024, 239, 1024, 1024, 246, qw1b, qb1, yt);
    }
    topk_kernel<<<16 * 300, 256, 256 * 8 + 256 * 4 + 256 * 4, stream>>>(
        yt, nullptr, 0,
        300, 246LL * 300, 1, 300,
        246, 256, 160, 256,
        qg, 239LL * 300, 480LL * 300, 1, 300);
    {
        dim3 g(2, 2, 16);
        conv1d_mfma_kernel<<<g, 256, 0, stream>>>(
            qg + 239 * 300, nullptr, 0, 480LL * 300, 160, 300, 320, 167, qw2b, qb2, yt);
    }
    topk_kernel<<<16 * 300, 256, 256 * 8 + 256 * 4 + 128 * 4, stream>>>(
        yt, nullptr, 0,
        300, 167LL * 300, 1, 300,
        167, 256, 80, 128,
        qg, 399LL * 300, 480LL * 300, 1, 300);
    {
        dim3 g(2, 1, 16);
        conv1d_mfma_kernel<<<g, 256, 0, stream>>>(
            qg + 399 * 300, nullptr, 0, 480LL * 300, 80, 300, 320, 87, qw3b, qb3, yt);
    }
    topk_kernel<<<16 * 300, 256, 128 * 8 + 128 * 4 + 2 * 4, stream>>>(
        yt, nullptr, 0,
        300, 87LL * 300, 1, 300,
        87, 128, 1, 2,
        qg, 479LL * 300, 480LL * 300, 1, 300);

    // ====================== doc tower (dg: 479+320+160+1 = 960) =============
    topk_kernel<<<80 * 479, 256, 1024 * 8 + 1024 * 4 + 512 * 4, stream>>>(
        pos_doc, neg_docs, 16,
        479, 479LL * 1024, 1024, 1,
        1024, 1024, 300, 512,
        dg, 0, 960LL * 300, 300, 1);
    {
        dim3 g(2, 4, 80);
        conv1d_mfma_kernel<<<g, 256, 0, stream>>>(
            pos_doc, neg_docs, 16, 479LL * 1024, 479, 1024, 1024, 486, dw1b, db1, yt);
    }
    topk_kernel<<<80 * 300, 256, 512 * 8 + 512 * 4 + 512 * 4, stream>>>(
        yt, nullptr, 0,
        300, 486LL * 300, 1, 300,
        486, 512, 320, 512,
        dg, 479LL * 300, 960LL * 300, 1, 300);
    {
        dim3 g(2, 3, 80);
        conv1d_mfma_kernel<<<g, 256, 0, stream>>>(
            dg + 479 * 300, nullptr, 0, 960LL * 300, 320, 300, 320, 327, dw2b, db2, yt);
    }
    topk_kernel<<<80 * 300, 256, 512 * 8 + 512 * 4 + 256 * 4, stream>>>(
        yt, nullptr, 0,
        300, 327LL * 300, 1, 300,
        327, 512, 160, 256,
        dg, 799LL * 300, 960LL * 300, 1, 300);
    {
        dim3 g(2, 2, 80);
        conv1d_mfma_kernel<<<g, 256, 0, stream>>>(
            dg + 799 * 300, nullptr, 0, 960LL * 300, 160, 300, 320, 167, dw3b, db3, yt);
    }
    topk_kernel<<<80 * 300, 256, 256 * 8 + 256 * 4 + 2 * 4, stream>>>(
        yt, nullptr, 0,
        300, 167LL * 300, 1, 300,
        167, 256, 1, 2,
        dg, 959LL * 300, 960LL * 300, 1, 300);

    // ====================== similarity + pooling ============================
    // NOTE: dgb16 overlaps yt — launch only after the last doc top-k above.
    dg_to_bf16_kernel<<<80 * 960 / 4, 256, 0, stream>>>(dg, dgb16);
    qt_kernel<<<16 * 480, 320, 0, stream>>>(qg, bw, qtb16);
    {
        dim3 g(5, 5, 80);
        mpool_mfma_kernel<<<g, 256, 0, stream>>>(qtb16, dgb16, bb, mp);
    }

    // ====================== conv blocks + head ==============================
    convblock_kernel<<<80, 256, 0, stream>>>(mp, mw1, mb1, xb2);
    convblock_kernel<<<80, 256, 0, stream>>>(xb2, mw2, mb2, mp);
    convblock_kernel<<<80, 256, 0, stream>>>(mp, mw3, mb3, xb2);
    head_kernel<<<80, 64, 0, stream>>>(xb2, lw, lb, (float*)d_out);
}

// Round 4
// 2510.769 us; speedup vs baseline: 2.4235x; 1.4576x over previous
//
#include <hip/hip_runtime.h>
#include <hip/hip_bf16.h>
#include <math.h>

typedef unsigned long long ull;
typedef unsigned int uint;
typedef unsigned short ushort_t;

typedef short bf16x8 __attribute__((ext_vector_type(8)));
typedef float floatx4 __attribute__((ext_vector_type(4)));

// ---------------------------------------------------------------------------
// fp32 -> bf16 (round-to-nearest-even-ish)
// ---------------------------------------------------------------------------
__device__ inline ushort_t f2b(float f) {
    uint u = __float_as_uint(f);
    u = u + 0x7fffu + ((u >> 16) & 1u);
    return (ushort_t)(u >> 16);
}

// order-preserving float->uint map (monotone increasing) and its inverse
__device__ inline uint fkey(float v) {
    uint u = __float_as_uint(v);
    return (u & 0x80000000u) ? ~u : (u | 0x80000000u);
}
__device__ inline float kinv(uint k) {
    uint u = (k & 0x80000000u) ? (k ^ 0x80000000u) : ~k;
    return __uint_as_float(u);
}

// ---------------------------------------------------------------------------
// Prep: w (300, C, 2) fp32 -> Wb[t][n][c] bf16, n in [0,320), c in [0,Cp).
// ---------------------------------------------------------------------------
__global__ void prep_w_kernel(const float* __restrict__ w, ushort_t* __restrict__ Wb,
                              int C, int Cp) {
    int total = 2 * 320 * Cp;
    for (int i = blockIdx.x * blockDim.x + threadIdx.x; i < total;
         i += gridDim.x * blockDim.x) {
        int t = i / (320 * Cp);
        int rem = i - t * 320 * Cp;
        int n = rem / Cp, c = rem - n * Cp;
        float v = (n < 300 && c < C) ? w[((size_t)n * C + c) * 2 + t] : 0.f;
        Wb[i] = f2b(v);
    }
}

// ---------------------------------------------------------------------------
// dg (80,960,300) fp32 -> dgb16 (80,960,320) bf16 (zero-padded cols 300..319)
// ---------------------------------------------------------------------------
__global__ __launch_bounds__(256) void dg_to_bf16_kernel(
    const float* __restrict__ dg, ushort_t* __restrict__ dgb16)
{
    int row = blockIdx.x * 4 + (threadIdx.x >> 6);
    int lane = threadIdx.x & 63;
    const float* sp = dg + (size_t)row * 300;
    ushort_t* dp = dgb16 + (size_t)row * 320;
#pragma unroll
    for (int i = 0; i < 5; i++) {
        int c = lane + i * 64;
        float v = (c < 300) ? sp[c] : 0.f;
        dp[c] = f2b(v);
    }
}

// ---------------------------------------------------------------------------
// MFMA conv1d k=2, PAD=4, + tanh.
// ---------------------------------------------------------------------------
__global__ __launch_bounds__(256) void conv1d_mfma_kernel(
    const float* __restrict__ src, const float* __restrict__ src2, int split_n,
    long long n_stride, int Lin, int C, int Cp, int Lout,
    const ushort_t* __restrict__ Wb, const float* __restrict__ bias,
    float* __restrict__ dst)
{
    __shared__ ushort_t Xs[129 * 40];

    int nb = blockIdx.x;
    int mt = blockIdx.y;
    int n  = blockIdx.z;
    int l0 = mt * 128;
    const float* sp = (split_n > 0 && n >= split_n)
                          ? src2 + (size_t)(n - split_n) * n_stride
                          : src + (size_t)n * n_stride;

    int tid = threadIdx.x;
    int wid = tid >> 6, lane = tid & 63;
    int wm = (wid >> 1) * 64;
    int wn = (wid & 1) * 80;
    int lrow = lane & 15, quad = lane >> 4;

    floatx4 acc[4][5];
#pragma unroll
    for (int i = 0; i < 4; i++)
#pragma unroll
        for (int j = 0; j < 5; j++) acc[i][j] = (floatx4){0.f, 0.f, 0.f, 0.f};

    for (int c0 = 0; c0 < Cp; c0 += 32) {
        __syncthreads();
        for (int idx = tid * 4; idx < 129 * 32; idx += 1024) {
            int r = idx >> 5, col = idx & 31;
            int g = l0 + r - 4;
            int c = c0 + col;
            ushort4 out4 = {0, 0, 0, 0};
            if (g >= 0 && g < Lin && c < C) {
                float4 v = *(const float4*)&sp[(size_t)g * C + c];
                out4.x = f2b(v.x); out4.y = f2b(v.y);
                out4.z = f2b(v.z); out4.w = f2b(v.w);
            }
            *(ushort4*)&Xs[r * 40 + col] = out4;
        }
        __syncthreads();

        bf16x8 wf[2][5];
#pragma unroll
        for (int t = 0; t < 2; t++)
#pragma unroll
            for (int ns = 0; ns < 5; ns++) {
                int ncol = nb * 160 + wn + ns * 16 + lrow;
                wf[t][ns] = *(const bf16x8*)&Wb[((size_t)(t * 320 + ncol)) * Cp + c0 + quad * 8];
            }
        bf16x8 af[2][4];
#pragma unroll
        for (int t = 0; t < 2; t++)
#pragma unroll
            for (int ms = 0; ms < 4; ms++) {
                int row = wm + ms * 16 + lrow + t;
                af[t][ms] = *(const bf16x8*)&Xs[row * 40 + quad * 8];
            }
#pragma unroll
        for (int t = 0; t < 2; t++)
#pragma unroll
            for (int ms = 0; ms < 4; ms++)
#pragma unroll
                for (int ns = 0; ns < 5; ns++)
                    acc[ms][ns] = __builtin_amdgcn_mfma_f32_16x16x32_bf16(
                        af[t][ms], wf[t][ns], acc[ms][ns], 0, 0, 0);
    }

#pragma unroll
    for (int ns = 0; ns < 5; ns++) {
        int o = nb * 160 + wn + ns * 16 + lrow;
        if (o >= 300) continue;
        float bo = bias[o];
#pragma unroll
        for (int ms = 0; ms < 4; ms++) {
#pragma unroll
            for (int r = 0; r < 4; r++) {
                int m = l0 + wm + ms * 16 + quad * 4 + r;
                if (m < Lout)
                    dst[((size_t)n * Lout + m) * 300 + o] = tanhf(acc[ms][ns][r] + bo);
            }
        }
    }
}

// ---------------------------------------------------------------------------
// Radix-select top-k (k largest, ties -> smallest index), output values in
// ascending original-index order. Exact lax.top_k semantics; bit-exact values.
// One block (256 thr) per row; thread t owns element indices [t*EPT,(t+1)*EPT).
// 4 passes of 8-bit radix histogram (descending) -> threshold key T + tie
// count, then stable packed prefix-scan compaction.
// ---------------------------------------------------------------------------
template <int EPT>
__global__ __launch_bounds__(256) void topk_radix_kernel(
    const float* __restrict__ src, const float* __restrict__ src2, int split_n,
    int CC, long long src_n_stride, long long src_c_stride, long long src_e_stride,
    int L, int k,
    float* __restrict__ dst, long long dst_off, long long dst_n_stride,
    long long dst_c_stride, long long dst_e_stride)
{
    __shared__ uint sbuf[257];
    __shared__ uint wtot[4];
    __shared__ uint bsel[2];
    __shared__ uint wsum[4];

    int row = blockIdx.x;
    int n = row / CC, c = row - n * CC;
    const float* sp = (split_n > 0 && n >= split_n)
                          ? src2 + (size_t)(n - split_n) * src_n_stride
                          : src + (size_t)n * src_n_stride;
    sp += (size_t)c * src_c_stride;

    int tid = threadIdx.x, lane = tid & 63, wid = tid >> 6;
    int base = tid * EPT;

    uint key[EPT];
    if (EPT == 4 && src_e_stride == 1 && base + 3 < L) {
        float4 v = *(const float4*)&sp[base];
        key[0] = fkey(v.x); key[1] = fkey(v.y);
        key[2] = fkey(v.z); key[3] = fkey(v.w);
    } else {
#pragma unroll
        for (int e = 0; e < EPT; e++) {
            int i = base + e;
            key[e] = (i < L) ? fkey(sp[(size_t)i * src_e_stride]) : 0u;
        }
    }

    uint pmask = 0, pval = 0, rem = (uint)k;
#pragma unroll
    for (int shift = 24; shift >= 0; shift -= 8) {
        sbuf[tid] = 0;
        __syncthreads();
#pragma unroll
        for (int e = 0; e < EPT; e++) {
            int i = base + e;
            if (i < L && (key[e] & pmask) == pval)
                atomicAdd(&sbuf[(key[e] >> shift) & 255], 1u);
        }
        __syncthreads();
        uint sfx = sbuf[tid];
        // wave-level inclusive suffix scan over 64 bins
#pragma unroll
        for (int off = 1; off < 64; off <<= 1) {
            uint u2 = __shfl_down(sfx, off);
            if (lane + off < 64) sfx += u2;
        }
        if (lane == 0) wtot[wid] = sfx;
        __syncthreads();
        uint hi = 0;
        for (int w = wid + 1; w < 4; w++) hi += wtot[w];
        sbuf[tid] = sfx + hi;             // cnt_ge[bin=tid]
        if (tid == 0) sbuf[256] = 0;
        __syncthreads();
        uint cg = sbuf[tid], cgn = sbuf[tid + 1];
        if (cg >= rem && cgn < rem) { bsel[0] = (uint)tid; bsel[1] = rem - cgn; }
        __syncthreads();
        pval |= bsel[0] << shift;
        pmask |= 0xFFu << shift;
        rem = bsel[1];
        __syncthreads();                  // protect bsel/sbuf before next pass
    }

    const uint T = pval;
    // stable compaction: packed (gt<<16 | eq) exclusive scan across threads
    uint gtc = 0, eqc = 0;
#pragma unroll
    for (int e = 0; e < EPT; e++) {
        int i = base + e;
        if (i < L) {
            gtc += (key[e] > T) ? 1u : 0u;
            eqc += (key[e] == T) ? 1u : 0u;
        }
    }
    uint pack = (gtc << 16) | eqc;
    uint incl = pack;
#pragma unroll
    for (int off = 1; off < 64; off <<= 1) {
        uint u2 = __shfl_up(incl, off);
        if (lane >= off) incl += u2;
    }
    uint excl = incl - pack;
    if (lane == 63) wsum[wid] = incl;
    __syncthreads();
    uint badd = 0;
    for (int w = 0; w < wid; w++) badd += wsum[w];
    excl += badd;
    uint gt_before = excl >> 16, eq_before = excl & 0xffffu;

    float* dp = dst + (size_t)dst_off + (size_t)n * dst_n_stride + (size_t)c * dst_c_stride;
#pragma unroll
    for (int e = 0; e < EPT; e++) {
        int i = base + e;
        if (i >= L) break;
        uint kk = key[e];
        if (kk > T) {
            uint pos = gt_before + (eq_before < rem ? eq_before : rem);
            dp[(size_t)pos * dst_e_stride] = kinv(kk);
            gt_before++;
        } else if (kk == T) {
            if (eq_before < rem) {
                uint pos = gt_before + eq_before;
                dp[(size_t)pos * dst_e_stride] = kinv(kk);
            }
            eq_before++;
        }
    }
}

// ---------------------------------------------------------------------------
// qt row GEMV: qtb16[r,e] = bf16( sum_d qg[r,d] * bw[d,e] ), e padded to 320.
// ---------------------------------------------------------------------------
__global__ __launch_bounds__(320) void qt_kernel(
    const float* __restrict__ qg, const float* __restrict__ bw,
    ushort_t* __restrict__ qtb16)
{
    __shared__ float rowS[300];
    int r = blockIdx.x;
    const float* gp = qg + (size_t)r * 300;
    int tid = threadIdx.x;
    for (int i = tid; i < 300; i += blockDim.x) rowS[i] = gp[i];
    __syncthreads();
    float acc = 0.f;
    if (tid < 300) {
        for (int d = 0; d < 300; d++) acc += rowS[d] * bw[d * 300 + tid];
    }
    qtb16[(size_t)r * 320 + tid] = (tid < 300) ? f2b(acc) : (ushort_t)0;
}

// ---------------------------------------------------------------------------
// MFMA M-GEMM fused with pooling (as R3).
// ---------------------------------------------------------------------------
__global__ __launch_bounds__(256) void mpool_mfma_kernel(
    const ushort_t* __restrict__ qtb16, const ushort_t* __restrict__ dgb16,
    const float* __restrict__ bb, float* __restrict__ mp)
{
    __shared__ float pool[2 * 12 * 192];

    int jb = blockIdx.x;
    int qb = blockIdx.y;
    int n  = blockIdx.z;
    int b  = n & 15;

    int tid = threadIdx.x;
    int wid = tid >> 6, lane = tid & 63;
    int wm2 = wid >> 1;
    int wm = wm2 * 48, wn = (wid & 1) * 96;
    int lrow = lane & 15, quad = lane >> 4;

    const ushort_t* Abase = qtb16 + ((size_t)b * 480 + qb * 96 + wm) * 320 + quad * 8;
    const ushort_t* Bbase = dgb16 + ((size_t)n * 960 + jb * 192 + wn) * 320 + quad * 8;

    floatx4 acc[3][6];
#pragma unroll
    for (int i = 0; i < 3; i++)
#pragma unroll
        for (int j = 0; j < 6; j++) acc[i][j] = (floatx4){0.f, 0.f, 0.f, 0.f};

#pragma unroll 2
    for (int c0 = 0; c0 < 320; c0 += 32) {
        bf16x8 af[3], bf[6];
#pragma unroll
        for (int mt = 0; mt < 3; mt++)
            af[mt] = *(const bf16x8*)&Abase[(size_t)(mt * 16 + lrow) * 320 + c0];
#pragma unroll
        for (int nt = 0; nt < 6; nt++)
            bf[nt] = *(const bf16x8*)&Bbase[(size_t)(nt * 16 + lrow) * 320 + c0];
#pragma unroll
        for (int mt = 0; mt < 3; mt++)
#pragma unroll
            for (int nt = 0; nt < 6; nt++)
                acc[mt][nt] = __builtin_amdgcn_mfma_f32_16x16x32_bf16(
                    af[mt], bf[nt], acc[mt][nt], 0, 0, 0);
    }

#pragma unroll
    for (int mt = 0; mt < 3; mt++) {
        int g = mt * 4 + quad;
#pragma unroll
        for (int nt = 0; nt < 6; nt++) {
            floatx4 a = acc[mt][nt];
            float rm = fmaxf(fmaxf(a[0], a[1]), fmaxf(a[2], a[3]));
            pool[(wm2 * 12 + g) * 192 + wn + nt * 16 + lrow] = rm;
        }
    }
    __syncthreads();

    if (tid < 64) {
        int qw = tid >> 3, jw = tid & 7;
        int slab = qw >> 2, w = qw & 3;
        float m = -INFINITY;
        const float* pp = &pool[(slab * 12 + w * 3) * 192 + jw * 24];
        for (int g = 0; g < 3; g++)
            for (int c = 0; c < 24; c++)
                m = fmaxf(m, pp[g * 192 + c]);
        float sig = 1.f / (1.f + expf(-(m + bb[0])));
        mp[(size_t)n * 1600 + (size_t)(qb * 8 + qw) * 40 + (jb * 8 + jw)] = sig;
    }
}

// ---------------------------------------------------------------------------
// Conv block: pad4 -> conv2x2(50) -> sigmoid -> pool 47->40 (H,W) -> ch-max.
// ---------------------------------------------------------------------------
__global__ __launch_bounds__(256) void convblock_kernel(
    const float* __restrict__ X, const float* __restrict__ w,
    const float* __restrict__ bias, float* __restrict__ Y)
{
    __shared__ float xp[48 * 48];
    __shared__ float ys[47 * 47];
    __shared__ float t1[40 * 47];
    __shared__ float outacc[1600];

    int n = blockIdx.x, t = threadIdx.x;
    const float* xn = X + (size_t)n * 1600;
    for (int i = t; i < 48 * 48; i += 256) {
        int r = i / 48, c = i - r * 48;
        int rr = r - 4, cc = c - 4;
        xp[i] = (rr >= 0 && rr < 40 && cc >= 0 && cc < 40) ? xn[rr * 40 + cc] : 0.f;
    }
    for (int i = t; i < 1600; i += 256) outacc[i] = -INFINITY;
    __syncthreads();

    for (int oc = 0; oc < 50; oc++) {
        float w00 = w[oc * 4 + 0], w01 = w[oc * 4 + 1];
        float w10 = w[oc * 4 + 2], w11 = w[oc * 4 + 3];
        float bo = bias[oc];
        for (int i = t; i < 47 * 47; i += 256) {
            int r = i / 47, c = i - r * 47;
            float v = xp[r * 48 + c] * w00 + xp[r * 48 + c + 1] * w01
                    + xp[(r + 1) * 48 + c] * w10 + xp[(r + 1) * 48 + c + 1] * w11 + bo;
            ys[i] = 1.f / (1.f + expf(-v));
        }
        __syncthreads();
        for (int i = t; i < 40 * 47; i += 256) {
            int r = i / 47, c = i - r * 47;
            int s = (47 * r) / 40, e = (47 * (r + 1) + 39) / 40;
            float m = ys[s * 47 + c];
            for (int x = s + 1; x < e; x++) m = fmaxf(m, ys[x * 47 + c]);
            t1[i] = m;
        }
        __syncthreads();
        for (int i = t; i < 1600; i += 256) {
            int r = i / 40, c = i - r * 40;
            int s = (47 * c) / 40, e = (47 * (c + 1) + 39) / 40;
            float m = t1[r * 47 + s];
            for (int x = s + 1; x < e; x++) m = fmaxf(m, t1[r * 47 + x]);
            outacc[i] = fmaxf(outacc[i], m);
        }
        __syncthreads();
    }
    for (int i = t; i < 1600; i += 256) Y[(size_t)n * 1600 + i] = outacc[i];
}

// ---------------------------------------------------------------------------
// Head
// ---------------------------------------------------------------------------
__global__ __launch_bounds__(64) void head_kernel(
    const float* __restrict__ feat, const float* __restrict__ lw,
    const float* __restrict__ lb, float* __restrict__ out)
{
    __shared__ float hs[40];
    int n = blockIdx.x, t = threadIdx.x;
    const float* f = feat + (size_t)n * 1600;
    if (t < 40) {
        float a = 0.f;
        for (int j = 0; j < 40; j++) a += f[t * 40 + j] * lw[j];
        hs[t] = 1.f / (1.f + expf(-(a + lb[0])));
    }
    __syncthreads();
    if (t == 0) {
        float a = 0.f;
        for (int i = 0; i < 40; i++) a += hs[i] * lw[i];
        out[n] = 1.f / (1.f + expf(-(a + lb[0])));
    }
}

// ---------------------------------------------------------------------------
extern "C" void kernel_launch(void* const* d_in, const int* in_sizes, int n_in,
                              void* d_out, int out_size, void* d_ws, size_t ws_size,
                              hipStream_t stream) {
    const float* query    = (const float*)d_in[0];
    const float* pos_doc  = (const float*)d_in[1];
    const float* neg_docs = (const float*)d_in[2];
    const float* qw1 = (const float*)d_in[3];  const float* qb1 = (const float*)d_in[4];
    const float* qw2 = (const float*)d_in[5];  const float* qb2 = (const float*)d_in[6];
    const float* qw3 = (const float*)d_in[7];  const float* qb3 = (const float*)d_in[8];
    const float* dw1 = (const float*)d_in[9];  const float* db1 = (const float*)d_in[10];
    const float* dw2 = (const float*)d_in[11]; const float* db2 = (const float*)d_in[12];
    const float* dw3 = (const float*)d_in[13]; const float* db3 = (const float*)d_in[14];
    const float* bw  = (const float*)d_in[15]; const float* bb  = (const float*)d_in[16];
    const float* mw1 = (const float*)d_in[17]; const float* mb1 = (const float*)d_in[18];
    const float* mw2 = (const float*)d_in[19]; const float* mb2 = (const float*)d_in[20];
    const float* mw3 = (const float*)d_in[21]; const float* mb3 = (const float*)d_in[22];
    const float* lw  = (const float*)d_in[23]; const float* lb  = (const float*)d_in[24];

    float* ws = (float*)d_ws;
    ushort_t* qw1b = (ushort_t*)(ws + 0);        // 2*320*1024 bf16
    ushort_t* qw2b = (ushort_t*)(ws + 327680);   // 2*320*320
    ushort_t* qw3b = (ushort_t*)(ws + 430080);
    ushort_t* dw1b = (ushort_t*)(ws + 532480);
    ushort_t* dw2b = (ushort_t*)(ws + 860160);
    ushort_t* dw3b = (ushort_t*)(ws + 962560);
    float* qg   = ws + 1064960;    // (16, 480, 300)
    float* dg   = ws + 3368960;    // (80, 960, 300)
    float* yt   = ws + 26408960;   // conv temp, max (80, 486, 300)
    // dgb16 overlaps yt (yt dead after last doc top-k)
    ushort_t* dgb16 = (ushort_t*)(ws + 26408960);   // (80,960,320) bf16
    ushort_t* qtb16 = (ushort_t*)(ws + 38696960);   // (16,480,320) bf16
    float* mp   = ws + 39925760;   // (80, 40, 40)
    float* xb2  = ws + 40053760;   // (80, 40, 40)

    // --- weight prep ---
    prep_w_kernel<<<512, 256, 0, stream>>>(qw1, qw1b, 1024, 1024);
    prep_w_kernel<<<256, 256, 0, stream>>>(qw2, qw2b, 300, 320);
    prep_w_kernel<<<256, 256, 0, stream>>>(qw3, qw3b, 300, 320);
    prep_w_kernel<<<512, 256, 0, stream>>>(dw1, dw1b, 1024, 1024);
    prep_w_kernel<<<256, 256, 0, stream>>>(dw2, dw2b, 300, 320);
    prep_w_kernel<<<256, 256, 0, stream>>>(dw3, dw3b, 300, 320);

    // ====================== query tower (qg: 239+160+80+1 = 480) ============
    topk_radix_kernel<4><<<16 * 239, 256, 0, stream>>>(
        query, nullptr, 0,
        239, 239LL * 1024, 1024, 1,
        1024, 300,
        qg, 0, 480LL * 300, 300, 1);
    {
        dim3 g(2, 2, 16);
        conv1d_mfma_kernel<<<g, 256, 0, stream>>>(
            query, nullptr, 0, 239LL * 1024, 239, 1024, 1024, 246, qw1b, qb1, yt);
    }
    topk_radix_kernel<1><<<16 * 300, 256, 0, stream>>>(
        yt, nullptr, 0,
        300, 246LL * 300, 1, 300,
        246, 160,
        qg, 239LL * 300, 480LL * 300, 1, 300);
    {
        dim3 g(2, 2, 16);
        conv1d_mfma_kernel<<<g, 256, 0, stream>>>(
            qg + 239 * 300, nullptr, 0, 480LL * 300, 160, 300, 320, 167, qw2b, qb2, yt);
    }
    topk_radix_kernel<1><<<16 * 300, 256, 0, stream>>>(
        yt, nullptr, 0,
        300, 167LL * 300, 1, 300,
        167, 80,
        qg, 399LL * 300, 480LL * 300, 1, 300);
    {
        dim3 g(2, 1, 16);
        conv1d_mfma_kernel<<<g, 256, 0, stream>>>(
            qg + 399 * 300, nullptr, 0, 480LL * 300, 80, 300, 320, 87, qw3b, qb3, yt);
    }
    topk_radix_kernel<1><<<16 * 300, 256, 0, stream>>>(
        yt, nullptr, 0,
        300, 87LL * 300, 1, 300,
        87, 1,
        qg, 479LL * 300, 480LL * 300, 1, 300);

    // ====================== doc tower (dg: 479+320+160+1 = 960) =============
    topk_radix_kernel<4><<<80 * 479, 256, 0, stream>>>(
        pos_doc, neg_docs, 16,
        479, 479LL * 1024, 1024, 1,
        1024, 300,
        dg, 0, 960LL * 300, 300, 1);
    {
        dim3 g(2, 4, 80);
        conv1d_mfma_kernel<<<g, 256, 0, stream>>>(
            pos_doc, neg_docs, 16, 479LL * 1024, 479, 1024, 1024, 486, dw1b, db1, yt);
    }
    topk_radix_kernel<2><<<80 * 300, 256, 0, stream>>>(
        yt, nullptr, 0,
        300, 486LL * 300, 1, 300,
        486, 320,
        dg, 479LL * 300, 960LL * 300, 1, 300);
    {
        dim3 g(2, 3, 80);
        conv1d_mfma_kernel<<<g, 256, 0, stream>>>(
            dg + 479 * 300, nullptr, 0, 960LL * 300, 320, 300, 320, 327, dw2b, db2, yt);
    }
    topk_radix_kernel<2><<<80 * 300, 256, 0, stream>>>(
        yt, nullptr, 0,
        300, 327LL * 300, 1, 300,
        327, 160,
        dg, 799LL * 300, 960LL * 300, 1, 300);
    {
        dim3 g(2, 2, 80);
        conv1d_mfma_kernel<<<g, 256, 0, stream>>>(
            dg + 799 * 300, nullptr, 0, 960LL * 300, 160, 300, 320, 167, dw3b, db3, yt);
    }
    topk_radix_kernel<1><<<80 * 300, 256, 0, stream>>>(
        yt, nullptr, 0,
        300, 167LL * 300, 1, 300,
        167, 1,
        dg, 959LL * 300, 960LL * 300, 1, 300);

    // ====================== similarity + pooling ============================
    // NOTE: dgb16 overlaps yt — launch only after the last doc top-k above.
    dg_to_bf16_kernel<<<80 * 960 / 4, 256, 0, stream>>>(dg, dgb16);
    qt_kernel<<<16 * 480, 320, 0, stream>>>(qg, bw, qtb16);
    {
        dim3 g(5, 5, 80);
        mpool_mfma_kernel<<<g, 256, 0, stream>>>(qtb16, dgb16, bb, mp);
    }

    // ====================== conv blocks + head ==============================
    convblock_kernel<<<80, 256, 0, stream>>>(mp, mw1, mb1, xb2);
    convblock_kernel<<<80, 256, 0, stream>>>(xb2, mw2, mb2, mp);
    convblock_kernel<<<80, 256, 0, stream>>>(mp, mw3, mb3, xb2);
    head_kernel<<<80, 64, 0, stream>>>(xb2, lw, lb, (float*)d_out);
}

// Round 5
// 2203.783 us; speedup vs baseline: 2.7611x; 1.1393x over previous
//
#include <hip/hip_runtime.h>
#include <hip/hip_bf16.h>
#include <math.h>

typedef unsigned long long ull;
typedef unsigned int uint;
typedef unsigned short ushort_t;

typedef short bf16x8 __attribute__((ext_vector_type(8)));
typedef float floatx4 __attribute__((ext_vector_type(4)));

// ---------------------------------------------------------------------------
// fp32 -> bf16 (round-to-nearest-even-ish)
// ---------------------------------------------------------------------------
__device__ inline ushort_t f2b(float f) {
    uint u = __float_as_uint(f);
    u = u + 0x7fffu + ((u >> 16) & 1u);
    return (ushort_t)(u >> 16);
}

// order-preserving bf16(bits)->uint16 map and inverse
__device__ inline uint kmap16(ushort_t u) {
    return (u & 0x8000u) ? (uint)((~u) & 0xFFFFu) : (uint)(u | 0x8000u);
}
__device__ inline ushort_t kinv16(uint k) {
    return (k & 0x8000u) ? (ushort_t)(k ^ 0x8000u) : (ushort_t)((~k) & 0xFFFFu);
}

// ---------------------------------------------------------------------------
// Prep: w (300, C, 2) fp32 -> Wb[t][n][c] bf16, n in [0,320), c in [0,Cp),
// zeros outside n<300 / c<C.
// ---------------------------------------------------------------------------
__global__ void prep_w_kernel(const float* __restrict__ w, ushort_t* __restrict__ Wb,
                              int C, int Cp) {
    int total = 2 * 320 * Cp;
    for (int i = blockIdx.x * blockDim.x + threadIdx.x; i < total;
         i += gridDim.x * blockDim.x) {
        int t = i / (320 * Cp);
        int rem = i - t * 320 * Cp;
        int n = rem / Cp, c = rem - n * Cp;
        float v = (n < 300 && c < C) ? w[((size_t)n * C + c) * 2 + t] : 0.f;
        Wb[i] = f2b(v);
    }
}

// bw (300,300) fp32 -> bwb[e][d] bf16 (320x320, zero pad)
__global__ void prep_bw_kernel(const float* __restrict__ bw, ushort_t* __restrict__ bwb) {
    int i = blockIdx.x * 256 + threadIdx.x;
    if (i >= 320 * 320) return;
    int e = i / 320, d = i - e * 320;
    bwb[i] = (e < 300 && d < 300) ? f2b(bw[d * 300 + e]) : (ushort_t)0;
}

// ---------------------------------------------------------------------------
// Input fp32 -> padded bf16: dst[n][r][1024], r=0..rows-1, value = src row
// r-4 (zero outside [0,Lin)).  Block = one (r,n), 256 thr x 4 cols.
// ---------------------------------------------------------------------------
__global__ __launch_bounds__(256) void x_pad_bf16_kernel(
    const float* __restrict__ src, const float* __restrict__ src2, int split_n,
    long long s_nstr, int Lin, ushort_t* __restrict__ dst, int rows)
{
    int r = blockIdx.x, n = blockIdx.y;
    const float* sp = (split_n > 0 && n >= split_n)
                          ? src2 + (size_t)(n - split_n) * s_nstr
                          : src + (size_t)n * s_nstr;
    int g = r - 4;
    ushort_t* dp = dst + ((size_t)n * rows + r) * 1024;
    int c = threadIdx.x * 4;
    ushort4 o = {0, 0, 0, 0};
    if (g >= 0 && g < Lin) {
        float4 v = *(const float4*)&sp[(size_t)g * 1024 + c];
        o.x = f2b(v.x); o.y = f2b(v.y); o.z = f2b(v.z); o.w = f2b(v.w);
    }
    *(ushort4*)&dp[c] = o;
}

// ---------------------------------------------------------------------------
// Barrier-free MFMA conv1d (k=2 taps) on padded bf16 input, q+d merged.
// Block: MT=32 rows x 320 N, 4 waves N-split (wave 32x80 = 2x5 MFMAs/tap).
// A/B fragments straight from global. Output: yt bf16 [96][488][320], tanh.
// ---------------------------------------------------------------------------
template <int CP>
__global__ __launch_bounds__(256) void conv_mfma2_kernel(
    const ushort_t* __restrict__ xq, long long xq_nstr,
    const ushort_t* __restrict__ xd, long long xd_nstr,
    const ushort_t* __restrict__ Wq, const ushort_t* __restrict__ Wd,
    const float* __restrict__ bq, const float* __restrict__ bd,
    int Lout_q, int Lout_d, int mtiles_q,
    ushort_t* __restrict__ yt)
{
    int mt = blockIdx.x, n = blockIdx.y;
    bool isq = (n < 16);
    if (isq && mt >= mtiles_q) return;
    const ushort_t* x = isq ? xq + (size_t)n * xq_nstr
                            : xd + (size_t)(n - 16) * xd_nstr;
    const ushort_t* W = isq ? Wq : Wd;
    const float* bias = isq ? bq : bd;
    int Lout = isq ? Lout_q : Lout_d;
    int l0 = mt * 32;

    int tid = threadIdx.x, wid = tid >> 6, lane = tid & 63;
    int wn = wid * 80;
    int lrow = lane & 15, quad = lane >> 4;

    const ushort_t* Abase = x + (size_t)(l0 + lrow) * CP + quad * 8;
    const ushort_t* Bbase = W + (size_t)(wn + lrow) * CP + quad * 8;

    floatx4 acc[2][5];
#pragma unroll
    for (int i = 0; i < 2; i++)
#pragma unroll
        for (int j = 0; j < 5; j++) acc[i][j] = (floatx4){0.f, 0.f, 0.f, 0.f};

#pragma unroll 4
    for (int c0 = 0; c0 < CP; c0 += 32) {
        bf16x8 af[2][2], bfr[2][5];
#pragma unroll
        for (int t = 0; t < 2; t++) {
#pragma unroll
            for (int ms = 0; ms < 2; ms++)
                af[t][ms] = *(const bf16x8*)&Abase[(size_t)(ms * 16 + t) * CP + c0];
#pragma unroll
            for (int ns = 0; ns < 5; ns++)
                bfr[t][ns] = *(const bf16x8*)&Bbase[(size_t)(t * 320 + ns * 16) * CP + c0];
        }
#pragma unroll
        for (int t = 0; t < 2; t++)
#pragma unroll
            for (int ms = 0; ms < 2; ms++)
#pragma unroll
                for (int ns = 0; ns < 5; ns++)
                    acc[ms][ns] = __builtin_amdgcn_mfma_f32_16x16x32_bf16(
                        af[t][ms], bfr[t][ns], acc[ms][ns], 0, 0, 0);
    }

    ushort_t* yp = yt + (size_t)n * 488 * 320;
#pragma unroll
    for (int ns = 0; ns < 5; ns++) {
        int o = wn + ns * 16 + lrow;
        if (o >= 300) continue;
        float bo = bias[o];
#pragma unroll
        for (int ms = 0; ms < 2; ms++)
#pragma unroll
            for (int r = 0; r < 4; r++) {
                int l = l0 + ms * 16 + quad * 4 + r;
                if (l < Lout)
                    yp[(size_t)l * 320 + o] = f2b(tanhf(acc[ms][ns][r] + bo));
            }
    }
}

// ---------------------------------------------------------------------------
// 2-pass radix-select top-k on bf16 keys (k largest, ties -> smallest index),
// outputs in ascending original-index order (bit-exact bf16 values).
// Dual output (out2 optional).
// ---------------------------------------------------------------------------
template <int EPT>
__global__ __launch_bounds__(256) void topk16_kernel(
    const ushort_t* __restrict__ src, int CC,
    long long s_n, long long s_c, long long s_e,
    int L, int k,
    ushort_t* __restrict__ out1, long long o1_off, long long o1_n,
    long long o1_c, long long o1_e,
    ushort_t* __restrict__ out2, long long o2_off, long long o2_n,
    long long o2_c, long long o2_e)
{
    __shared__ uint sbuf[257];
    __shared__ uint wtot[4];
    __shared__ uint bsel[2];
    __shared__ uint wsum[4];

    int row = blockIdx.x;
    int n = row / CC, c = row - n * CC;
    const ushort_t* sp = src + (size_t)n * s_n + (size_t)c * s_c;

    int tid = threadIdx.x, lane = tid & 63, wid = tid >> 6;
    int base = tid * EPT;

    uint key[EPT];
    if (EPT == 4 && s_e == 1) {          // L == 1024 contiguous case
        ushort4 v = *(const ushort4*)&sp[base];
        key[0] = kmap16(v.x); key[1] = kmap16(v.y);
        key[2] = kmap16(v.z); key[3] = kmap16(v.w);
    } else {
#pragma unroll
        for (int e = 0; e < EPT; e++) {
            int i = base + e;
            key[e] = (i < L) ? kmap16(sp[(size_t)i * s_e]) : 0u;
        }
    }

    uint pmask = 0, pval = 0, rem = (uint)k;
#pragma unroll
    for (int shift = 8; shift >= 0; shift -= 8) {
        sbuf[tid] = 0;
        __syncthreads();
#pragma unroll
        for (int e = 0; e < EPT; e++) {
            int i = base + e;
            if (i < L && (key[e] & pmask) == pval)
                atomicAdd(&sbuf[(key[e] >> shift) & 255], 1u);
        }
        __syncthreads();
        uint sfx = sbuf[tid];
#pragma unroll
        for (int off = 1; off < 64; off <<= 1) {
            uint u2 = __shfl_down(sfx, off);
            if (lane + off < 64) sfx += u2;
        }
        if (lane == 0) wtot[wid] = sfx;
        __syncthreads();
        uint hi = 0;
        for (int w = wid + 1; w < 4; w++) hi += wtot[w];
        sbuf[tid] = sfx + hi;             // cnt_ge[bin=tid]
        if (tid == 0) sbuf[256] = 0;
        __syncthreads();
        uint cg = sbuf[tid], cgn = sbuf[tid + 1];
        if (cg >= rem && cgn < rem) { bsel[0] = (uint)tid; bsel[1] = rem - cgn; }
        __syncthreads();
        pval |= bsel[0] << shift;
        pmask |= 0xFFu << shift;
        rem = bsel[1];
        __syncthreads();
    }

    const uint T = pval;
    uint gtc = 0, eqc = 0;
#pragma unroll
    for (int e = 0; e < EPT; e++) {
        int i = base + e;
        if (i < L) {
            gtc += (key[e] > T) ? 1u : 0u;
            eqc += (key[e] == T) ? 1u : 0u;
        }
    }
    uint pack = (gtc << 16) | eqc;
    uint incl = pack;
#pragma unroll
    for (int off = 1; off < 64; off <<= 1) {
        uint u2 = __shfl_up(incl, off);
        if (lane >= off) incl += u2;
    }
    uint excl = incl - pack;
    if (lane == 63) wsum[wid] = incl;
    __syncthreads();
    uint badd = 0;
    for (int w = 0; w < wid; w++) badd += wsum[w];
    excl += badd;
    uint gt_before = excl >> 16, eq_before = excl & 0xffffu;

    ushort_t* dp1 = out1 + (size_t)o1_off + (size_t)n * o1_n + (size_t)c * o1_c;
    ushort_t* dp2 = out2 ? out2 + (size_t)o2_off + (size_t)n * o2_n + (size_t)c * o2_c
                         : (ushort_t*)0;
#pragma unroll
    for (int e = 0; e < EPT; e++) {
        int i = base + e;
        if (i >= L) break;
        uint kk = key[e];
        if (kk > T) {
            uint pos = gt_before + (eq_before < rem ? eq_before : rem);
            ushort_t v = kinv16(kk);
            dp1[(size_t)pos * o1_e] = v;
            if (dp2) dp2[(size_t)pos * o2_e] = v;
            gt_before++;
        } else if (kk == T) {
            if (eq_before < rem) {
                uint pos = gt_before + eq_before;
                ushort_t v = kinv16(kk);
                dp1[(size_t)pos * o1_e] = v;
                if (dp2) dp2[(size_t)pos * o2_e] = v;
            }
            eq_before++;
        }
    }
}

// ---------------------------------------------------------------------------
// qt GEMM: qtb[b,m,e] = bf16( sum_d qgb[b,m,d] * bwb[e,d] ).  M-tile 48,
// 4 waves N-split 80 (3x5 MFMAs), K=320, barrier-free.
// ---------------------------------------------------------------------------
__global__ __launch_bounds__(256) void qt_mfma_kernel(
    const ushort_t* __restrict__ qgb, const ushort_t* __restrict__ bwb,
    ushort_t* __restrict__ qtb)
{
    int mt = blockIdx.x, b = blockIdx.y;
    int tid = threadIdx.x, wid = tid >> 6, lane = tid & 63;
    int wn = wid * 80, lrow = lane & 15, quad = lane >> 4;

    const ushort_t* A = qgb + ((size_t)b * 480 + mt * 48 + lrow) * 320 + quad * 8;
    const ushort_t* B = bwb + (size_t)(wn + lrow) * 320 + quad * 8;

    floatx4 acc[3][5];
#pragma unroll
    for (int i = 0; i < 3; i++)
#pragma unroll
        for (int j = 0; j < 5; j++) acc[i][j] = (floatx4){0.f, 0.f, 0.f, 0.f};

#pragma unroll 5
    for (int c0 = 0; c0 < 320; c0 += 32) {
        bf16x8 af[3], bfr[5];
#pragma unroll
        for (int ms = 0; ms < 3; ms++)
            af[ms] = *(const bf16x8*)&A[(size_t)(ms * 16) * 320 + c0];
#pragma unroll
        for (int ns = 0; ns < 5; ns++)
            bfr[ns] = *(const bf16x8*)&B[(size_t)(ns * 16) * 320 + c0];
#pragma unroll
        for (int ms = 0; ms < 3; ms++)
#pragma unroll
            for (int ns = 0; ns < 5; ns++)
                acc[ms][ns] = __builtin_amdgcn_mfma_f32_16x16x32_bf16(
                    af[ms], bfr[ns], acc[ms][ns], 0, 0, 0);
    }

    ushort_t* out = qtb + ((size_t)b * 480 + mt * 48) * 320;
#pragma unroll
    for (int ms = 0; ms < 3; ms++)
#pragma unroll
        for (int ns = 0; ns < 5; ns++)
#pragma unroll
            for (int r = 0; r < 4; r++)
                out[(size_t)(ms * 16 + quad * 4 + r) * 320 + wn + ns * 16 + lrow] =
                    f2b(acc[ms][ns][r]);
}

// ---------------------------------------------------------------------------
// MFMA M-GEMM fused with pooling (unchanged from R3/R4).
// ---------------------------------------------------------------------------
__global__ __launch_bounds__(256) void mpool_mfma_kernel(
    const ushort_t* __restrict__ qtb16, const ushort_t* __restrict__ dgb16,
    const float* __restrict__ bb, float* __restrict__ mp)
{
    __shared__ float pool[2 * 12 * 192];

    int jb = blockIdx.x;
    int qb = blockIdx.y;
    int n  = blockIdx.z;
    int b  = n & 15;

    int tid = threadIdx.x;
    int wid = tid >> 6, lane = tid & 63;
    int wm2 = wid >> 1;
    int wm = wm2 * 48, wn = (wid & 1) * 96;
    int lrow = lane & 15, quad = lane >> 4;

    const ushort_t* Abase = qtb16 + ((size_t)b * 480 + qb * 96 + wm) * 320 + quad * 8;
    const ushort_t* Bbase = dgb16 + ((size_t)n * 960 + jb * 192 + wn) * 320 + quad * 8;

    floatx4 acc[3][6];
#pragma unroll
    for (int i = 0; i < 3; i++)
#pragma unroll
        for (int j = 0; j < 6; j++) acc[i][j] = (floatx4){0.f, 0.f, 0.f, 0.f};

#pragma unroll 2
    for (int c0 = 0; c0 < 320; c0 += 32) {
        bf16x8 af[3], bfr[6];
#pragma unroll
        for (int mt = 0; mt < 3; mt++)
            af[mt] = *(const bf16x8*)&Abase[(size_t)(mt * 16 + lrow) * 320 + c0];
#pragma unroll
        for (int nt = 0; nt < 6; nt++)
            bfr[nt] = *(const bf16x8*)&Bbase[(size_t)(nt * 16 + lrow) * 320 + c0];
#pragma unroll
        for (int mt = 0; mt < 3; mt++)
#pragma unroll
            for (int nt = 0; nt < 6; nt++)
                acc[mt][nt] = __builtin_amdgcn_mfma_f32_16x16x32_bf16(
                    af[mt], bfr[nt], acc[mt][nt], 0, 0, 0);
    }

#pragma unroll
    for (int mt = 0; mt < 3; mt++) {
        int g = mt * 4 + quad;
#pragma unroll
        for (int nt = 0; nt < 6; nt++) {
            floatx4 a = acc[mt][nt];
            float rm = fmaxf(fmaxf(a[0], a[1]), fmaxf(a[2], a[3]));
            pool[(wm2 * 12 + g) * 192 + wn + nt * 16 + lrow] = rm;
        }
    }
    __syncthreads();

    if (tid < 64) {
        int qw = tid >> 3, jw = tid & 7;
        int slab = qw >> 2, w = qw & 3;
        float m = -INFINITY;
        const float* pp = &pool[(slab * 12 + w * 3) * 192 + jw * 24];
        for (int g = 0; g < 3; g++)
            for (int cc = 0; cc < 24; cc++)
                m = fmaxf(m, pp[g * 192 + cc]);
        float sig = 1.f / (1.f + expf(-(m + bb[0])));
        mp[(size_t)n * 1600 + (size_t)(qb * 8 + qw) * 40 + (jb * 8 + jw)] = sig;
    }
}

// ---------------------------------------------------------------------------
// Conv block: pad4 -> conv2x2(50) -> sigmoid -> pool 47->40 (H,W) -> ch-max.
// ---------------------------------------------------------------------------
__global__ __launch_bounds__(256) void convblock_kernel(
    const float* __restrict__ X, const float* __restrict__ w,
    const float* __restrict__ bias, float* __restrict__ Y)
{
    __shared__ float xp[48 * 48];
    __shared__ float ys[47 * 47];
    __shared__ float t1[40 * 47];
    __shared__ float outacc[1600];

    int n = blockIdx.x, t = threadIdx.x;
    const float* xn = X + (size_t)n * 1600;
    for (int i = t; i < 48 * 48; i += 256) {
        int r = i / 48, c = i - r * 48;
        int rr = r - 4, cc = c - 4;
        xp[i] = (rr >= 0 && rr < 40 && cc >= 0 && cc < 40) ? xn[rr * 40 + cc] : 0.f;
    }
    for (int i = t; i < 1600; i += 256) outacc[i] = -INFINITY;
    __syncthreads();

    for (int oc = 0; oc < 50; oc++) {
        float w00 = w[oc * 4 + 0], w01 = w[oc * 4 + 1];
        float w10 = w[oc * 4 + 2], w11 = w[oc * 4 + 3];
        float bo = bias[oc];
        for (int i = t; i < 47 * 47; i += 256) {
            int r = i / 47, c = i - r * 47;
            float v = xp[r * 48 + c] * w00 + xp[r * 48 + c + 1] * w01
                    + xp[(r + 1) * 48 + c] * w10 + xp[(r + 1) * 48 + c + 1] * w11 + bo;
            ys[i] = 1.f / (1.f + expf(-v));
        }
        __syncthreads();
        for (int i = t; i < 40 * 47; i += 256) {
            int r = i / 47, c = i - r * 47;
            int s = (47 * r) / 40, e = (47 * (r + 1) + 39) / 40;
            float m = ys[s * 47 + c];
            for (int x = s + 1; x < e; x++) m = fmaxf(m, ys[x * 47 + c]);
            t1[i] = m;
        }
        __syncthreads();
        for (int i = t; i < 1600; i += 256) {
            int r = i / 40, c = i - r * 40;
            int s = (47 * c) / 40, e = (47 * (c + 1) + 39) / 40;
            float m = t1[r * 47 + s];
            for (int x = s + 1; x < e; x++) m = fmaxf(m, t1[r * 47 + x]);
            outacc[i] = fmaxf(outacc[i], m);
        }
        __syncthreads();
    }
    for (int i = t; i < 1600; i += 256) Y[(size_t)n * 1600 + i] = outacc[i];
}

// ---------------------------------------------------------------------------
// Head
// ---------------------------------------------------------------------------
__global__ __launch_bounds__(64) void head_kernel(
    const float* __restrict__ feat, const float* __restrict__ lw,
    const float* __restrict__ lb, float* __restrict__ out)
{
    __shared__ float hs[40];
    int n = blockIdx.x, t = threadIdx.x;
    const float* f = feat + (size_t)n * 1600;
    if (t < 40) {
        float a = 0.f;
        for (int j = 0; j < 40; j++) a += f[t * 40 + j] * lw[j];
        hs[t] = 1.f / (1.f + expf(-(a + lb[0])));
    }
    __syncthreads();
    if (t == 0) {
        float a = 0.f;
        for (int i = 0; i < 40; i++) a += hs[i] * lw[i];
        out[n] = 1.f / (1.f + expf(-(a + lb[0])));
    }
}

// ---------------------------------------------------------------------------
extern "C" void kernel_launch(void* const* d_in, const int* in_sizes, int n_in,
                              void* d_out, int out_size, void* d_ws, size_t ws_size,
                              hipStream_t stream) {
    const float* query    = (const float*)d_in[0];
    const float* pos_doc  = (const float*)d_in[1];
    const float* neg_docs = (const float*)d_in[2];
    const float* qw1 = (const float*)d_in[3];  const float* qb1 = (const float*)d_in[4];
    const float* qw2 = (const float*)d_in[5];  const float* qb2 = (const float*)d_in[6];
    const float* qw3 = (const float*)d_in[7];  const float* qb3 = (const float*)d_in[8];
    const float* dw1 = (const float*)d_in[9];  const float* db1 = (const float*)d_in[10];
    const float* dw2 = (const float*)d_in[11]; const float* db2 = (const float*)d_in[12];
    const float* dw3 = (const float*)d_in[13]; const float* db3 = (const float*)d_in[14];
    const float* bw  = (const float*)d_in[15]; const float* bb  = (const float*)d_in[16];
    const float* mw1 = (const float*)d_in[17]; const float* mb1 = (const float*)d_in[18];
    const float* mw2 = (const float*)d_in[19]; const float* mb2 = (const float*)d_in[20];
    const float* mw3 = (const float*)d_in[21]; const float* mb3 = (const float*)d_in[22];
    const float* lw  = (const float*)d_in[23]; const float* lb  = (const float*)d_in[24];

    float* ws = (float*)d_ws;
    // ---- layout (float offsets) ----
    ushort_t* qw1b  = (ushort_t*)(ws + 0);          // 2*320*1024 bf16
    ushort_t* qw2b  = (ushort_t*)(ws + 327680);     // 2*320*320
    ushort_t* qw3b  = (ushort_t*)(ws + 430080);
    ushort_t* dw1b  = (ushort_t*)(ws + 532480);
    ushort_t* dw2b  = (ushort_t*)(ws + 860160);
    ushort_t* dw3b  = (ushort_t*)(ws + 962560);
    ushort_t* bwb   = (ushort_t*)(ws + 1064960);    // 320*320
    ushort_t* qgb16 = (ushort_t*)(ws + 1116160);    // (16,480,320)
    ushort_t* dgb16 = (ushort_t*)(ws + 2344960);    // (80,960,320)
    ushort_t* yt    = (ushort_t*)(ws + 14632960);   // (96,488,320)
    // qxb region (dead after conv1): qxb / then p1q,p2q
    ushort_t* qxb   = (ushort_t*)(ws + 22128640);   // (16,264,1024)
    ushort_t* p1q   = (ushort_t*)(ws + 22128640);   // (16,200,320)
    ushort_t* p2q   = (ushort_t*)(ws + 22640640);   // (16,104,320)
    // dxb region (dead after conv1): dxb / then p1d,p2d,qtb16,mp,xb2
    ushort_t* dxb   = (ushort_t*)(ws + 24291328);   // (80,520,1024)
    ushort_t* p1d   = (ushort_t*)(ws + 24291328);   // (80,360,320)
    ushort_t* p2d   = (ushort_t*)(ws + 28899328);   // (80,200,320)
    ushort_t* qtb16 = (ushort_t*)(ws + 31459328);   // (16,480,320)
    float*    mp    = ws + 32688128;                // (80,40,40)
    float*    xb2   = ws + 32816128;                // (80,40,40)

    // ---- weight prep ----
    prep_w_kernel<<<512, 256, 0, stream>>>(qw1, qw1b, 1024, 1024);
    prep_w_kernel<<<256, 256, 0, stream>>>(qw2, qw2b, 300, 320);
    prep_w_kernel<<<256, 256, 0, stream>>>(qw3, qw3b, 300, 320);
    prep_w_kernel<<<512, 256, 0, stream>>>(dw1, dw1b, 1024, 1024);
    prep_w_kernel<<<256, 256, 0, stream>>>(dw2, dw2b, 300, 320);
    prep_w_kernel<<<256, 256, 0, stream>>>(dw3, dw3b, 300, 320);
    prep_bw_kernel<<<400, 256, 0, stream>>>(bw, bwb);

    // ---- input convert to padded bf16 ----
    {
        dim3 g(264, 16);
        x_pad_bf16_kernel<<<g, 256, 0, stream>>>(query, nullptr, 0,
                                                 239LL * 1024, 239, qxb, 264);
    }
    {
        dim3 g(520, 80);
        x_pad_bf16_kernel<<<g, 256, 0, stream>>>(pos_doc, neg_docs, 16,
                                                 479LL * 1024, 479, dxb, 520);
    }

    // ---- g0 top-ks (read padded inputs, rows shifted by +4) ----
    topk16_kernel<4><<<16 * 239, 256, 0, stream>>>(
        qxb + 4 * 1024, 239, 264LL * 1024, 1024, 1, 1024, 300,
        qgb16, 0, 480LL * 320, 320, 1,
        nullptr, 0, 0, 0, 0);
    topk16_kernel<4><<<80 * 479, 256, 0, stream>>>(
        dxb + 4 * 1024, 479, 520LL * 1024, 1024, 1, 1024, 300,
        dgb16, 0, 960LL * 320, 320, 1,
        nullptr, 0, 0, 0, 0);

    // ---- conv1 (merged q+d) ----
    {
        dim3 g(16, 96);
        conv_mfma2_kernel<1024><<<g, 256, 0, stream>>>(
            qxb, 264LL * 1024, dxb, 520LL * 1024,
            qw1b, dw1b, qb1, db1, 246, 486, 8, yt);
    }

    // ---- zero conv2/3 input pads (regions free only after conv1) ----
    hipMemsetAsync(p1q, 0, 16 * 200 * 320 * 2, stream);
    hipMemsetAsync(p2q, 0, 16 * 104 * 320 * 2, stream);
    hipMemsetAsync(p1d, 0, (size_t)80 * 360 * 320 * 2, stream);
    hipMemsetAsync(p2d, 0, (size_t)80 * 200 * 320 * 2, stream);

    // ---- p1 top-ks ----
    topk16_kernel<1><<<16 * 300, 256, 0, stream>>>(
        yt, 300, 488LL * 320, 1, 320, 246, 160,
        qgb16, 239LL * 320, 480LL * 320, 1, 320,
        p1q, 4LL * 320, 200LL * 320, 1, 320);
    topk16_kernel<2><<<80 * 300, 256, 0, stream>>>(
        yt + (size_t)16 * 488 * 320, 300, 488LL * 320, 1, 320, 486, 320,
        dgb16, 479LL * 320, 960LL * 320, 1, 320,
        p1d, 4LL * 320, 360LL * 320, 1, 320);

    // ---- conv2 ----
    {
        dim3 g(11, 96);
        conv_mfma2_kernel<320><<<g, 256, 0, stream>>>(
            p1q, 200LL * 320, p1d, 360LL * 320,
            qw2b, dw2b, qb2, db2, 167, 327, 6, yt);
    }

    // ---- p2 top-ks ----
    topk16_kernel<1><<<16 * 300, 256, 0, stream>>>(
        yt, 300, 488LL * 320, 1, 320, 167, 80,
        qgb16, 399LL * 320, 480LL * 320, 1, 320,
        p2q, 4LL * 320, 104LL * 320, 1, 320);
    topk16_kernel<2><<<80 * 300, 256, 0, stream>>>(
        yt + (size_t)16 * 488 * 320, 300, 488LL * 320, 1, 320, 327, 160,
        dgb16, 799LL * 320, 960LL * 320, 1, 320,
        p2d, 4LL * 320, 200LL * 320, 1, 320);

    // ---- conv3 ----
    {
        dim3 g(6, 96);
        conv_mfma2_kernel<320><<<g, 256, 0, stream>>>(
            p2q, 104LL * 320, p2d, 200LL * 320,
            qw3b, dw3b, qb3, db3, 87, 167, 3, yt);
    }

    // ---- p3 top-ks ----
    topk16_kernel<1><<<16 * 300, 256, 0, stream>>>(
        yt, 300, 488LL * 320, 1, 320, 87, 1,
        qgb16, 479LL * 320, 480LL * 320, 1, 320,
        nullptr, 0, 0, 0, 0);
    topk16_kernel<1><<<80 * 300, 256, 0, stream>>>(
        yt + (size_t)16 * 488 * 320, 300, 488LL * 320, 1, 320, 167, 1,
        dgb16, 959LL * 320, 960LL * 320, 1, 320,
        nullptr, 0, 0, 0, 0);

    // ---- qt GEMM + fused similarity/pool ----
    {
        dim3 g(10, 16);
        qt_mfma_kernel<<<g, 256, 0, stream>>>(qgb16, bwb, qtb16);
    }
    {
        dim3 g(5, 5, 80);
        mpool_mfma_kernel<<<g, 256, 0, stream>>>(qtb16, dgb16, bb, mp);
    }

    // ---- conv blocks + head ----
    convblock_kernel<<<80, 256, 0, stream>>>(mp, mw1, mb1, xb2);
    convblock_kernel<<<80, 256, 0, stream>>>(xb2, mw2, mb2, mp);
    convblock_kernel<<<80, 256, 0, stream>>>(mp, mw3, mb3, xb2);
    head_kernel<<<80, 64, 0, stream>>>(xb2, lw, lb, (float*)d_out);
}

// Round 6
// 2109.014 us; speedup vs baseline: 2.8852x; 1.0449x over previous
//
#include <hip/hip_runtime.h>
#include <hip/hip_bf16.h>
#include <math.h>

typedef unsigned long long ull;
typedef unsigned int uint;
typedef unsigned short ushort_t;

typedef short bf16x8 __attribute__((ext_vector_type(8)));
typedef float floatx4 __attribute__((ext_vector_type(4)));

// ---------------------------------------------------------------------------
// fp32 -> bf16 (round-to-nearest-even-ish)
// ---------------------------------------------------------------------------
__device__ inline ushort_t f2b(float f) {
    uint u = __float_as_uint(f);
    u = u + 0x7fffu + ((u >> 16) & 1u);
    return (ushort_t)(u >> 16);
}

// order-preserving bf16(bits)->uint16 map and inverse
__device__ inline uint kmap16(ushort_t u) {
    return (u & 0x8000u) ? (uint)((~u) & 0xFFFFu) : (uint)(u | 0x8000u);
}
__device__ inline ushort_t kinv16(uint k) {
    return (k & 0x8000u) ? (ushort_t)(k ^ 0x8000u) : (ushort_t)((~k) & 0xFFFFu);
}

// ---------------------------------------------------------------------------
// Prep: w (300, C, 2) fp32 -> Wb2[n][t*CPAD + c] bf16 (im2col layout),
// n in [0,320), zeros for n>=300 or c>=C.  Total 320 * 2*CPAD entries.
// ---------------------------------------------------------------------------
__global__ void prep_w2_kernel(const float* __restrict__ w, ushort_t* __restrict__ Wb,
                               int C, int CPAD) {
    int total = 320 * 2 * CPAD;
    for (int i = blockIdx.x * blockDim.x + threadIdx.x; i < total;
         i += gridDim.x * blockDim.x) {
        int n = i / (2 * CPAD);
        int rem = i - n * 2 * CPAD;       // t*CPAD + c
        int t = rem / CPAD, c = rem - t * CPAD;
        float v = (n < 300 && c < C) ? w[((size_t)n * C + c) * 2 + t] : 0.f;
        Wb[i] = f2b(v);
    }
}

// bw (300,300) fp32 -> bwb[e][d] bf16 (320x320, zero pad)
__global__ void prep_bw_kernel(const float* __restrict__ bw, ushort_t* __restrict__ bwb) {
    int i = blockIdx.x * 256 + threadIdx.x;
    if (i >= 320 * 320) return;
    int e = i / 320, d = i - e * 320;
    bwb[i] = (e < 300 && d < 300) ? f2b(bw[d * 300 + e]) : (ushort_t)0;
}

// ---------------------------------------------------------------------------
// Input fp32 -> padded bf16: dst[n][r][1024], value = src row r-4 (zero pad).
// ---------------------------------------------------------------------------
__global__ __launch_bounds__(256) void x_pad_bf16_kernel(
    const float* __restrict__ src, const float* __restrict__ src2, int split_n,
    long long s_nstr, int Lin, ushort_t* __restrict__ dst, int rows)
{
    int r = blockIdx.x, n = blockIdx.y;
    const float* sp = (split_n > 0 && n >= split_n)
                          ? src2 + (size_t)(n - split_n) * s_nstr
                          : src + (size_t)n * s_nstr;
    int g = r - 4;
    ushort_t* dp = dst + ((size_t)n * rows + r) * 1024;
    int c = threadIdx.x * 4;
    ushort4 o = {0, 0, 0, 0};
    if (g >= 0 && g < Lin) {
        float4 v = *(const float4*)&sp[(size_t)g * 1024 + c];
        o.x = f2b(v.x); o.y = f2b(v.y); o.z = f2b(v.z); o.w = f2b(v.w);
    }
    *(ushort4*)&dp[c] = o;
}

// ---------------------------------------------------------------------------
// Barrier-free im2col MFMA conv GEMM, q+d merged, register double-buffered.
// A row l = x + l*CP (length 2*CP, rows contiguous => im2col is free).
// B = Wb2 [320][2*CP].  Block tile 128M x 160N (grid.y=2), 4 waves 2x2,
// wave 64x80 (4x5 MFMAs).  out yt[n][l][320] = bf16(tanh(acc + bias)).
// ---------------------------------------------------------------------------
template <int CP>
__global__ __launch_bounds__(256, 2) void conv_gemm_kernel(
    const ushort_t* __restrict__ xq, long long xq_nstr,
    const ushort_t* __restrict__ xd, long long xd_nstr,
    const ushort_t* __restrict__ Wq, const ushort_t* __restrict__ Wd,
    const float* __restrict__ bq, const float* __restrict__ bd,
    int Lout_q, int Lout_d, int mtiles_q,
    ushort_t* __restrict__ yt)
{
    constexpr int K = 2 * CP;
    constexpr int KITER = K / 32;       // 64 (conv1) / 20 (conv2,3) — even
    int mt = blockIdx.x, nb = blockIdx.y, n = blockIdx.z;
    bool isq = (n < 16);
    if (isq && mt >= mtiles_q) return;
    const ushort_t* x = isq ? xq + (size_t)n * xq_nstr
                            : xd + (size_t)(n - 16) * xd_nstr;
    const ushort_t* W = isq ? Wq : Wd;
    const float* bias = isq ? bq : bd;
    int Lout = isq ? Lout_q : Lout_d;
    int l0 = mt * 128;

    int tid = threadIdx.x, wid = tid >> 6, lane = tid & 63;
    int wm = (wid & 1) * 64, wn = (wid >> 1) * 80;
    int lrow = lane & 15, quad = lane >> 4;

    const ushort_t* A = x + (size_t)(l0 + wm + lrow) * CP + quad * 8;
    const ushort_t* B = W + (size_t)(nb * 160 + wn + lrow) * K + quad * 8;

    floatx4 acc[4][5];
#pragma unroll
    for (int i = 0; i < 4; i++)
#pragma unroll
        for (int j = 0; j < 5; j++) acc[i][j] = (floatx4){0.f, 0.f, 0.f, 0.f};

    bf16x8 afA[4], bfA[5], afB[4], bfB[5];
#pragma unroll
    for (int ms = 0; ms < 4; ms++)
        afA[ms] = *(const bf16x8*)&A[(size_t)(ms * 16) * CP];
#pragma unroll
    for (int ns = 0; ns < 5; ns++)
        bfA[ns] = *(const bf16x8*)&B[(size_t)(ns * 16) * K];

    for (int c = 0; c < KITER; c += 2) {
        int k1 = (c + 1) * 32;
#pragma unroll
        for (int ms = 0; ms < 4; ms++)
            afB[ms] = *(const bf16x8*)&A[(size_t)(ms * 16) * CP + k1];
#pragma unroll
        for (int ns = 0; ns < 5; ns++)
            bfB[ns] = *(const bf16x8*)&B[(size_t)(ns * 16) * K + k1];
#pragma unroll
        for (int ms = 0; ms < 4; ms++)
#pragma unroll
            for (int ns = 0; ns < 5; ns++)
                acc[ms][ns] = __builtin_amdgcn_mfma_f32_16x16x32_bf16(
                    afA[ms], bfA[ns], acc[ms][ns], 0, 0, 0);
        int k2 = (c + 2 < KITER) ? (c + 2) * 32 : 0;
#pragma unroll
        for (int ms = 0; ms < 4; ms++)
            afA[ms] = *(const bf16x8*)&A[(size_t)(ms * 16) * CP + k2];
#pragma unroll
        for (int ns = 0; ns < 5; ns++)
            bfA[ns] = *(const bf16x8*)&B[(size_t)(ns * 16) * K + k2];
#pragma unroll
        for (int ms = 0; ms < 4; ms++)
#pragma unroll
            for (int ns = 0; ns < 5; ns++)
                acc[ms][ns] = __builtin_amdgcn_mfma_f32_16x16x32_bf16(
                    afB[ms], bfB[ns], acc[ms][ns], 0, 0, 0);
    }

    ushort_t* yp = yt + (size_t)n * 488 * 320;
#pragma unroll
    for (int ns = 0; ns < 5; ns++) {
        int o = nb * 160 + wn + ns * 16 + lrow;
        if (o >= 300) continue;
        float bo = bias[o];
#pragma unroll
        for (int ms = 0; ms < 4; ms++)
#pragma unroll
            for (int r = 0; r < 4; r++) {
                int l = l0 + wm + ms * 16 + quad * 4 + r;
                if (l < Lout)
                    yp[(size_t)l * 320 + o] = f2b(tanhf(acc[ms][ns][r] + bo));
            }
    }
}

// ---------------------------------------------------------------------------
// 2-pass radix-select top-k on bf16 keys (k largest, ties -> smallest index),
// outputs in ascending original-index order (bit-exact bf16 values).
// ---------------------------------------------------------------------------
template <int EPT>
__global__ __launch_bounds__(256) void topk16_kernel(
    const ushort_t* __restrict__ src, int CC,
    long long s_n, long long s_c, long long s_e,
    int L, int k,
    ushort_t* __restrict__ out1, long long o1_off, long long o1_n,
    long long o1_c, long long o1_e,
    ushort_t* __restrict__ out2, long long o2_off, long long o2_n,
    long long o2_c, long long o2_e)
{
    __shared__ uint sbuf[257];
    __shared__ uint wtot[4];
    __shared__ uint bsel[2];
    __shared__ uint wsum[4];

    int row = blockIdx.x;
    int n = row / CC, c = row - n * CC;
    const ushort_t* sp = src + (size_t)n * s_n + (size_t)c * s_c;

    int tid = threadIdx.x, lane = tid & 63, wid = tid >> 6;
    int base = tid * EPT;

    uint key[EPT];
    if (EPT == 4 && s_e == 1) {
        ushort4 v = *(const ushort4*)&sp[base];
        key[0] = kmap16(v.x); key[1] = kmap16(v.y);
        key[2] = kmap16(v.z); key[3] = kmap16(v.w);
    } else {
#pragma unroll
        for (int e = 0; e < EPT; e++) {
            int i = base + e;
            key[e] = (i < L) ? kmap16(sp[(size_t)i * s_e]) : 0u;
        }
    }

    uint pmask = 0, pval = 0, rem = (uint)k;
#pragma unroll
    for (int shift = 8; shift >= 0; shift -= 8) {
        sbuf[tid] = 0;
        __syncthreads();
#pragma unroll
        for (int e = 0; e < EPT; e++) {
            int i = base + e;
            if (i < L && (key[e] & pmask) == pval)
                atomicAdd(&sbuf[(key[e] >> shift) & 255], 1u);
        }
        __syncthreads();
        uint sfx = sbuf[tid];
#pragma unroll
        for (int off = 1; off < 64; off <<= 1) {
            uint u2 = __shfl_down(sfx, off);
            if (lane + off < 64) sfx += u2;
        }
        if (lane == 0) wtot[wid] = sfx;
        __syncthreads();
        uint hi = 0;
        for (int w = wid + 1; w < 4; w++) hi += wtot[w];
        sbuf[tid] = sfx + hi;             // cnt_ge[bin=tid]
        if (tid == 0) sbuf[256] = 0;
        __syncthreads();
        uint cg = sbuf[tid], cgn = sbuf[tid + 1];
        if (cg >= rem && cgn < rem) { bsel[0] = (uint)tid; bsel[1] = rem - cgn; }
        __syncthreads();
        pval |= bsel[0] << shift;
        pmask |= 0xFFu << shift;
        rem = bsel[1];
        __syncthreads();
    }

    const uint T = pval;
    uint gtc = 0, eqc = 0;
#pragma unroll
    for (int e = 0; e < EPT; e++) {
        int i = base + e;
        if (i < L) {
            gtc += (key[e] > T) ? 1u : 0u;
            eqc += (key[e] == T) ? 1u : 0u;
        }
    }
    uint pack = (gtc << 16) | eqc;
    uint incl = pack;
#pragma unroll
    for (int off = 1; off < 64; off <<= 1) {
        uint u2 = __shfl_up(incl, off);
        if (lane >= off) incl += u2;
    }
    uint excl = incl - pack;
    if (lane == 63) wsum[wid] = incl;
    __syncthreads();
    uint badd = 0;
    for (int w = 0; w < wid; w++) badd += wsum[w];
    excl += badd;
    uint gt_before = excl >> 16, eq_before = excl & 0xffffu;

    ushort_t* dp1 = out1 + (size_t)o1_off + (size_t)n * o1_n + (size_t)c * o1_c;
    ushort_t* dp2 = out2 ? out2 + (size_t)o2_off + (size_t)n * o2_n + (size_t)c * o2_c
                         : (ushort_t*)0;
#pragma unroll
    for (int e = 0; e < EPT; e++) {
        int i = base + e;
        if (i >= L) break;
        uint kk = key[e];
        if (kk > T) {
            uint pos = gt_before + (eq_before < rem ? eq_before : rem);
            ushort_t v = kinv16(kk);
            dp1[(size_t)pos * o1_e] = v;
            if (dp2) dp2[(size_t)pos * o2_e] = v;
            gt_before++;
        } else if (kk == T) {
            if (eq_before < rem) {
                uint pos = gt_before + eq_before;
                ushort_t v = kinv16(kk);
                dp1[(size_t)pos * o1_e] = v;
                if (dp2) dp2[(size_t)pos * o2_e] = v;
            }
            eq_before++;
        }
    }
}

// ---------------------------------------------------------------------------
// qt GEMM: qtb[b,m,e] = bf16( sum_d qgb[b,m,d] * bwb[e,d] ).
// ---------------------------------------------------------------------------
__global__ __launch_bounds__(256) void qt_mfma_kernel(
    const ushort_t* __restrict__ qgb, const ushort_t* __restrict__ bwb,
    ushort_t* __restrict__ qtb)
{
    int mt = blockIdx.x, b = blockIdx.y;
    int tid = threadIdx.x, wid = tid >> 6, lane = tid & 63;
    int wn = wid * 80, lrow = lane & 15, quad = lane >> 4;

    const ushort_t* A = qgb + ((size_t)b * 480 + mt * 48 + lrow) * 320 + quad * 8;
    const ushort_t* B = bwb + (size_t)(wn + lrow) * 320 + quad * 8;

    floatx4 acc[3][5];
#pragma unroll
    for (int i = 0; i < 3; i++)
#pragma unroll
        for (int j = 0; j < 5; j++) acc[i][j] = (floatx4){0.f, 0.f, 0.f, 0.f};

#pragma unroll 5
    for (int c0 = 0; c0 < 320; c0 += 32) {
        bf16x8 af[3], bfr[5];
#pragma unroll
        for (int ms = 0; ms < 3; ms++)
            af[ms] = *(const bf16x8*)&A[(size_t)(ms * 16) * 320 + c0];
#pragma unroll
        for (int ns = 0; ns < 5; ns++)
            bfr[ns] = *(const bf16x8*)&B[(size_t)(ns * 16) * 320 + c0];
#pragma unroll
        for (int ms = 0; ms < 3; ms++)
#pragma unroll
            for (int ns = 0; ns < 5; ns++)
                acc[ms][ns] = __builtin_amdgcn_mfma_f32_16x16x32_bf16(
                    af[ms], bfr[ns], acc[ms][ns], 0, 0, 0);
    }

    ushort_t* out = qtb + ((size_t)b * 480 + mt * 48) * 320;
#pragma unroll
    for (int ms = 0; ms < 3; ms++)
#pragma unroll
        for (int ns = 0; ns < 5; ns++)
#pragma unroll
            for (int r = 0; r < 4; r++)
                out[(size_t)(ms * 16 + quad * 4 + r) * 320 + wn + ns * 16 + lrow] =
                    f2b(acc[ms][ns][r]);
}

// ---------------------------------------------------------------------------
// MFMA M-GEMM fused with pooling.
// ---------------------------------------------------------------------------
__global__ __launch_bounds__(256) void mpool_mfma_kernel(
    const ushort_t* __restrict__ qtb16, const ushort_t* __restrict__ dgb16,
    const float* __restrict__ bb, float* __restrict__ mp)
{
    __shared__ float pool[2 * 12 * 192];

    int jb = blockIdx.x;
    int qb = blockIdx.y;
    int n  = blockIdx.z;
    int b  = n & 15;

    int tid = threadIdx.x;
    int wid = tid >> 6, lane = tid & 63;
    int wm2 = wid >> 1;
    int wm = wm2 * 48, wn = (wid & 1) * 96;
    int lrow = lane & 15, quad = lane >> 4;

    const ushort_t* Abase = qtb16 + ((size_t)b * 480 + qb * 96 + wm) * 320 + quad * 8;
    const ushort_t* Bbase = dgb16 + ((size_t)n * 960 + jb * 192 + wn) * 320 + quad * 8;

    floatx4 acc[3][6];
#pragma unroll
    for (int i = 0; i < 3; i++)
#pragma unroll
        for (int j = 0; j < 6; j++) acc[i][j] = (floatx4){0.f, 0.f, 0.f, 0.f};

#pragma unroll 2
    for (int c0 = 0; c0 < 320; c0 += 32) {
        bf16x8 af[3], bfr[6];
#pragma unroll
        for (int mt = 0; mt < 3; mt++)
            af[mt] = *(const bf16x8*)&Abase[(size_t)(mt * 16 + lrow) * 320 + c0];
#pragma unroll
        for (int nt = 0; nt < 6; nt++)
            bfr[nt] = *(const bf16x8*)&Bbase[(size_t)(nt * 16 + lrow) * 320 + c0];
#pragma unroll
        for (int mt = 0; mt < 3; mt++)
#pragma unroll
            for (int nt = 0; nt < 6; nt++)
                acc[mt][nt] = __builtin_amdgcn_mfma_f32_16x16x32_bf16(
                    af[mt], bfr[nt], acc[mt][nt], 0, 0, 0);
    }

#pragma unroll
    for (int mt = 0; mt < 3; mt++) {
        int g = mt * 4 + quad;
#pragma unroll
        for (int nt = 0; nt < 6; nt++) {
            floatx4 a = acc[mt][nt];
            float rm = fmaxf(fmaxf(a[0], a[1]), fmaxf(a[2], a[3]));
            pool[(wm2 * 12 + g) * 192 + wn + nt * 16 + lrow] = rm;
        }
    }
    __syncthreads();

    if (tid < 64) {
        int qw = tid >> 3, jw = tid & 7;
        int slab = qw >> 2, w = qw & 3;
        float m = -INFINITY;
        const float* pp = &pool[(slab * 12 + w * 3) * 192 + jw * 24];
        for (int g = 0; g < 3; g++)
            for (int cc = 0; cc < 24; cc++)
                m = fmaxf(m, pp[g * 192 + cc]);
        float sig = 1.f / (1.f + expf(-(m + bb[0])));
        mp[(size_t)n * 1600 + (size_t)(qb * 8 + qw) * 40 + (jb * 8 + jw)] = sig;
    }
}

// ---------------------------------------------------------------------------
// Conv block: pad4 -> conv2x2(50) -> sigmoid -> pool 47->40 (H,W) -> ch-max.
// ---------------------------------------------------------------------------
__global__ __launch_bounds__(256) void convblock_kernel(
    const float* __restrict__ X, const float* __restrict__ w,
    const float* __restrict__ bias, float* __restrict__ Y)
{
    __shared__ float xp[48 * 48];
    __shared__ float ys[47 * 47];
    __shared__ float t1[40 * 47];
    __shared__ float outacc[1600];

    int n = blockIdx.x, t = threadIdx.x;
    const float* xn = X + (size_t)n * 1600;
    for (int i = t; i < 48 * 48; i += 256) {
        int r = i / 48, c = i - r * 48;
        int rr = r - 4, cc = c - 4;
        xp[i] = (rr >= 0 && rr < 40 && cc >= 0 && cc < 40) ? xn[rr * 40 + cc] : 0.f;
    }
    for (int i = t; i < 1600; i += 256) outacc[i] = -INFINITY;
    __syncthreads();

    for (int oc = 0; oc < 50; oc++) {
        float w00 = w[oc * 4 + 0], w01 = w[oc * 4 + 1];
        float w10 = w[oc * 4 + 2], w11 = w[oc * 4 + 3];
        float bo = bias[oc];
        for (int i = t; i < 47 * 47; i += 256) {
            int r = i / 47, c = i - r * 47;
            float v = xp[r * 48 + c] * w00 + xp[r * 48 + c + 1] * w01
                    + xp[(r + 1) * 48 + c] * w10 + xp[(r + 1) * 48 + c + 1] * w11 + bo;
            ys[i] = 1.f / (1.f + expf(-v));
        }
        __syncthreads();
        for (int i = t; i < 40 * 47; i += 256) {
            int r = i / 47, c = i - r * 47;
            int s = (47 * r) / 40, e = (47 * (r + 1) + 39) / 40;
            float m = ys[s * 47 + c];
            for (int x = s + 1; x < e; x++) m = fmaxf(m, ys[x * 47 + c]);
            t1[i] = m;
        }
        __syncthreads();
        for (int i = t; i < 1600; i += 256) {
            int r = i / 40, c = i - r * 40;
            int s = (47 * c) / 40, e = (47 * (c + 1) + 39) / 40;
            float m = t1[r * 47 + s];
            for (int x = s + 1; x < e; x++) m = fmaxf(m, t1[r * 47 + x]);
            outacc[i] = fmaxf(outacc[i], m);
        }
        __syncthreads();
    }
    for (int i = t; i < 1600; i += 256) Y[(size_t)n * 1600 + i] = outacc[i];
}

// ---------------------------------------------------------------------------
// Head
// ---------------------------------------------------------------------------
__global__ __launch_bounds__(64) void head_kernel(
    const float* __restrict__ feat, const float* __restrict__ lw,
    const float* __restrict__ lb, float* __restrict__ out)
{
    __shared__ float hs[40];
    int n = blockIdx.x, t = threadIdx.x;
    const float* f = feat + (size_t)n * 1600;
    if (t < 40) {
        float a = 0.f;
        for (int j = 0; j < 40; j++) a += f[t * 40 + j] * lw[j];
        hs[t] = 1.f / (1.f + expf(-(a + lb[0])));
    }
    __syncthreads();
    if (t == 0) {
        float a = 0.f;
        for (int i = 0; i < 40; i++) a += hs[i] * lw[i];
        out[n] = 1.f / (1.f + expf(-(a + lb[0])));
    }
}

// ---------------------------------------------------------------------------
extern "C" void kernel_launch(void* const* d_in, const int* in_sizes, int n_in,
                              void* d_out, int out_size, void* d_ws, size_t ws_size,
                              hipStream_t stream) {
    const float* query    = (const float*)d_in[0];
    const float* pos_doc  = (const float*)d_in[1];
    const float* neg_docs = (const float*)d_in[2];
    const float* qw1 = (const float*)d_in[3];  const float* qb1 = (const float*)d_in[4];
    const float* qw2 = (const float*)d_in[5];  const float* qb2 = (const float*)d_in[6];
    const float* qw3 = (const float*)d_in[7];  const float* qb3 = (const float*)d_in[8];
    const float* dw1 = (const float*)d_in[9];  const float* db1 = (const float*)d_in[10];
    const float* dw2 = (const float*)d_in[11]; const float* db2 = (const float*)d_in[12];
    const float* dw3 = (const float*)d_in[13]; const float* db3 = (const float*)d_in[14];
    const float* bw  = (const float*)d_in[15]; const float* bb  = (const float*)d_in[16];
    const float* mw1 = (const float*)d_in[17]; const float* mb1 = (const float*)d_in[18];
    const float* mw2 = (const float*)d_in[19]; const float* mb2 = (const float*)d_in[20];
    const float* mw3 = (const float*)d_in[21]; const float* mb3 = (const float*)d_in[22];
    const float* lw  = (const float*)d_in[23]; const float* lb  = (const float*)d_in[24];

    float* ws = (float*)d_ws;
    // ---- layout (float offsets) ----
    ushort_t* qw1b  = (ushort_t*)(ws + 0);          // 320*2048 bf16
    ushort_t* qw2b  = (ushort_t*)(ws + 327680);     // 320*640
    ushort_t* qw3b  = (ushort_t*)(ws + 430080);
    ushort_t* dw1b  = (ushort_t*)(ws + 532480);
    ushort_t* dw2b  = (ushort_t*)(ws + 860160);
    ushort_t* dw3b  = (ushort_t*)(ws + 962560);
    ushort_t* bwb   = (ushort_t*)(ws + 1064960);    // 320*320
    ushort_t* qgb16 = (ushort_t*)(ws + 1116160);    // (16,480,320)
    ushort_t* dgb16 = (ushort_t*)(ws + 2344960);    // (80,960,320)
    ushort_t* yt    = (ushort_t*)(ws + 14632960);   // (96,488,320)
    ushort_t* qxb   = (ushort_t*)(ws + 22128640);   // (16,264,1024)
    ushort_t* p1q   = (ushort_t*)(ws + 22128640);   // (16,200,320)
    ushort_t* p2q   = (ushort_t*)(ws + 22640640);   // (16,104,320)
    ushort_t* dxb   = (ushort_t*)(ws + 24291328);   // (80,520,1024)
    ushort_t* p1d   = (ushort_t*)(ws + 24291328);   // (80,360,320)
    ushort_t* p2d   = (ushort_t*)(ws + 28899328);   // (80,200,320)
    ushort_t* qtb16 = (ushort_t*)(ws + 31459328);   // (16,480,320)
    float*    mp    = ws + 32688128;                // (80,40,40)
    float*    xb2   = ws + 32816128;                // (80,40,40)

    // ---- weight prep (im2col layout [n][t*CPAD+c]) ----
    prep_w2_kernel<<<1280, 256, 0, stream>>>(qw1, qw1b, 1024, 1024);
    prep_w2_kernel<<<400, 256, 0, stream>>>(qw2, qw2b, 300, 320);
    prep_w2_kernel<<<400, 256, 0, stream>>>(qw3, qw3b, 300, 320);
    prep_w2_kernel<<<1280, 256, 0, stream>>>(dw1, dw1b, 1024, 1024);
    prep_w2_kernel<<<400, 256, 0, stream>>>(dw2, dw2b, 300, 320);
    prep_w2_kernel<<<400, 256, 0, stream>>>(dw3, dw3b, 300, 320);
    prep_bw_kernel<<<400, 256, 0, stream>>>(bw, bwb);

    // ---- input convert to padded bf16 ----
    {
        dim3 g(264, 16);
        x_pad_bf16_kernel<<<g, 256, 0, stream>>>(query, nullptr, 0,
                                                 239LL * 1024, 239, qxb, 264);
    }
    {
        dim3 g(520, 80);
        x_pad_bf16_kernel<<<g, 256, 0, stream>>>(pos_doc, neg_docs, 16,
                                                 479LL * 1024, 479, dxb, 520);
    }

    // ---- g0 top-ks ----
    topk16_kernel<4><<<16 * 239, 256, 0, stream>>>(
        qxb + 4 * 1024, 239, 264LL * 1024, 1024, 1, 1024, 300,
        qgb16, 0, 480LL * 320, 320, 1,
        nullptr, 0, 0, 0, 0);
    topk16_kernel<4><<<80 * 479, 256, 0, stream>>>(
        dxb + 4 * 1024, 479, 520LL * 1024, 1024, 1, 1024, 300,
        dgb16, 0, 960LL * 320, 320, 1,
        nullptr, 0, 0, 0, 0);

    // ---- conv1 ----
    {
        dim3 g(4, 2, 96);
        conv_gemm_kernel<1024><<<g, 256, 0, stream>>>(
            qxb, 264LL * 1024, dxb, 520LL * 1024,
            qw1b, dw1b, qb1, db1, 246, 486, 2, yt);
    }

    // ---- zero conv2/3 input pads ----
    hipMemsetAsync(p1q, 0, 16 * 200 * 320 * 2, stream);
    hipMemsetAsync(p2q, 0, 16 * 104 * 320 * 2, stream);
    hipMemsetAsync(p1d, 0, (size_t)80 * 360 * 320 * 2, stream);
    hipMemsetAsync(p2d, 0, (size_t)80 * 200 * 320 * 2, stream);

    // ---- p1 top-ks ----
    topk16_kernel<1><<<16 * 300, 256, 0, stream>>>(
        yt, 300, 488LL * 320, 1, 320, 246, 160,
        qgb16, 239LL * 320, 480LL * 320, 1, 320,
        p1q, 4LL * 320, 200LL * 320, 1, 320);
    topk16_kernel<2><<<80 * 300, 256, 0, stream>>>(
        yt + (size_t)16 * 488 * 320, 300, 488LL * 320, 1, 320, 486, 320,
        dgb16, 479LL * 320, 960LL * 320, 1, 320,
        p1d, 4LL * 320, 360LL * 320, 1, 320);

    // ---- conv2 ----
    {
        dim3 g(3, 2, 96);
        conv_gemm_kernel<320><<<g, 256, 0, stream>>>(
            p1q, 200LL * 320, p1d, 360LL * 320,
            qw2b, dw2b, qb2, db2, 167, 327, 2, yt);
    }

    // ---- p2 top-ks ----
    topk16_kernel<1><<<16 * 300, 256, 0, stream>>>(
        yt, 300, 488LL * 320, 1, 320, 167, 80,
        qgb16, 399LL * 320, 480LL * 320, 1, 320,
        p2q, 4LL * 320, 104LL * 320, 1, 320);
    topk16_kernel<2><<<80 * 300, 256, 0, stream>>>(
        yt + (size_t)16 * 488 * 320, 300, 488LL * 320, 1, 320, 327, 160,
        dgb16, 799LL * 320, 960LL * 320, 1, 320,
        p2d, 4LL * 320, 200LL * 320, 1, 320);

    // ---- conv3 ----
    {
        dim3 g(2, 2, 96);
        conv_gemm_kernel<320><<<g, 256, 0, stream>>>(
            p2q, 104LL * 320, p2d, 200LL * 320,
            qw3b, dw3b, qb3, db3, 87, 167, 1, yt);
    }

    // ---- p3 top-ks ----
    topk16_kernel<1><<<16 * 300, 256, 0, stream>>>(
        yt, 300, 488LL * 320, 1, 320, 87, 1,
        qgb16, 479LL * 320, 480LL * 320, 1, 320,
        nullptr, 0, 0, 0, 0);
    topk16_kernel<1><<<80 * 300, 256, 0, stream>>>(
        yt + (size_t)16 * 488 * 320, 300, 488LL * 320, 1, 320, 167, 1,
        dgb16, 959LL * 320, 960LL * 320, 1, 320,
        nullptr, 0, 0, 0, 0);

    // ---- qt GEMM + fused similarity/pool ----
    {
        dim3 g(10, 16);
        qt_mfma_kernel<<<g, 256, 0, stream>>>(qgb16, bwb, qtb16);
    }
    {
        dim3 g(5, 5, 80);
        mpool_mfma_kernel<<<g, 256, 0, stream>>>(qtb16, dgb16, bb, mp);
    }

    // ---- conv blocks + head ----
    convblock_kernel<<<80, 256, 0, stream>>>(mp, mw1, mb1, xb2);
    convblock_kernel<<<80, 256, 0, stream>>>(xb2, mw2, mb2, mp);
    convblock_kernel<<<80, 256, 0, stream>>>(mp, mw3, mb3, xb2);
    head_kernel<<<80, 64, 0, stream>>>(xb2, lw, lb, (float*)d_out);
}

// Round 7
// 1411.805 us; speedup vs baseline: 4.3100x; 1.4938x over previous
//
#include <hip/hip_runtime.h>
#include <hip/hip_bf16.h>
#include <math.h>

typedef unsigned long long ull;
typedef unsigned int uint;
typedef unsigned short ushort_t;

typedef short bf16x8 __attribute__((ext_vector_type(8)));
typedef float floatx4 __attribute__((ext_vector_type(4)));

// ---------------------------------------------------------------------------
// fp32 -> bf16 (round-to-nearest-even-ish)
// ---------------------------------------------------------------------------
__device__ inline ushort_t f2b(float f) {
    uint u = __float_as_uint(f);
    u = u + 0x7fffu + ((u >> 16) & 1u);
    return (ushort_t)(u >> 16);
}

// order-preserving bf16(bits)->uint16 map and inverse
__device__ inline uint kmap16(ushort_t u) {
    return (u & 0x8000u) ? (uint)((~u) & 0xFFFFu) : (uint)(u | 0x8000u);
}
__device__ inline ushort_t kinv16(uint k) {
    return (k & 0x8000u) ? (ushort_t)(k ^ 0x8000u) : (ushort_t)((~k) & 0xFFFFu);
}

// ---------------------------------------------------------------------------
// Prep: w (300, C, 2) fp32 -> Wb2[n][t*CPAD + c] bf16 (im2col layout),
// n in [0,320), zeros for n>=300 or c>=C.
// ---------------------------------------------------------------------------
__global__ void prep_w2_kernel(const float* __restrict__ w, ushort_t* __restrict__ Wb,
                               int C, int CPAD) {
    int total = 320 * 2 * CPAD;
    for (int i = blockIdx.x * blockDim.x + threadIdx.x; i < total;
         i += gridDim.x * blockDim.x) {
        int n = i / (2 * CPAD);
        int rem = i - n * 2 * CPAD;       // t*CPAD + c
        int t = rem / CPAD, c = rem - t * CPAD;
        float v = (n < 300 && c < C) ? w[((size_t)n * C + c) * 2 + t] : 0.f;
        Wb[i] = f2b(v);
    }
}

// bw (300,300) fp32 -> bwb[e][d] bf16 (320x320, zero pad)
__global__ void prep_bw_kernel(const float* __restrict__ bw, ushort_t* __restrict__ bwb) {
    int i = blockIdx.x * 256 + threadIdx.x;
    if (i >= 320 * 320) return;
    int e = i / 320, d = i - e * 320;
    bwb[i] = (e < 300 && d < 300) ? f2b(bw[d * 300 + e]) : (ushort_t)0;
}

// ---------------------------------------------------------------------------
// Input fp32 -> padded bf16: dst[n][r][1024], value = src row r-4 (zero pad).
// ---------------------------------------------------------------------------
__global__ __launch_bounds__(256) void x_pad_bf16_kernel(
    const float* __restrict__ src, const float* __restrict__ src2, int split_n,
    long long s_nstr, int Lin, ushort_t* __restrict__ dst, int rows)
{
    int r = blockIdx.x, n = blockIdx.y;
    const float* sp = (split_n > 0 && n >= split_n)
                          ? src2 + (size_t)(n - split_n) * s_nstr
                          : src + (size_t)n * s_nstr;
    int g = r - 4;
    ushort_t* dp = dst + ((size_t)n * rows + r) * 1024;
    int c = threadIdx.x * 4;
    ushort4 o = {0, 0, 0, 0};
    if (g >= 0 && g < Lin) {
        float4 v = *(const float4*)&sp[(size_t)g * 1024 + c];
        o.x = f2b(v.x); o.y = f2b(v.y); o.z = f2b(v.z); o.w = f2b(v.w);
    }
    *(ushort4*)&dp[c] = o;
}

// ---------------------------------------------------------------------------
// Barrier-free im2col MFMA conv GEMM, q+d merged, register double-buffered.
// ---------------------------------------------------------------------------
template <int CP>
__global__ __launch_bounds__(256, 2) void conv_gemm_kernel(
    const ushort_t* __restrict__ xq, long long xq_nstr,
    const ushort_t* __restrict__ xd, long long xd_nstr,
    const ushort_t* __restrict__ Wq, const ushort_t* __restrict__ Wd,
    const float* __restrict__ bq, const float* __restrict__ bd,
    int Lout_q, int Lout_d, int mtiles_q,
    ushort_t* __restrict__ yt)
{
    constexpr int K = 2 * CP;
    constexpr int KITER = K / 32;
    int mt = blockIdx.x, nb = blockIdx.y, n = blockIdx.z;
    bool isq = (n < 16);
    if (isq && mt >= mtiles_q) return;
    const ushort_t* x = isq ? xq + (size_t)n * xq_nstr
                            : xd + (size_t)(n - 16) * xd_nstr;
    const ushort_t* W = isq ? Wq : Wd;
    const float* bias = isq ? bq : bd;
    int Lout = isq ? Lout_q : Lout_d;
    int l0 = mt * 128;

    int tid = threadIdx.x, wid = tid >> 6, lane = tid & 63;
    int wm = (wid & 1) * 64, wn = (wid >> 1) * 80;
    int lrow = lane & 15, quad = lane >> 4;

    const ushort_t* A = x + (size_t)(l0 + wm + lrow) * CP + quad * 8;
    const ushort_t* B = W + (size_t)(nb * 160 + wn + lrow) * K + quad * 8;

    floatx4 acc[4][5];
#pragma unroll
    for (int i = 0; i < 4; i++)
#pragma unroll
        for (int j = 0; j < 5; j++) acc[i][j] = (floatx4){0.f, 0.f, 0.f, 0.f};

    bf16x8 afA[4], bfA[5], afB[4], bfB[5];
#pragma unroll
    for (int ms = 0; ms < 4; ms++)
        afA[ms] = *(const bf16x8*)&A[(size_t)(ms * 16) * CP];
#pragma unroll
    for (int ns = 0; ns < 5; ns++)
        bfA[ns] = *(const bf16x8*)&B[(size_t)(ns * 16) * K];

    for (int c = 0; c < KITER; c += 2) {
        int k1 = (c + 1) * 32;
#pragma unroll
        for (int ms = 0; ms < 4; ms++)
            afB[ms] = *(const bf16x8*)&A[(size_t)(ms * 16) * CP + k1];
#pragma unroll
        for (int ns = 0; ns < 5; ns++)
            bfB[ns] = *(const bf16x8*)&B[(size_t)(ns * 16) * K + k1];
#pragma unroll
        for (int ms = 0; ms < 4; ms++)
#pragma unroll
            for (int ns = 0; ns < 5; ns++)
                acc[ms][ns] = __builtin_amdgcn_mfma_f32_16x16x32_bf16(
                    afA[ms], bfA[ns], acc[ms][ns], 0, 0, 0);
        int k2 = (c + 2 < KITER) ? (c + 2) * 32 : 0;
#pragma unroll
        for (int ms = 0; ms < 4; ms++)
            afA[ms] = *(const bf16x8*)&A[(size_t)(ms * 16) * CP + k2];
#pragma unroll
        for (int ns = 0; ns < 5; ns++)
            bfA[ns] = *(const bf16x8*)&B[(size_t)(ns * 16) * K + k2];
#pragma unroll
        for (int ms = 0; ms < 4; ms++)
#pragma unroll
            for (int ns = 0; ns < 5; ns++)
                acc[ms][ns] = __builtin_amdgcn_mfma_f32_16x16x32_bf16(
                    afB[ms], bfB[ns], acc[ms][ns], 0, 0, 0);
    }

    ushort_t* yp = yt + (size_t)n * 488 * 320;
#pragma unroll
    for (int ns = 0; ns < 5; ns++) {
        int o = nb * 160 + wn + ns * 16 + lrow;
        if (o >= 300) continue;
        float bo = bias[o];
#pragma unroll
        for (int ms = 0; ms < 4; ms++)
#pragma unroll
            for (int r = 0; r < 4; r++) {
                int l = l0 + wm + ms * 16 + quad * 4 + r;
                if (l < Lout)
                    yp[(size_t)l * 320 + o] = f2b(tanhf(acc[ms][ns][r] + bo));
            }
    }
}

// ---------------------------------------------------------------------------
// 2-pass radix-select top-k on bf16 keys (k largest, ties -> smallest index).
// ---------------------------------------------------------------------------
template <int EPT>
__global__ __launch_bounds__(256) void topk16_kernel(
    const ushort_t* __restrict__ src, int CC,
    long long s_n, long long s_c, long long s_e,
    int L, int k,
    ushort_t* __restrict__ out1, long long o1_off, long long o1_n,
    long long o1_c, long long o1_e,
    ushort_t* __restrict__ out2, long long o2_off, long long o2_n,
    long long o2_c, long long o2_e)
{
    __shared__ uint sbuf[257];
    __shared__ uint wtot[4];
    __shared__ uint bsel[2];
    __shared__ uint wsum[4];

    int row = blockIdx.x;
    int n = row / CC, c = row - n * CC;
    const ushort_t* sp = src + (size_t)n * s_n + (size_t)c * s_c;

    int tid = threadIdx.x, lane = tid & 63, wid = tid >> 6;
    int base = tid * EPT;

    uint key[EPT];
    if (EPT == 4 && s_e == 1) {
        ushort4 v = *(const ushort4*)&sp[base];
        key[0] = kmap16(v.x); key[1] = kmap16(v.y);
        key[2] = kmap16(v.z); key[3] = kmap16(v.w);
    } else {
#pragma unroll
        for (int e = 0; e < EPT; e++) {
            int i = base + e;
            key[e] = (i < L) ? kmap16(sp[(size_t)i * s_e]) : 0u;
        }
    }

    uint pmask = 0, pval = 0, rem = (uint)k;
#pragma unroll
    for (int shift = 8; shift >= 0; shift -= 8) {
        sbuf[tid] = 0;
        __syncthreads();
#pragma unroll
        for (int e = 0; e < EPT; e++) {
            int i = base + e;
            if (i < L && (key[e] & pmask) == pval)
                atomicAdd(&sbuf[(key[e] >> shift) & 255], 1u);
        }
        __syncthreads();
        uint sfx = sbuf[tid];
#pragma unroll
        for (int off = 1; off < 64; off <<= 1) {
            uint u2 = __shfl_down(sfx, off);
            if (lane + off < 64) sfx += u2;
        }
        if (lane == 0) wtot[wid] = sfx;
        __syncthreads();
        uint hi = 0;
        for (int w = wid + 1; w < 4; w++) hi += wtot[w];
        sbuf[tid] = sfx + hi;             // cnt_ge[bin=tid]
        if (tid == 0) sbuf[256] = 0;
        __syncthreads();
        uint cg = sbuf[tid], cgn = sbuf[tid + 1];
        if (cg >= rem && cgn < rem) { bsel[0] = (uint)tid; bsel[1] = rem - cgn; }
        __syncthreads();
        pval |= bsel[0] << shift;
        pmask |= 0xFFu << shift;
        rem = bsel[1];
        __syncthreads();
    }

    const uint T = pval;
    uint gtc = 0, eqc = 0;
#pragma unroll
    for (int e = 0; e < EPT; e++) {
        int i = base + e;
        if (i < L) {
            gtc += (key[e] > T) ? 1u : 0u;
            eqc += (key[e] == T) ? 1u : 0u;
        }
    }
    uint pack = (gtc << 16) | eqc;
    uint incl = pack;
#pragma unroll
    for (int off = 1; off < 64; off <<= 1) {
        uint u2 = __shfl_up(incl, off);
        if (lane >= off) incl += u2;
    }
    uint excl = incl - pack;
    if (lane == 63) wsum[wid] = incl;
    __syncthreads();
    uint badd = 0;
    for (int w = 0; w < wid; w++) badd += wsum[w];
    excl += badd;
    uint gt_before = excl >> 16, eq_before = excl & 0xffffu;

    ushort_t* dp1 = out1 + (size_t)o1_off + (size_t)n * o1_n + (size_t)c * o1_c;
    ushort_t* dp2 = out2 ? out2 + (size_t)o2_off + (size_t)n * o2_n + (size_t)c * o2_c
                         : (ushort_t*)0;
#pragma unroll
    for (int e = 0; e < EPT; e++) {
        int i = base + e;
        if (i >= L) break;
        uint kk = key[e];
        if (kk > T) {
            uint pos = gt_before + (eq_before < rem ? eq_before : rem);
            ushort_t v = kinv16(kk);
            dp1[(size_t)pos * o1_e] = v;
            if (dp2) dp2[(size_t)pos * o2_e] = v;
            gt_before++;
        } else if (kk == T) {
            if (eq_before < rem) {
                uint pos = gt_before + eq_before;
                ushort_t v = kinv16(kk);
                dp1[(size_t)pos * o1_e] = v;
                if (dp2) dp2[(size_t)pos * o2_e] = v;
            }
            eq_before++;
        }
    }
}

// ---------------------------------------------------------------------------
// qt GEMM: qtb[b,m,e] = bf16( sum_d qgb[b,m,d] * bwb[e,d] ).
// ---------------------------------------------------------------------------
__global__ __launch_bounds__(256) void qt_mfma_kernel(
    const ushort_t* __restrict__ qgb, const ushort_t* __restrict__ bwb,
    ushort_t* __restrict__ qtb)
{
    int mt = blockIdx.x, b = blockIdx.y;
    int tid = threadIdx.x, wid = tid >> 6, lane = tid & 63;
    int wn = wid * 80, lrow = lane & 15, quad = lane >> 4;

    const ushort_t* A = qgb + ((size_t)b * 480 + mt * 48 + lrow) * 320 + quad * 8;
    const ushort_t* B = bwb + (size_t)(wn + lrow) * 320 + quad * 8;

    floatx4 acc[3][5];
#pragma unroll
    for (int i = 0; i < 3; i++)
#pragma unroll
        for (int j = 0; j < 5; j++) acc[i][j] = (floatx4){0.f, 0.f, 0.f, 0.f};

#pragma unroll 5
    for (int c0 = 0; c0 < 320; c0 += 32) {
        bf16x8 af[3], bfr[5];
#pragma unroll
        for (int ms = 0; ms < 3; ms++)
            af[ms] = *(const bf16x8*)&A[(size_t)(ms * 16) * 320 + c0];
#pragma unroll
        for (int ns = 0; ns < 5; ns++)
            bfr[ns] = *(const bf16x8*)&B[(size_t)(ns * 16) * 320 + c0];
#pragma unroll
        for (int ms = 0; ms < 3; ms++)
#pragma unroll
            for (int ns = 0; ns < 5; ns++)
                acc[ms][ns] = __builtin_amdgcn_mfma_f32_16x16x32_bf16(
                    af[ms], bfr[ns], acc[ms][ns], 0, 0, 0);
    }

    ushort_t* out = qtb + ((size_t)b * 480 + mt * 48) * 320;
#pragma unroll
    for (int ms = 0; ms < 3; ms++)
#pragma unroll
        for (int ns = 0; ns < 5; ns++)
#pragma unroll
            for (int r = 0; r < 4; r++)
                out[(size_t)(ms * 16 + quad * 4 + r) * 320 + wn + ns * 16 + lrow] =
                    f2b(acc[ms][ns][r]);
}

// ---------------------------------------------------------------------------
// MFMA M-GEMM fused with pooling.
// ---------------------------------------------------------------------------
__global__ __launch_bounds__(256) void mpool_mfma_kernel(
    const ushort_t* __restrict__ qtb16, const ushort_t* __restrict__ dgb16,
    const float* __restrict__ bb, float* __restrict__ mp)
{
    __shared__ float pool[2 * 12 * 192];

    int jb = blockIdx.x;
    int qb = blockIdx.y;
    int n  = blockIdx.z;
    int b  = n & 15;

    int tid = threadIdx.x;
    int wid = tid >> 6, lane = tid & 63;
    int wm2 = wid >> 1;
    int wm = wm2 * 48, wn = (wid & 1) * 96;
    int lrow = lane & 15, quad = lane >> 4;

    const ushort_t* Abase = qtb16 + ((size_t)b * 480 + qb * 96 + wm) * 320 + quad * 8;
    const ushort_t* Bbase = dgb16 + ((size_t)n * 960 + jb * 192 + wn) * 320 + quad * 8;

    floatx4 acc[3][6];
#pragma unroll
    for (int i = 0; i < 3; i++)
#pragma unroll
        for (int j = 0; j < 6; j++) acc[i][j] = (floatx4){0.f, 0.f, 0.f, 0.f};

#pragma unroll 2
    for (int c0 = 0; c0 < 320; c0 += 32) {
        bf16x8 af[3], bfr[6];
#pragma unroll
        for (int mt = 0; mt < 3; mt++)
            af[mt] = *(const bf16x8*)&Abase[(size_t)(mt * 16 + lrow) * 320 + c0];
#pragma unroll
        for (int nt = 0; nt < 6; nt++)
            bfr[nt] = *(const bf16x8*)&Bbase[(size_t)(nt * 16 + lrow) * 320 + c0];
#pragma unroll
        for (int mt = 0; mt < 3; mt++)
#pragma unroll
            for (int nt = 0; nt < 6; nt++)
                acc[mt][nt] = __builtin_amdgcn_mfma_f32_16x16x32_bf16(
                    af[mt], bfr[nt], acc[mt][nt], 0, 0, 0);
    }

#pragma unroll
    for (int mt = 0; mt < 3; mt++) {
        int g = mt * 4 + quad;
#pragma unroll
        for (int nt = 0; nt < 6; nt++) {
            floatx4 a = acc[mt][nt];
            float rm = fmaxf(fmaxf(a[0], a[1]), fmaxf(a[2], a[3]));
            pool[(wm2 * 12 + g) * 192 + wn + nt * 16 + lrow] = rm;
        }
    }
    __syncthreads();

    if (tid < 64) {
        int qw = tid >> 3, jw = tid & 7;
        int slab = qw >> 2, w = qw & 3;
        float m = -INFINITY;
        const float* pp = &pool[(slab * 12 + w * 3) * 192 + jw * 24];
        for (int g = 0; g < 3; g++)
            for (int cc = 0; cc < 24; cc++)
                m = fmaxf(m, pp[g * 192 + cc]);
        float sig = 1.f / (1.f + expf(-(m + bb[0])));
        mp[(size_t)n * 1600 + (size_t)(qb * 8 + qw) * 40 + (jb * 8 + jw)] = sig;
    }
}

// ---------------------------------------------------------------------------
// Conv block, channel-parallel: grid (n, 50/OCG).  Each block computes the
// max over its OCG channels of [pad4 -> conv2x2 -> sigmoid -> pool H,W] and
// atomicMax-merges (uint compare == float compare: sigmoid > 0) into Y[n].
// Y must be zero-initialized before launch.
// ---------------------------------------------------------------------------
#define OCG 10
__global__ __launch_bounds__(256) void convblock_atomic_kernel(
    const float* __restrict__ X, const float* __restrict__ w,
    const float* __restrict__ bias, uint* __restrict__ Y)
{
    __shared__ float xp[48 * 48];
    __shared__ float ys[47 * 47];
    __shared__ float t1[40 * 47];
    __shared__ float outacc[1600];

    int n = blockIdx.x, t = threadIdx.x;
    int oc0 = blockIdx.y * OCG;
    const float* xn = X + (size_t)n * 1600;
    for (int i = t; i < 48 * 48; i += 256) {
        int r = i / 48, c = i - r * 48;
        int rr = r - 4, cc = c - 4;
        xp[i] = (rr >= 0 && rr < 40 && cc >= 0 && cc < 40) ? xn[rr * 40 + cc] : 0.f;
    }
    for (int i = t; i < 1600; i += 256) outacc[i] = 0.f;
    __syncthreads();

    for (int oc = oc0; oc < oc0 + OCG; oc++) {
        float w00 = w[oc * 4 + 0], w01 = w[oc * 4 + 1];
        float w10 = w[oc * 4 + 2], w11 = w[oc * 4 + 3];
        float bo = bias[oc];
        for (int i = t; i < 47 * 47; i += 256) {
            int r = i / 47, c = i - r * 47;
            float v = xp[r * 48 + c] * w00 + xp[r * 48 + c + 1] * w01
                    + xp[(r + 1) * 48 + c] * w10 + xp[(r + 1) * 48 + c + 1] * w11 + bo;
            ys[i] = 1.f / (1.f + expf(-v));
        }
        __syncthreads();
        for (int i = t; i < 40 * 47; i += 256) {
            int r = i / 47, c = i - r * 47;
            int s = (47 * r) / 40, e = (47 * (r + 1) + 39) / 40;
            float m = ys[s * 47 + c];
            for (int x = s + 1; x < e; x++) m = fmaxf(m, ys[x * 47 + c]);
            t1[i] = m;
        }
        __syncthreads();
        for (int i = t; i < 1600; i += 256) {
            int r = i / 40, c = i - r * 40;
            int s = (47 * c) / 40, e = (47 * (c + 1) + 39) / 40;
            float m = t1[r * 47 + s];
            for (int x = s + 1; x < e; x++) m = fmaxf(m, t1[r * 47 + x]);
            outacc[i] = fmaxf(outacc[i], m);
        }
        __syncthreads();
    }
    for (int i = t; i < 1600; i += 256)
        atomicMax(&Y[(size_t)n * 1600 + i], __float_as_uint(outacc[i]));
}

// ---------------------------------------------------------------------------
// Head
// ---------------------------------------------------------------------------
__global__ __launch_bounds__(64) void head_kernel(
    const float* __restrict__ feat, const float* __restrict__ lw,
    const float* __restrict__ lb, float* __restrict__ out)
{
    __shared__ float hs[40];
    int n = blockIdx.x, t = threadIdx.x;
    const float* f = feat + (size_t)n * 1600;
    if (t < 40) {
        float a = 0.f;
        for (int j = 0; j < 40; j++) a += f[t * 40 + j] * lw[j];
        hs[t] = 1.f / (1.f + expf(-(a + lb[0])));
    }
    __syncthreads();
    if (t == 0) {
        float a = 0.f;
        for (int i = 0; i < 40; i++) a += hs[i] * lw[i];
        out[n] = 1.f / (1.f + expf(-(a + lb[0])));
    }
}

// ---------------------------------------------------------------------------
extern "C" void kernel_launch(void* const* d_in, const int* in_sizes, int n_in,
                              void* d_out, int out_size, void* d_ws, size_t ws_size,
                              hipStream_t stream) {
    const float* query    = (const float*)d_in[0];
    const float* pos_doc  = (const float*)d_in[1];
    const float* neg_docs = (const float*)d_in[2];
    const float* qw1 = (const float*)d_in[3];  const float* qb1 = (const float*)d_in[4];
    const float* qw2 = (const float*)d_in[5];  const float* qb2 = (const float*)d_in[6];
    const float* qw3 = (const float*)d_in[7];  const float* qb3 = (const float*)d_in[8];
    const float* dw1 = (const float*)d_in[9];  const float* db1 = (const float*)d_in[10];
    const float* dw2 = (const float*)d_in[11]; const float* db2 = (const float*)d_in[12];
    const float* dw3 = (const float*)d_in[13]; const float* db3 = (const float*)d_in[14];
    const float* bw  = (const float*)d_in[15]; const float* bb  = (const float*)d_in[16];
    const float* mw1 = (const float*)d_in[17]; const float* mb1 = (const float*)d_in[18];
    const float* mw2 = (const float*)d_in[19]; const float* mb2 = (const float*)d_in[20];
    const float* mw3 = (const float*)d_in[21]; const float* mb3 = (const float*)d_in[22];
    const float* lw  = (const float*)d_in[23]; const float* lb  = (const float*)d_in[24];

    float* ws = (float*)d_ws;
    // ---- layout (float offsets) ----
    ushort_t* qw1b  = (ushort_t*)(ws + 0);          // 320*2048 bf16
    ushort_t* qw2b  = (ushort_t*)(ws + 327680);     // 320*640
    ushort_t* qw3b  = (ushort_t*)(ws + 430080);
    ushort_t* dw1b  = (ushort_t*)(ws + 532480);
    ushort_t* dw2b  = (ushort_t*)(ws + 860160);
    ushort_t* dw3b  = (ushort_t*)(ws + 962560);
    ushort_t* bwb   = (ushort_t*)(ws + 1064960);    // 320*320
    ushort_t* qgb16 = (ushort_t*)(ws + 1116160);    // (16,480,320)
    ushort_t* dgb16 = (ushort_t*)(ws + 2344960);    // (80,960,320)
    ushort_t* yt    = (ushort_t*)(ws + 14632960);   // (96,488,320)
    ushort_t* qxb   = (ushort_t*)(ws + 22128640);   // (16,264,1024)
    ushort_t* p1q   = (ushort_t*)(ws + 22128640);   // (16,200,320)
    ushort_t* p2q   = (ushort_t*)(ws + 22640640);   // (16,104,320)
    ushort_t* dxb   = (ushort_t*)(ws + 24291328);   // (80,520,1024)
    ushort_t* p1d   = (ushort_t*)(ws + 24291328);   // (80,360,320)
    ushort_t* p2d   = (ushort_t*)(ws + 28899328);   // (80,200,320)
    ushort_t* qtb16 = (ushort_t*)(ws + 31459328);   // (16,480,320)
    float*    mp    = ws + 32688128;                // (80,40,40)
    float*    ya    = ws + 32816128;                // (80,40,40)
    float*    yb    = ws + 32944128;                // (80,40,40)
    float*    yc    = ws + 33072128;                // (80,40,40)

    // ---- weight prep (im2col layout [n][t*CPAD+c]) ----
    prep_w2_kernel<<<1280, 256, 0, stream>>>(qw1, qw1b, 1024, 1024);
    prep_w2_kernel<<<400, 256, 0, stream>>>(qw2, qw2b, 300, 320);
    prep_w2_kernel<<<400, 256, 0, stream>>>(qw3, qw3b, 300, 320);
    prep_w2_kernel<<<1280, 256, 0, stream>>>(dw1, dw1b, 1024, 1024);
    prep_w2_kernel<<<400, 256, 0, stream>>>(dw2, dw2b, 300, 320);
    prep_w2_kernel<<<400, 256, 0, stream>>>(dw3, dw3b, 300, 320);
    prep_bw_kernel<<<400, 256, 0, stream>>>(bw, bwb);

    // ---- input convert to padded bf16 ----
    {
        dim3 g(264, 16);
        x_pad_bf16_kernel<<<g, 256, 0, stream>>>(query, nullptr, 0,
                                                 239LL * 1024, 239, qxb, 264);
    }
    {
        dim3 g(520, 80);
        x_pad_bf16_kernel<<<g, 256, 0, stream>>>(pos_doc, neg_docs, 16,
                                                 479LL * 1024, 479, dxb, 520);
    }

    // ---- g0 top-ks ----
    topk16_kernel<4><<<16 * 239, 256, 0, stream>>>(
        qxb + 4 * 1024, 239, 264LL * 1024, 1024, 1, 1024, 300,
        qgb16, 0, 480LL * 320, 320, 1,
        nullptr, 0, 0, 0, 0);
    topk16_kernel<4><<<80 * 479, 256, 0, stream>>>(
        dxb + 4 * 1024, 479, 520LL * 1024, 1024, 1, 1024, 300,
        dgb16, 0, 960LL * 320, 320, 1,
        nullptr, 0, 0, 0, 0);

    // ---- conv1 ----
    {
        dim3 g(4, 2, 96);
        conv_gemm_kernel<1024><<<g, 256, 0, stream>>>(
            qxb, 264LL * 1024, dxb, 520LL * 1024,
            qw1b, dw1b, qb1, db1, 246, 486, 2, yt);
    }

    // ---- zero conv2/3 input pads ----
    hipMemsetAsync(p1q, 0, 16 * 200 * 320 * 2, stream);
    hipMemsetAsync(p2q, 0, 16 * 104 * 320 * 2, stream);
    hipMemsetAsync(p1d, 0, (size_t)80 * 360 * 320 * 2, stream);
    hipMemsetAsync(p2d, 0, (size_t)80 * 200 * 320 * 2, stream);
    // ---- zero conv-block outputs (atomicMax targets) ----
    hipMemsetAsync(ya, 0, 80 * 1600 * 4, stream);
    hipMemsetAsync(yb, 0, 80 * 1600 * 4, stream);
    hipMemsetAsync(yc, 0, 80 * 1600 * 4, stream);

    // ---- p1 top-ks ----
    topk16_kernel<1><<<16 * 300, 256, 0, stream>>>(
        yt, 300, 488LL * 320, 1, 320, 246, 160,
        qgb16, 239LL * 320, 480LL * 320, 1, 320,
        p1q, 4LL * 320, 200LL * 320, 1, 320);
    topk16_kernel<2><<<80 * 300, 256, 0, stream>>>(
        yt + (size_t)16 * 488 * 320, 300, 488LL * 320, 1, 320, 486, 320,
        dgb16, 479LL * 320, 960LL * 320, 1, 320,
        p1d, 4LL * 320, 360LL * 320, 1, 320);

    // ---- conv2 ----
    {
        dim3 g(3, 2, 96);
        conv_gemm_kernel<320><<<g, 256, 0, stream>>>(
            p1q, 200LL * 320, p1d, 360LL * 320,
            qw2b, dw2b, qb2, db2, 167, 327, 2, yt);
    }

    // ---- p2 top-ks ----
    topk16_kernel<1><<<16 * 300, 256, 0, stream>>>(
        yt, 300, 488LL * 320, 1, 320, 167, 80,
        qgb16, 399LL * 320, 480LL * 320, 1, 320,
        p2q, 4LL * 320, 104LL * 320, 1, 320);
    topk16_kernel<2><<<80 * 300, 256, 0, stream>>>(
        yt + (size_t)16 * 488 * 320, 300, 488LL * 320, 1, 320, 327, 160,
        dgb16, 799LL * 320, 960LL * 320, 1, 320,
        p2d, 4LL * 320, 200LL * 320, 1, 320);

    // ---- conv3 ----
    {
        dim3 g(2, 2, 96);
        conv_gemm_kernel<320><<<g, 256, 0, stream>>>(
            p2q, 104LL * 320, p2d, 200LL * 320,
            qw3b, dw3b, qb3, db3, 87, 167, 1, yt);
    }

    // ---- p3 top-ks ----
    topk16_kernel<1><<<16 * 300, 256, 0, stream>>>(
        yt, 300, 488LL * 320, 1, 320, 87, 1,
        qgb16, 479LL * 320, 480LL * 320, 1, 320,
        nullptr, 0, 0, 0, 0);
    topk16_kernel<1><<<80 * 300, 256, 0, stream>>>(
        yt + (size_t)16 * 488 * 320, 300, 488LL * 320, 1, 320, 167, 1,
        dgb16, 959LL * 320, 960LL * 320, 1, 320,
        nullptr, 0, 0, 0, 0);

    // ---- qt GEMM + fused similarity/pool ----
    {
        dim3 g(10, 16);
        qt_mfma_kernel<<<g, 256, 0, stream>>>(qgb16, bwb, qtb16);
    }
    {
        dim3 g(5, 5, 80);
        mpool_mfma_kernel<<<g, 256, 0, stream>>>(qtb16, dgb16, bb, mp);
    }

    // ---- conv blocks (channel-parallel, atomicMax-merged) + head ----
    {
        dim3 g(80, 5);
        convblock_atomic_kernel<<<g, 256, 0, stream>>>(mp, mw1, mb1, (uint*)ya);
        convblock_atomic_kernel<<<g, 256, 0, stream>>>(ya, mw2, mb2, (uint*)yb);
        convblock_atomic_kernel<<<g, 256, 0, stream>>>(yb, mw3, mb3, (uint*)yc);
    }
    head_kernel<<<80, 64, 0, stream>>>(yc, lw, lb, (float*)d_out);
}

// Round 8
// 1312.917 us; speedup vs baseline: 4.6346x; 1.0753x over previous
//
#include <hip/hip_runtime.h>
#include <hip/hip_bf16.h>
#include <math.h>

typedef unsigned long long ull;
typedef unsigned int uint;
typedef unsigned short ushort_t;

typedef short bf16x8 __attribute__((ext_vector_type(8)));
typedef float floatx4 __attribute__((ext_vector_type(4)));

// ---------------------------------------------------------------------------
// fp32 -> bf16 (round-to-nearest-even-ish)
// ---------------------------------------------------------------------------
__device__ inline ushort_t f2b(float f) {
    uint u = __float_as_uint(f);
    u = u + 0x7fffu + ((u >> 16) & 1u);
    return (ushort_t)(u >> 16);
}

// order-preserving bf16(bits)->uint16 map and inverse
__device__ inline uint kmap16(ushort_t u) {
    return (u & 0x8000u) ? (uint)((~u) & 0xFFFFu) : (uint)(u | 0x8000u);
}
__device__ inline ushort_t kinv16(uint k) {
    return (k & 0x8000u) ? (ushort_t)(k ^ 0x8000u) : (ushort_t)((~k) & 0xFFFFu);
}

// async 16B global -> LDS (DMA).  LDS dest = wave-uniform base + lane*16.
__device__ inline void async_copy16(const void* g, void* l) {
    __builtin_amdgcn_global_load_lds(
        (const __attribute__((address_space(1))) void*)g,
        (__attribute__((address_space(3))) void*)l, 16, 0, 0);
}

// ---------------------------------------------------------------------------
// Prep: w (300, C, 2) fp32 -> Wb2[n][t*CPAD + c] bf16 (im2col layout),
// n in [0,320), zeros for n>=300 or c>=C.
// ---------------------------------------------------------------------------
__global__ void prep_w2_kernel(const float* __restrict__ w, ushort_t* __restrict__ Wb,
                               int C, int CPAD) {
    int total = 320 * 2 * CPAD;
    for (int i = blockIdx.x * blockDim.x + threadIdx.x; i < total;
         i += gridDim.x * blockDim.x) {
        int n = i / (2 * CPAD);
        int rem = i - n * 2 * CPAD;       // t*CPAD + c
        int t = rem / CPAD, c = rem - t * CPAD;
        float v = (n < 300 && c < C) ? w[((size_t)n * C + c) * 2 + t] : 0.f;
        Wb[i] = f2b(v);
    }
}

// bw (300,300) fp32 -> bwb[e][d] bf16 (320x320, zero pad)
__global__ void prep_bw_kernel(const float* __restrict__ bw, ushort_t* __restrict__ bwb) {
    int i = blockIdx.x * 256 + threadIdx.x;
    if (i >= 320 * 320) return;
    int e = i / 320, d = i - e * 320;
    bwb[i] = (e < 300 && d < 300) ? f2b(bw[d * 300 + e]) : (ushort_t)0;
}

// ---------------------------------------------------------------------------
// Input fp32 -> padded bf16: dst[n][r][1024], value = src row r-4 (zero pad).
// ---------------------------------------------------------------------------
__global__ __launch_bounds__(256) void x_pad_bf16_kernel(
    const float* __restrict__ src, const float* __restrict__ src2, int split_n,
    long long s_nstr, int Lin, ushort_t* __restrict__ dst, int rows)
{
    int r = blockIdx.x, n = blockIdx.y;
    const float* sp = (split_n > 0 && n >= split_n)
                          ? src2 + (size_t)(n - split_n) * s_nstr
                          : src + (size_t)n * s_nstr;
    int g = r - 4;
    ushort_t* dp = dst + ((size_t)n * rows + r) * 1024;
    int c = threadIdx.x * 4;
    ushort4 o = {0, 0, 0, 0};
    if (g >= 0 && g < Lin) {
        float4 v = *(const float4*)&sp[(size_t)g * 1024 + c];
        o.x = f2b(v.x); o.y = f2b(v.y); o.z = f2b(v.z); o.w = f2b(v.w);
    }
    *(ushort4*)&dp[c] = o;
}

// ---------------------------------------------------------------------------
// Conv GEMM, m97-style: A (HBM stream) staged async into double-buffered LDS,
// B (L2-resident weights) from global, MFMA from LDS.  q+d merged.
// Block: 256 thr, 4 waves; tile M=64 x N=320 (full N -> A fetched once).
// Wave: 64M x 80N; per 32-ch chunk: 2 taps x 4x5 MFMAs = 40.
// Per chunk: barrier -> B loads (10) -> stage next A (DMA) -> ds_read A (8)
// -> MFMA.  B issued before the DMA so its vmcnt wait doesn't drain the DMA.
// ---------------------------------------------------------------------------
template <int CP>
__global__ __launch_bounds__(256, 2) void conv_lds_kernel(
    const ushort_t* __restrict__ xq, long long xq_nstr,
    const ushort_t* __restrict__ xd, long long xd_nstr,
    const ushort_t* __restrict__ Wq, const ushort_t* __restrict__ Wd,
    const float* __restrict__ bq, const float* __restrict__ bd,
    int Lout_q, int Lout_d, int mtiles_q,
    ushort_t* __restrict__ yt)
{
    constexpr int CH = CP / 32;
    constexpr int K2 = 2 * CP;
    __shared__ ushort_t Abuf[2][65 * 32];   // [buf][row*32 + ch], 4160 B each

    int mt = blockIdx.x, n = blockIdx.y;
    bool isq = (n < 16);
    if (isq && mt >= mtiles_q) return;
    const ushort_t* x = isq ? xq + (size_t)n * xq_nstr
                            : xd + (size_t)(n - 16) * xd_nstr;
    const ushort_t* W = isq ? Wq : Wd;
    const float* bias = isq ? bq : bd;
    int Lout = isq ? Lout_q : Lout_d;
    int l0 = mt * 64;

    int tid = threadIdx.x, wid = tid >> 6, lane = tid & 63;
    int wn = wid * 80;
    int lrow = lane & 15, quad = lane >> 4;

    // staging: chunk idx = tid -> (row = tid/4, slot = tid%4), 16B each;
    // extra chunks 256..259 (row 64) by wave 0 lanes 0..3.
    const ushort_t* g0 = x + (size_t)(l0 + (tid >> 2)) * CP + (tid & 3) * 8;
    const ushort_t* g1 = x + (size_t)(l0 + 64) * CP + (tid & 3) * 8;

    const ushort_t* Bb = W + (size_t)(wn + lrow) * K2 + quad * 8;

    floatx4 acc[4][5];
#pragma unroll
    for (int i = 0; i < 4; i++)
#pragma unroll
        for (int j = 0; j < 5; j++) acc[i][j] = (floatx4){0.f, 0.f, 0.f, 0.f};

    // prologue: stage chunk 0 into buf 0
    {
        char* lb = (char*)&Abuf[0][0];
        async_copy16(g0, lb + wid * 1024);
        if (tid < 4) async_copy16(g1, lb + 4096);
    }

    for (int c = 0; c < CH; c++) {
        __syncthreads();                       // drains DMA for Abuf[c&1]
        int c0 = c * 32;

        // B fragments first (so their vmcnt wait precedes the new DMA)
        bf16x8 bfr[2][5];
#pragma unroll
        for (int t = 0; t < 2; t++)
#pragma unroll
            for (int ns = 0; ns < 5; ns++)
                bfr[t][ns] = *(const bf16x8*)&Bb[(size_t)(ns * 16) * K2 + t * CP + c0];

        // stage next chunk into the other buffer
        if (c + 1 < CH) {
            char* lb = (char*)&Abuf[(c + 1) & 1][0];
            async_copy16(g0 + c0 + 32, lb + wid * 1024);
            if (tid < 4) async_copy16(g1 + c0 + 32, lb + 4096);
        }

        // A fragments from LDS: row = ms*16 + lrow + tap, 16B at quad*16
        const char* ab = (const char*)&Abuf[c & 1][0];
        bf16x8 af[2][4];
#pragma unroll
        for (int t = 0; t < 2; t++)
#pragma unroll
            for (int ms = 0; ms < 4; ms++)
                af[t][ms] = *(const bf16x8*)(ab + (ms * 16 + lrow + t) * 64 + quad * 16);

#pragma unroll
        for (int t = 0; t < 2; t++)
#pragma unroll
            for (int ms = 0; ms < 4; ms++)
#pragma unroll
                for (int ns = 0; ns < 5; ns++)
                    acc[ms][ns] = __builtin_amdgcn_mfma_f32_16x16x32_bf16(
                        af[t][ms], bfr[t][ns], acc[ms][ns], 0, 0, 0);
    }

    ushort_t* yp = yt + (size_t)n * 488 * 320;
#pragma unroll
    for (int ns = 0; ns < 5; ns++) {
        int o = wn + ns * 16 + lrow;
        if (o >= 300) continue;
        float bo = bias[o];
#pragma unroll
        for (int ms = 0; ms < 4; ms++)
#pragma unroll
            for (int r = 0; r < 4; r++) {
                int l = l0 + ms * 16 + quad * 4 + r;
                if (l < Lout)
                    yp[(size_t)l * 320 + o] = f2b(tanhf(acc[ms][ns][r] + bo));
            }
    }
}

// ---------------------------------------------------------------------------
// 2-pass radix-select top-k on bf16 keys (k largest, ties -> smallest index).
// ---------------------------------------------------------------------------
template <int EPT>
__global__ __launch_bounds__(256) void topk16_kernel(
    const ushort_t* __restrict__ src, int CC,
    long long s_n, long long s_c, long long s_e,
    int L, int k,
    ushort_t* __restrict__ out1, long long o1_off, long long o1_n,
    long long o1_c, long long o1_e,
    ushort_t* __restrict__ out2, long long o2_off, long long o2_n,
    long long o2_c, long long o2_e)
{
    __shared__ uint sbuf[257];
    __shared__ uint wtot[4];
    __shared__ uint bsel[2];
    __shared__ uint wsum[4];

    int row = blockIdx.x;
    int n = row / CC, c = row - n * CC;
    const ushort_t* sp = src + (size_t)n * s_n + (size_t)c * s_c;

    int tid = threadIdx.x, lane = tid & 63, wid = tid >> 6;
    int base = tid * EPT;

    uint key[EPT];
    if (EPT == 4 && s_e == 1) {
        ushort4 v = *(const ushort4*)&sp[base];
        key[0] = kmap16(v.x); key[1] = kmap16(v.y);
        key[2] = kmap16(v.z); key[3] = kmap16(v.w);
    } else {
#pragma unroll
        for (int e = 0; e < EPT; e++) {
            int i = base + e;
            key[e] = (i < L) ? kmap16(sp[(size_t)i * s_e]) : 0u;
        }
    }

    uint pmask = 0, pval = 0, rem = (uint)k;
#pragma unroll
    for (int shift = 8; shift >= 0; shift -= 8) {
        sbuf[tid] = 0;
        __syncthreads();
#pragma unroll
        for (int e = 0; e < EPT; e++) {
            int i = base + e;
            if (i < L && (key[e] & pmask) == pval)
                atomicAdd(&sbuf[(key[e] >> shift) & 255], 1u);
        }
        __syncthreads();
        uint sfx = sbuf[tid];
#pragma unroll
        for (int off = 1; off < 64; off <<= 1) {
            uint u2 = __shfl_down(sfx, off);
            if (lane + off < 64) sfx += u2;
        }
        if (lane == 0) wtot[wid] = sfx;
        __syncthreads();
        uint hi = 0;
        for (int w = wid + 1; w < 4; w++) hi += wtot[w];
        sbuf[tid] = sfx + hi;             // cnt_ge[bin=tid]
        if (tid == 0) sbuf[256] = 0;
        __syncthreads();
        uint cg = sbuf[tid], cgn = sbuf[tid + 1];
        if (cg >= rem && cgn < rem) { bsel[0] = (uint)tid; bsel[1] = rem - cgn; }
        __syncthreads();
        pval |= bsel[0] << shift;
        pmask |= 0xFFu << shift;
        rem = bsel[1];
        __syncthreads();
    }

    const uint T = pval;
    uint gtc = 0, eqc = 0;
#pragma unroll
    for (int e = 0; e < EPT; e++) {
        int i = base + e;
        if (i < L) {
            gtc += (key[e] > T) ? 1u : 0u;
            eqc += (key[e] == T) ? 1u : 0u;
        }
    }
    uint pack = (gtc << 16) | eqc;
    uint incl = pack;
#pragma unroll
    for (int off = 1; off < 64; off <<= 1) {
        uint u2 = __shfl_up(incl, off);
        if (lane >= off) incl += u2;
    }
    uint excl = incl - pack;
    if (lane == 63) wsum[wid] = incl;
    __syncthreads();
    uint badd = 0;
    for (int w = 0; w < wid; w++) badd += wsum[w];
    excl += badd;
    uint gt_before = excl >> 16, eq_before = excl & 0xffffu;

    ushort_t* dp1 = out1 + (size_t)o1_off + (size_t)n * o1_n + (size_t)c * o1_c;
    ushort_t* dp2 = out2 ? out2 + (size_t)o2_off + (size_t)n * o2_n + (size_t)c * o2_c
                         : (ushort_t*)0;
#pragma unroll
    for (int e = 0; e < EPT; e++) {
        int i = base + e;
        if (i >= L) break;
        uint kk = key[e];
        if (kk > T) {
            uint pos = gt_before + (eq_before < rem ? eq_before : rem);
            ushort_t v = kinv16(kk);
            dp1[(size_t)pos * o1_e] = v;
            if (dp2) dp2[(size_t)pos * o2_e] = v;
            gt_before++;
        } else if (kk == T) {
            if (eq_before < rem) {
                uint pos = gt_before + eq_before;
                ushort_t v = kinv16(kk);
                dp1[(size_t)pos * o1_e] = v;
                if (dp2) dp2[(size_t)pos * o2_e] = v;
            }
            eq_before++;
        }
    }
}

// ---------------------------------------------------------------------------
// qt GEMM: qtb[b,m,e] = bf16( sum_d qgb[b,m,d] * bwb[e,d] ).
// ---------------------------------------------------------------------------
__global__ __launch_bounds__(256) void qt_mfma_kernel(
    const ushort_t* __restrict__ qgb, const ushort_t* __restrict__ bwb,
    ushort_t* __restrict__ qtb)
{
    int mt = blockIdx.x, b = blockIdx.y;
    int tid = threadIdx.x, wid = tid >> 6, lane = tid & 63;
    int wn = wid * 80, lrow = lane & 15, quad = lane >> 4;

    const ushort_t* A = qgb + ((size_t)b * 480 + mt * 48 + lrow) * 320 + quad * 8;
    const ushort_t* B = bwb + (size_t)(wn + lrow) * 320 + quad * 8;

    floatx4 acc[3][5];
#pragma unroll
    for (int i = 0; i < 3; i++)
#pragma unroll
        for (int j = 0; j < 5; j++) acc[i][j] = (floatx4){0.f, 0.f, 0.f, 0.f};

#pragma unroll 5
    for (int c0 = 0; c0 < 320; c0 += 32) {
        bf16x8 af[3], bfr[5];
#pragma unroll
        for (int ms = 0; ms < 3; ms++)
            af[ms] = *(const bf16x8*)&A[(size_t)(ms * 16) * 320 + c0];
#pragma unroll
        for (int ns = 0; ns < 5; ns++)
            bfr[ns] = *(const bf16x8*)&B[(size_t)(ns * 16) * 320 + c0];
#pragma unroll
        for (int ms = 0; ms < 3; ms++)
#pragma unroll
            for (int ns = 0; ns < 5; ns++)
                acc[ms][ns] = __builtin_amdgcn_mfma_f32_16x16x32_bf16(
                    af[ms], bfr[ns], acc[ms][ns], 0, 0, 0);
    }

    ushort_t* out = qtb + ((size_t)b * 480 + mt * 48) * 320;
#pragma unroll
    for (int ms = 0; ms < 3; ms++)
#pragma unroll
        for (int ns = 0; ns < 5; ns++)
#pragma unroll
            for (int r = 0; r < 4; r++)
                out[(size_t)(ms * 16 + quad * 4 + r) * 320 + wn + ns * 16 + lrow] =
                    f2b(acc[ms][ns][r]);
}

// ---------------------------------------------------------------------------
// MFMA M-GEMM fused with pooling.
// ---------------------------------------------------------------------------
__global__ __launch_bounds__(256) void mpool_mfma_kernel(
    const ushort_t* __restrict__ qtb16, const ushort_t* __restrict__ dgb16,
    const float* __restrict__ bb, float* __restrict__ mp)
{
    __shared__ float pool[2 * 12 * 192];

    int jb = blockIdx.x;
    int qb = blockIdx.y;
    int n  = blockIdx.z;
    int b  = n & 15;

    int tid = threadIdx.x;
    int wid = tid >> 6, lane = tid & 63;
    int wm2 = wid >> 1;
    int wm = wm2 * 48, wn = (wid & 1) * 96;
    int lrow = lane & 15, quad = lane >> 4;

    const ushort_t* Abase = qtb16 + ((size_t)b * 480 + qb * 96 + wm) * 320 + quad * 8;
    const ushort_t* Bbase = dgb16 + ((size_t)n * 960 + jb * 192 + wn) * 320 + quad * 8;

    floatx4 acc[3][6];
#pragma unroll
    for (int i = 0; i < 3; i++)
#pragma unroll
        for (int j = 0; j < 6; j++) acc[i][j] = (floatx4){0.f, 0.f, 0.f, 0.f};

#pragma unroll 2
    for (int c0 = 0; c0 < 320; c0 += 32) {
        bf16x8 af[3], bfr[6];
#pragma unroll
        for (int mt = 0; mt < 3; mt++)
            af[mt] = *(const bf16x8*)&Abase[(size_t)(mt * 16 + lrow) * 320 + c0];
#pragma unroll
        for (int nt = 0; nt < 6; nt++)
            bfr[nt] = *(const bf16x8*)&Bbase[(size_t)(nt * 16 + lrow) * 320 + c0];
#pragma unroll
        for (int mt = 0; mt < 3; mt++)
#pragma unroll
            for (int nt = 0; nt < 6; nt++)
                acc[mt][nt] = __builtin_amdgcn_mfma_f32_16x16x32_bf16(
                    af[mt], bfr[nt], acc[mt][nt], 0, 0, 0);
    }

#pragma unroll
    for (int mt = 0; mt < 3; mt++) {
        int g = mt * 4 + quad;
#pragma unroll
        for (int nt = 0; nt < 6; nt++) {
            floatx4 a = acc[mt][nt];
            float rm = fmaxf(fmaxf(a[0], a[1]), fmaxf(a[2], a[3]));
            pool[(wm2 * 12 + g) * 192 + wn + nt * 16 + lrow] = rm;
        }
    }
    __syncthreads();

    if (tid < 64) {
        int qw = tid >> 3, jw = tid & 7;
        int slab = qw >> 2, w = qw & 3;
        float m = -INFINITY;
        const float* pp = &pool[(slab * 12 + w * 3) * 192 + jw * 24];
        for (int g = 0; g < 3; g++)
            for (int cc = 0; cc < 24; cc++)
                m = fmaxf(m, pp[g * 192 + cc]);
        float sig = 1.f / (1.f + expf(-(m + bb[0])));
        mp[(size_t)n * 1600 + (size_t)(qb * 8 + qw) * 40 + (jb * 8 + jw)] = sig;
    }
}

// ---------------------------------------------------------------------------
// Conv block, channel-parallel, atomicMax-merged (Y zeroed before launch).
// ---------------------------------------------------------------------------
#define OCG 10
__global__ __launch_bounds__(256) void convblock_atomic_kernel(
    const float* __restrict__ X, const float* __restrict__ w,
    const float* __restrict__ bias, uint* __restrict__ Y)
{
    __shared__ float xp[48 * 48];
    __shared__ float ys[47 * 47];
    __shared__ float t1[40 * 47];
    __shared__ float outacc[1600];

    int n = blockIdx.x, t = threadIdx.x;
    int oc0 = blockIdx.y * OCG;
    const float* xn = X + (size_t)n * 1600;
    for (int i = t; i < 48 * 48; i += 256) {
        int r = i / 48, c = i - r * 48;
        int rr = r - 4, cc = c - 4;
        xp[i] = (rr >= 0 && rr < 40 && cc >= 0 && cc < 40) ? xn[rr * 40 + cc] : 0.f;
    }
    for (int i = t; i < 1600; i += 256) outacc[i] = 0.f;
    __syncthreads();

    for (int oc = oc0; oc < oc0 + OCG; oc++) {
        float w00 = w[oc * 4 + 0], w01 = w[oc * 4 + 1];
        float w10 = w[oc * 4 + 2], w11 = w[oc * 4 + 3];
        float bo = bias[oc];
        for (int i = t; i < 47 * 47; i += 256) {
            int r = i / 47, c = i - r * 47;
            float v = xp[r * 48 + c] * w00 + xp[r * 48 + c + 1] * w01
                    + xp[(r + 1) * 48 + c] * w10 + xp[(r + 1) * 48 + c + 1] * w11 + bo;
            ys[i] = 1.f / (1.f + expf(-v));
        }
        __syncthreads();
        for (int i = t; i < 40 * 47; i += 256) {
            int r = i / 47, c = i - r * 47;
            int s = (47 * r) / 40, e = (47 * (r + 1) + 39) / 40;
            float m = ys[s * 47 + c];
            for (int x = s + 1; x < e; x++) m = fmaxf(m, ys[x * 47 + c]);
            t1[i] = m;
        }
        __syncthreads();
        for (int i = t; i < 1600; i += 256) {
            int r = i / 40, c = i - r * 40;
            int s = (47 * c) / 40, e = (47 * (c + 1) + 39) / 40;
            float m = t1[r * 47 + s];
            for (int x = s + 1; x < e; x++) m = fmaxf(m, t1[r * 47 + x]);
            outacc[i] = fmaxf(outacc[i], m);
        }
        __syncthreads();
    }
    for (int i = t; i < 1600; i += 256)
        atomicMax(&Y[(size_t)n * 1600 + i], __float_as_uint(outacc[i]));
}

// ---------------------------------------------------------------------------
// Head
// ---------------------------------------------------------------------------
__global__ __launch_bounds__(64) void head_kernel(
    const float* __restrict__ feat, const float* __restrict__ lw,
    const float* __restrict__ lb, float* __restrict__ out)
{
    __shared__ float hs[40];
    int n = blockIdx.x, t = threadIdx.x;
    const float* f = feat + (size_t)n * 1600;
    if (t < 40) {
        float a = 0.f;
        for (int j = 0; j < 40; j++) a += f[t * 40 + j] * lw[j];
        hs[t] = 1.f / (1.f + expf(-(a + lb[0])));
    }
    __syncthreads();
    if (t == 0) {
        float a = 0.f;
        for (int i = 0; i < 40; i++) a += hs[i] * lw[i];
        out[n] = 1.f / (1.f + expf(-(a + lb[0])));
    }
}

// ---------------------------------------------------------------------------
extern "C" void kernel_launch(void* const* d_in, const int* in_sizes, int n_in,
                              void* d_out, int out_size, void* d_ws, size_t ws_size,
                              hipStream_t stream) {
    const float* query    = (const float*)d_in[0];
    const float* pos_doc  = (const float*)d_in[1];
    const float* neg_docs = (const float*)d_in[2];
    const float* qw1 = (const float*)d_in[3];  const float* qb1 = (const float*)d_in[4];
    const float* qw2 = (const float*)d_in[5];  const float* qb2 = (const float*)d_in[6];
    const float* qw3 = (const float*)d_in[7];  const float* qb3 = (const float*)d_in[8];
    const float* dw1 = (const float*)d_in[9];  const float* db1 = (const float*)d_in[10];
    const float* dw2 = (const float*)d_in[11]; const float* db2 = (const float*)d_in[12];
    const float* dw3 = (const float*)d_in[13]; const float* db3 = (const float*)d_in[14];
    const float* bw  = (const float*)d_in[15]; const float* bb  = (const float*)d_in[16];
    const float* mw1 = (const float*)d_in[17]; const float* mb1 = (const float*)d_in[18];
    const float* mw2 = (const float*)d_in[19]; const float* mb2 = (const float*)d_in[20];
    const float* mw3 = (const float*)d_in[21]; const float* mb3 = (const float*)d_in[22];
    const float* lw  = (const float*)d_in[23]; const float* lb  = (const float*)d_in[24];

    float* ws = (float*)d_ws;
    // ---- layout (float offsets) ----
    ushort_t* qw1b  = (ushort_t*)(ws + 0);          // 320*2048 bf16
    ushort_t* qw2b  = (ushort_t*)(ws + 327680);     // 320*640
    ushort_t* qw3b  = (ushort_t*)(ws + 430080);
    ushort_t* dw1b  = (ushort_t*)(ws + 532480);
    ushort_t* dw2b  = (ushort_t*)(ws + 860160);
    ushort_t* dw3b  = (ushort_t*)(ws + 962560);
    ushort_t* bwb   = (ushort_t*)(ws + 1064960);    // 320*320
    ushort_t* qgb16 = (ushort_t*)(ws + 1116160);    // (16,480,320)
    ushort_t* dgb16 = (ushort_t*)(ws + 2344960);    // (80,960,320)
    ushort_t* yt    = (ushort_t*)(ws + 14632960);   // (96,488,320)
    ushort_t* qxb   = (ushort_t*)(ws + 22128640);   // (16,264,1024)
    ushort_t* p1q   = (ushort_t*)(ws + 22128640);   // (16,200,320)
    ushort_t* p2q   = (ushort_t*)(ws + 22640640);   // (16,104,320)
    ushort_t* dxb   = (ushort_t*)(ws + 24291328);   // (80,520,1024)
    ushort_t* p1d   = (ushort_t*)(ws + 24291328);   // (80,360,320)
    ushort_t* p2d   = (ushort_t*)(ws + 28899328);   // (80,200,320)
    ushort_t* qtb16 = (ushort_t*)(ws + 31459328);   // (16,480,320)
    float*    mp    = ws + 32688128;                // (80,40,40)
    float*    ya    = ws + 32816128;                // (80,40,40)
    float*    yb    = ws + 32944128;                // (80,40,40)
    float*    yc    = ws + 33072128;                // (80,40,40)

    // ---- weight prep (im2col layout [n][t*CPAD+c]) ----
    prep_w2_kernel<<<1280, 256, 0, stream>>>(qw1, qw1b, 1024, 1024);
    prep_w2_kernel<<<400, 256, 0, stream>>>(qw2, qw2b, 300, 320);
    prep_w2_kernel<<<400, 256, 0, stream>>>(qw3, qw3b, 300, 320);
    prep_w2_kernel<<<1280, 256, 0, stream>>>(dw1, dw1b, 1024, 1024);
    prep_w2_kernel<<<400, 256, 0, stream>>>(dw2, dw2b, 300, 320);
    prep_w2_kernel<<<400, 256, 0, stream>>>(dw3, dw3b, 300, 320);
    prep_bw_kernel<<<400, 256, 0, stream>>>(bw, bwb);

    // ---- input convert to padded bf16 ----
    {
        dim3 g(264, 16);
        x_pad_bf16_kernel<<<g, 256, 0, stream>>>(query, nullptr, 0,
                                                 239LL * 1024, 239, qxb, 264);
    }
    {
        dim3 g(520, 80);
        x_pad_bf16_kernel<<<g, 256, 0, stream>>>(pos_doc, neg_docs, 16,
                                                 479LL * 1024, 479, dxb, 520);
    }

    // ---- g0 top-ks ----
    topk16_kernel<4><<<16 * 239, 256, 0, stream>>>(
        qxb + 4 * 1024, 239, 264LL * 1024, 1024, 1, 1024, 300,
        qgb16, 0, 480LL * 320, 320, 1,
        nullptr, 0, 0, 0, 0);
    topk16_kernel<4><<<80 * 479, 256, 0, stream>>>(
        dxb + 4 * 1024, 479, 520LL * 1024, 1024, 1, 1024, 300,
        dgb16, 0, 960LL * 320, 320, 1,
        nullptr, 0, 0, 0, 0);

    // ---- conv1 (m97-style LDS pipeline, full N per block) ----
    {
        dim3 g(8, 96);
        conv_lds_kernel<1024><<<g, 256, 0, stream>>>(
            qxb, 264LL * 1024, dxb, 520LL * 1024,
            qw1b, dw1b, qb1, db1, 246, 486, 4, yt);
    }

    // ---- zero conv2/3 input pads ----
    hipMemsetAsync(p1q, 0, 16 * 200 * 320 * 2, stream);
    hipMemsetAsync(p2q, 0, 16 * 104 * 320 * 2, stream);
    hipMemsetAsync(p1d, 0, (size_t)80 * 360 * 320 * 2, stream);
    hipMemsetAsync(p2d, 0, (size_t)80 * 200 * 320 * 2, stream);
    // ---- zero conv-block outputs (atomicMax targets) ----
    hipMemsetAsync(ya, 0, 80 * 1600 * 4, stream);
    hipMemsetAsync(yb, 0, 80 * 1600 * 4, stream);
    hipMemsetAsync(yc, 0, 80 * 1600 * 4, stream);

    // ---- p1 top-ks ----
    topk16_kernel<1><<<16 * 300, 256, 0, stream>>>(
        yt, 300, 488LL * 320, 1, 320, 246, 160,
        qgb16, 239LL * 320, 480LL * 320, 1, 320,
        p1q, 4LL * 320, 200LL * 320, 1, 320);
    topk16_kernel<2><<<80 * 300, 256, 0, stream>>>(
        yt + (size_t)16 * 488 * 320, 300, 488LL * 320, 1, 320, 486, 320,
        dgb16, 479LL * 320, 960LL * 320, 1, 320,
        p1d, 4LL * 320, 360LL * 320, 1, 320);

    // ---- conv2 ----
    {
        dim3 g(6, 96);
        conv_lds_kernel<320><<<g, 256, 0, stream>>>(
            p1q, 200LL * 320, p1d, 360LL * 320,
            qw2b, dw2b, qb2, db2, 167, 327, 3, yt);
    }

    // ---- p2 top-ks ----
    topk16_kernel<1><<<16 * 300, 256, 0, stream>>>(
        yt, 300, 488LL * 320, 1, 320, 167, 80,
        qgb16, 399LL * 320, 480LL * 320, 1, 320,
        p2q, 4LL * 320, 104LL * 320, 1, 320);
    topk16_kernel<2><<<80 * 300, 256, 0, stream>>>(
        yt + (size_t)16 * 488 * 320, 300, 488LL * 320, 1, 320, 327, 160,
        dgb16, 799LL * 320, 960LL * 320, 1, 320,
        p2d, 4LL * 320, 200LL * 320, 1, 320);

    // ---- conv3 ----
    {
        dim3 g(3, 96);
        conv_lds_kernel<320><<<g, 256, 0, stream>>>(
            p2q, 104LL * 320, p2d, 200LL * 320,
            qw3b, dw3b, qb3, db3, 87, 167, 2, yt);
    }

    // ---- p3 top-ks ----
    topk16_kernel<1><<<16 * 300, 256, 0, stream>>>(
        yt, 300, 488LL * 320, 1, 320, 87, 1,
        qgb16, 479LL * 320, 480LL * 320, 1, 320,
        nullptr, 0, 0, 0, 0);
    topk16_kernel<1><<<80 * 300, 256, 0, stream>>>(
        yt + (size_t)16 * 488 * 320, 300, 488LL * 320, 1, 320, 167, 1,
        dgb16, 959LL * 320, 960LL * 320, 1, 320,
        nullptr, 0, 0, 0, 0);

    // ---- qt GEMM + fused similarity/pool ----
    {
        dim3 g(10, 16);
        qt_mfma_kernel<<<g, 256, 0, stream>>>(qgb16, bwb, qtb16);
    }
    {
        dim3 g(5, 5, 80);
        mpool_mfma_kernel<<<g, 256, 0, stream>>>(qtb16, dgb16, bb, mp);
    }

    // ---- conv blocks (channel-parallel, atomicMax-merged) + head ----
    {
        dim3 g(80, 5);
        convblock_atomic_kernel<<<g, 256, 0, stream>>>(mp, mw1, mb1, (uint*)ya);
        convblock_atomic_kernel<<<g, 256, 0, stream>>>(ya, mw2, mb2, (uint*)yb);
        convblock_atomic_kernel<<<g, 256, 0, stream>>>(yb, mw3, mb3, (uint*)yc);
    }
    head_kernel<<<80, 64, 0, stream>>>(yc, lw, lb, (float*)d_out);
}